// Round 4
// baseline (492.891 us; speedup 1.0000x reference)
//
#include <hip/hip_runtime.h>
#include <math.h>

#define NSRC 50000
#define NDST 50000
#define NE   500000
#define HD   128
#define EDIM 32
#define LN_EPS 1e-5f

typedef __attribute__((ext_vector_type(8))) short short8;   // 8 bf16 = 4 VGPR
typedef __attribute__((ext_vector_type(4))) float f32x4;
typedef unsigned short u16;

#define TL2E 2.8853900817779268f   /* 2*log2(e) */
#define L2E  1.4426950408889634f   /* log2(e)   */

__device__ __forceinline__ float EXP2(float x) {
#if __has_builtin(__builtin_amdgcn_exp2f)
    return __builtin_amdgcn_exp2f(x);
#else
    return exp2f(x);
#endif
}
__device__ __forceinline__ float RCP(float x) {
#if __has_builtin(__builtin_amdgcn_rcpf)
    return __builtin_amdgcn_rcpf(x);
#else
    return 1.f / x;
#endif
}
__device__ __forceinline__ u16 f2b(float x) {           // f32 -> bf16 RNE
    unsigned u = __float_as_uint(x);
    return (u16)((u + 0x7FFFu + ((u >> 16) & 1u)) >> 16);
}
__device__ __forceinline__ float b2f(u16 h) {
    return __uint_as_float(((unsigned)h) << 16);
}
__device__ __forceinline__ short8 ld8(const u16* p) { return *(const short8*)p; }

// ---------------------------------------------------------------------------
// prep: single launch replacing fold1 + fold2 + pack_all + memset.
// All packed weights computed directly from raw inputs (folded GEMMs done
// inline per block -- few-microsecond redundant dot products, off the
// critical path). Also zeroes the histogram counters.
// blocks (64 thr): 0-31 Wsrc_pk(TL2E) | 32-63 Wdst_pk(TL2E) | 64-95 W1_pk(+I)
//   96-127 W2_pk | 128-135 We_pk(TL2E) | 136-167 Wsm_pk=pack(Wsrc@Wmsg)
//   168-175 W3_pk=pack((We@Wmsg)@Wout2) | 176 c2+bias2 | 177 bsm | 178+ cnt=0
// ---------------------------------------------------------------------------
__global__ __launch_bounds__(64) void prep_kernel(
    const float* __restrict__ Wsrc, const float* __restrict__ bsrc,
    const float* __restrict__ Wdst, const float* __restrict__ We,
    const float* __restrict__ be,   const float* __restrict__ Wmsg,
    const float* __restrict__ bmsg, const float* __restrict__ Wout,
    const float* __restrict__ bout,
    u16* __restrict__ Wsrc_pk, u16* __restrict__ Wdst_pk,
    u16* __restrict__ W1_pk,   u16* __restrict__ W2_pk,
    u16* __restrict__ We_pk,   u16* __restrict__ Wsm_pk,
    u16* __restrict__ W3_pk,
    float* __restrict__ bsm, float* __restrict__ c2g,
    float* __restrict__ bias2, int* __restrict__ cnt)
{
    __shared__ float sbuf[32 * 128];        // wem (W3 blocks) / c2 (block 176)
    const int b = blockIdx.x;
    const int lane = threadIdx.x;

    if (b >= 178) {                          // ---- cnt zeroing
        const int i4 = (b - 178) * 64 + lane;
        if (i4 < 12504) ((int4*)cnt)[i4] = make_int4(0, 0, 0, 0);
        return;
    }

    const int ln = lane & 15, quad = lane >> 4;
    const float* Wout2 = Wout + HD*HD;

    if (b == 177) {                          // ---- bsm = bsrc@Wmsg + bmsg
#pragma unroll
        for (int h = 0; h < 2; ++h) {
            const int col = lane + h*64;
            float s = bmsg[col];
            for (int m = 0; m < 128; ++m) s = fmaf(bsrc[m], Wmsg[m*HD + col], s);
            bsm[col] = s;
        }
        return;
    }
    if (b == 176) {                          // ---- c2 = be@Wmsg; bias2
#pragma unroll
        for (int h = 0; h < 2; ++h) {
            const int col = lane + h*64;
            float s = 0.f;
            for (int m = 0; m < 128; ++m) s = fmaf(be[m], Wmsg[m*HD + col], s);
            sbuf[col] = s;
            c2g[col] = s;
        }
        __syncthreads();
#pragma unroll
        for (int h = 0; h < 2; ++h) {
            const int col = lane + h*64;
            float s = bout[col];
            for (int k = 0; k < 128; ++k) s = fmaf(sbuf[k], Wout2[k*HD + col], s);
            bias2[col] = s;
        }
        return;
    }
    if (b >= 168) {                          // ---- W3 = (We@Wmsg)@Wout2, pack
        const int tq = b - 168;
        const int i = lane >> 1, k0 = (lane & 1) * 64;
        for (int k = k0; k < k0 + 64; ++k) {
            float s = 0.f;
            for (int m = 0; m < 128; ++m) s = fmaf(We[i*HD + m], Wmsg[m*HD + k], s);
            sbuf[i*128 + k] = s;
        }
        __syncthreads();
        const int jj = tq*16 + ln;
        float s[8] = {0,0,0,0,0,0,0,0};
        for (int k = 0; k < 128; ++k) {
            const float w2 = Wout2[k*HD + jj];
#pragma unroll
            for (int j = 0; j < 8; ++j)
                s[j] = fmaf(sbuf[(quad*8 + j)*128 + k], w2, s[j]);
        }
        u16 tmp[8];
#pragma unroll
        for (int j = 0; j < 8; ++j) tmp[j] = f2b(s[j]);
        *(short8*)(W3_pk + (size_t)(tq*64 + lane)*8) = *(short8*)tmp;
        return;
    }
    if (b >= 136) {                          // ---- Wsm = Wsrc@Wmsg, pack
        const int lb = b - 136, kc = lb >> 3, tq = lb & 7;
        const int jj = tq*16 + ln;
        float s[8] = {0,0,0,0,0,0,0,0};
        for (int k = 0; k < 128; ++k) {
            const float wm = Wmsg[k*HD + jj];
#pragma unroll
            for (int j = 0; j < 8; ++j)
                s[j] = fmaf(Wsrc[(size_t)(kc*32 + quad*8 + j)*HD + k], wm, s[j]);
        }
        u16 tmp[8];
#pragma unroll
        for (int j = 0; j < 8; ++j) tmp[j] = f2b(s[j]);
        *(short8*)(Wsm_pk + (size_t)(lb*64 + lane)*8) = *(short8*)tmp;
        return;
    }

    // ---- direct packs
    const float* src; u16* dst; int lb; float scl = 1.f; bool addI = false;
    if      (b < 32)  { src = Wsrc;  dst = Wsrc_pk; lb = b;       scl = TL2E; }
    else if (b < 64)  { src = Wdst;  dst = Wdst_pk; lb = b - 32;  scl = TL2E; }
    else if (b < 96)  { src = Wout;  dst = W1_pk;   lb = b - 64;  addI = true; }
    else if (b < 128) { src = Wout2; dst = W2_pk;   lb = b - 96; }
    else              { src = We;    dst = We_pk;   lb = b - 128; scl = TL2E; }
    const int kc = lb >> 3, tq = lb & 7;
    u16 tmp[8];
#pragma unroll
    for (int j = 0; j < 8; ++j) {
        const int i = kc*32 + quad*8 + j, jj = tq*16 + ln;
        float v = src[(size_t)i*HD + jj] * scl;
        if (addI && i == jj) v += 1.f;
        tmp[j] = f2b(v);
    }
    *(short8*)(dst + (size_t)(lb*64 + lane)*8) = *(short8*)tmp;
}

// ---------------------------------------------------------------------------
// mega: block-range fusion:
//   [0, NBLK)      node: s1 tanh-dot + srcmsgb, 32 rows/wave, LDS-staged W
//   [NBLK, 2NBLK)  dst:  s2 tanh-dot, 32 rows/wave, LDS-staged W
//   [2NBLK, +HB4)  hist: cnt[dst]++ / rank, 4 edges per thread
// Weights staged to LDS once per block (32KB, restaged for phase 2) ->
// B-frags come from conflict-free ds_read_b128 instead of L1-thrashing L2.
// Each B-frag feeds TWO MFMAs (2 row-tiles) -> halved weight traffic.
// Transpose slab is per-wave (no barrier; DS ops in-order within a wave),
// XOR-swizzled (tt ^= row>>2) to spread the 32B column blocks across banks.
// ---------------------------------------------------------------------------
#define NBLK 391
#define HB4 ((NE/4 + 255) / 256)

__global__ __launch_bounds__(256) void mega_kernel(
    const float* __restrict__ src_x, const float* __restrict__ dst_x,
    const int* __restrict__ ei,
    const u16* __restrict__ Wsrc_pk, const u16* __restrict__ Wsm_pk,
    const u16* __restrict__ Wdst_pk,
    const float* __restrict__ bsrc, const float* __restrict__ bsm,
    const float* __restrict__ bdst, const float* __restrict__ wattn,
    float* __restrict__ s1, float* __restrict__ s2,
    u16* __restrict__ srcmsgb, int* __restrict__ cnt, int* __restrict__ rank)
{
    __shared__ __align__(16) u16 wlds[16384];      // 32 KB staged weights
    __shared__ __align__(16) u16 tlds[4][2048];    // 16 KB per-wave transpose
    const int t = threadIdx.x;
    const int blk = blockIdx.x;

    if (blk >= 2*NBLK) {                 // ---- hist path (4 edges/thread)
        const int idx = (blk - 2*NBLK) * 256 + t;
        if (idx < NE/4) {
            int4 d4 = ((const int4*)(ei + NE))[idx];
            int4 r4;
            r4.x = atomicAdd(&cnt[d4.x], 1);
            r4.y = atomicAdd(&cnt[d4.y], 1);
            r4.z = atomicAdd(&cnt[d4.z], 1);
            r4.w = atomicAdd(&cnt[d4.w], 1);
            ((int4*)rank)[idx] = r4;
        }
        return;
    }

    const int w = t >> 6, lane = t & 63;
    const int ln = lane & 15, quad = lane >> 4;
    const bool is_src = (blk < NBLK);
    const int b = is_src ? blk : blk - NBLK;
    int row0 = b * 128 + w * 32;
    if (row0 > NSRC - 32) row0 = NSRC - 32;       // dup writes benign

    // x loads (2 row-tiles), converted to bf16 A-frags in-register
    const float* X = is_src ? src_x : dst_x;
    const float* rp0 = X + (size_t)(row0 + ln)*HD;
    const float* rp1 = rp0 + (size_t)16*HD;
    short8 a0[4], a1[4];
#pragma unroll
    for (int kc = 0; kc < 4; ++kc) {
        float4 f0 = *(const float4*)(rp0 + kc*32 + quad*8);
        float4 f1 = *(const float4*)(rp0 + kc*32 + quad*8 + 4);
        float4 g0 = *(const float4*)(rp1 + kc*32 + quad*8);
        float4 g1 = *(const float4*)(rp1 + kc*32 + quad*8 + 4);
        u16 tb[8] = { f2b(f0.x), f2b(f0.y), f2b(f0.z), f2b(f0.w),
                      f2b(f1.x), f2b(f1.y), f2b(f1.z), f2b(f1.w) };
        a0[kc] = *(short8*)tb;
        u16 tc[8] = { f2b(g0.x), f2b(g0.y), f2b(g0.z), f2b(g0.w),
                      f2b(g1.x), f2b(g1.y), f2b(g1.z), f2b(g1.w) };
        a1[kc] = *(short8*)tc;
    }

    // stage phase-1 weights (32 KB, cooperative, coalesced 16B)
    const u16* Wpk = is_src ? Wsrc_pk : Wdst_pk;
#pragma unroll
    for (int it = 0; it < 8; ++it) {
        short8 v = ld8(Wpk + (size_t)(it*256 + t)*8);
        *(short8*)(&wlds[(it*256 + t)*8]) = v;
    }
    __syncthreads();

    const float* bb_ = is_src ? bsrc : bdst;
    const float* wa  = is_src ? wattn : wattn + HD;
    float* sout      = is_src ? s1 : s2;

    // ---- tanh-dot (exp2/rcp refactor), two tiles share each B-frag
    float v0[4] = {0,0,0,0}, v1[4] = {0,0,0,0};
    float ws = 0.f;
#pragma unroll
    for (int tt = 0; tt < 8; ++tt) {
        const float bb = bb_[tt*16 + ln] * TL2E;
        const float ww = wa[tt*16 + ln];
        f32x4 acc0 = {bb, bb, bb, bb};
        f32x4 acc1 = {bb, bb, bb, bb};
#pragma unroll
        for (int kc = 0; kc < 4; ++kc) {
            short8 bf = ld8(&wlds[(size_t)((kc*8 + tt)*64 + lane)*8]);
            acc0 = __builtin_amdgcn_mfma_f32_16x16x32_bf16(a0[kc], bf, acc0, 0, 0, 0);
            acc1 = __builtin_amdgcn_mfma_f32_16x16x32_bf16(a1[kc], bf, acc1, 0, 0, 0);
        }
        ws += ww;
#pragma unroll
        for (int r = 0; r < 4; ++r) {
            v0[r] = fmaf(ww, RCP(EXP2(acc0[r]) + 1.f), v0[r]);
            v1[r] = fmaf(ww, RCP(EXP2(acc1[r]) + 1.f), v1[r]);
        }
    }
#pragma unroll
    for (int off = 8; off >= 1; off >>= 1) {
        ws += __shfl_xor(ws, off);
#pragma unroll
        for (int r = 0; r < 4; ++r) {
            v0[r] += __shfl_xor(v0[r], off);
            v1[r] += __shfl_xor(v1[r], off);
        }
    }
    if (ln == 0) {
#pragma unroll
        for (int r = 0; r < 4; ++r) {
            sout[row0 + quad*4 + r]      = fmaf(-2.f, v0[r], ws);
            sout[row0 + 16 + quad*4 + r] = fmaf(-2.f, v1[r], ws);
        }
    }

    if (!is_src) return;

    // ---- restage with Wsm, then srcmsg path
    __syncthreads();
#pragma unroll
    for (int it = 0; it < 8; ++it) {
        short8 v = ld8(Wsm_pk + (size_t)(it*256 + t)*8);
        *(short8*)(&wlds[(it*256 + t)*8]) = v;
    }
    __syncthreads();

    u16* slab = &tlds[w][0];
#pragma unroll
    for (int tile = 0; tile < 2; ++tile) {
#pragma unroll
        for (int tt = 0; tt < 8; ++tt) {
            const float bs = bsm[tt*16 + ln];
            f32x4 acc = {bs, bs, bs, bs};
#pragma unroll
            for (int kc = 0; kc < 4; ++kc) {
                short8 bf = ld8(&wlds[(size_t)((kc*8 + tt)*64 + lane)*8]);
                acc = __builtin_amdgcn_mfma_f32_16x16x32_bf16(
                          tile ? a1[kc] : a0[kc], bf, acc, 0, 0, 0);
            }
            // swizzled write: row = quad*4+r (row>>2 == quad), col blk tt^quad
#pragma unroll
            for (int r = 0; r < 4; ++r)
                slab[(quad*4 + r)*128 + ((tt ^ quad) << 4) + ln] = f2b(acc[r]);
        }
        // per-wave readback (DS in-order within wave; no barrier needed)
#pragma unroll
        for (int r2 = 0; r2 < 4; ++r2) {
            const int row = r2*4 + quad;          // row>>2 == r2
            const int c = ln*8;
            const int sidx = row*128 + (((c >> 4) ^ r2) << 4) + (c & 15);
            short8 val = *(const short8*)(&slab[sidx]);
            *(short8*)(srcmsgb + (size_t)(row0 + tile*16 + row)*HD + c) = val;
        }
    }
}

// ---------------------------------------------------------------------------
// scan1: per-1024-chunk exclusive scan of cnt into rowptr, block sums to bsum
// ---------------------------------------------------------------------------
__global__ __launch_bounds__(1024) void scan1_kernel(
    const int* __restrict__ cnt, int* __restrict__ excl, int* __restrict__ bsum)
{
    __shared__ int buf[1024];
    const int t = threadIdx.x;
    const int i = blockIdx.x * 1024 + t;
    int v = (i < NDST) ? cnt[i] : 0;
    buf[t] = v;
    __syncthreads();
    for (int off = 1; off < 1024; off <<= 1) {
        int tv = (t >= off) ? buf[t - off] : 0;
        __syncthreads();
        buf[t] += tv;
        __syncthreads();
    }
    if (i < NDST) excl[i] = buf[t] - v;
    if (t == 1023) bsum[blockIdx.x] = buf[1023];
}

// ---------------------------------------------------------------------------
// scan23: every block redundantly wave-scans the 49 chunk sums, then applies
// the offset to its rowptr slice.
// ---------------------------------------------------------------------------
__global__ __launch_bounds__(256) void scan23_kernel(
    const int* __restrict__ bsum, int* __restrict__ rowptr)
{
    __shared__ int pref[64];
    const int t = threadIdx.x;
    const int NB = (NDST + 1023) / 1024;     // 49
    if (t < 64) {
        int orig = (t < NB) ? bsum[t] : 0;
        int v = orig;
        for (int off = 1; off < 64; off <<= 1) {
            int u = __shfl_up(v, off);
            if (t >= off) v += u;
        }
        pref[t] = v - orig;                  // exclusive prefix
        if (blockIdx.x == 0 && t == NB - 1) rowptr[NDST] = v;  // total
    }
    __syncthreads();
    const int i = blockIdx.x * 256 + t;
    if (i < NDST) rowptr[i] += pref[i >> 10];
}

// ---------------------------------------------------------------------------
// edge_score: 16 edges / wave. Reads edge_attr f32 directly; tanh-dot in
// exp2/rcp form; score kept in log2-domain (no-max softmax safe). Atomic-free
// scatter: pos = rowptr[dst] + rank[e]. Record int4 {src, e, score, 0}.
// ---------------------------------------------------------------------------
__global__ __launch_bounds__(256) void edge_score_kernel(
    const int* __restrict__ ei, const float* __restrict__ eattr,
    const u16* __restrict__ We_pk, const float* __restrict__ be,
    const float* __restrict__ wattn, const float* __restrict__ battn,
    const float* __restrict__ s1, const float* __restrict__ s2,
    const int* __restrict__ rowptr, const int* __restrict__ rank,
    int4* __restrict__ ev16)
{
    const int t = threadIdx.x;
    const int w = t >> 6, lane = t & 63;
    const int ln = lane & 15, quad = lane >> 4;
    const int e0 = (blockIdx.x * 4 + w) * 16;
    if (e0 >= NE) return;                  // NE%16==0, no partial tiles

    const float* ap = eattr + (size_t)(e0 + ln)*EDIM + quad*8;
    float4 f0 = *(const float4*)(ap);
    float4 f1 = *(const float4*)(ap + 4);
    u16 ab[8] = { f2b(f0.x), f2b(f0.y), f2b(f0.z), f2b(f0.w),
                  f2b(f1.x), f2b(f1.y), f2b(f1.z), f2b(f1.w) };
    short8 a = *(short8*)ab;

    const float* wa3 = wattn + 2*HD;
    float v[4] = {0.f, 0.f, 0.f, 0.f};
    float ws = 0.f;
#pragma unroll
    for (int tt = 0; tt < 8; ++tt) {
        const float bb = be[tt*16 + ln] * TL2E;
        const float ww = wa3[tt*16 + ln];
        f32x4 acc = {bb, bb, bb, bb};
        short8 b = ld8(We_pk + (size_t)(tt*64 + lane)*8);
        acc = __builtin_amdgcn_mfma_f32_16x16x32_bf16(a, b, acc, 0, 0, 0);
        ws += ww;
#pragma unroll
        for (int r = 0; r < 4; ++r)
            v[r] = fmaf(ww, RCP(EXP2(acc[r]) + 1.f), v[r]);
    }
#pragma unroll
    for (int off = 8; off >= 1; off >>= 1) {
        ws += __shfl_xor(ws, off);
#pragma unroll
        for (int r = 0; r < 4; ++r) v[r] += __shfl_xor(v[r], off);
    }
    // redistribute: lane ln gets the dot for edge e0+ln
    const int srcq = (ln >> 2) << 4;
    float sv0 = __shfl(v[0], srcq);
    float sv1 = __shfl(v[1], srcq);
    float sv2 = __shfl(v[2], srcq);
    float sv3 = __shfl(v[3], srcq);
    const int rr = ln & 3;
    float vlo = (rr & 1) ? sv1 : sv0;
    float vhi = (rr & 1) ? sv3 : sv2;
    float vv  = (rr & 2) ? vhi : vlo;

    if (quad == 0) {                       // 16 lanes, one edge each
        const int e = e0 + ln;
        const int srcn = ei[e];
        const int dstn = ei[NE + e];
        float sc = (fmaf(-2.f, vv, ws) + s1[srcn] + s2[dstn] + battn[0]) * L2E;
        const int pos = rowptr[dstn] + rank[e];
        ev16[pos] = make_int4(srcn, e, __float_as_int(sc), 0);
    }
}

// ---------------------------------------------------------------------------
// dst_agg: 1 wave per dst, single pass (no-max softmax): accumulate
// unnormalized w=exp2(sc), sum(w), sum(w*msg), sum(w*ea); normalize at end.
// msg row: 16 lanes x 16B bf16; ea row: 8 lanes x 16B f32 (one cache line).
// ---------------------------------------------------------------------------
__global__ __launch_bounds__(256) void dst_agg_kernel(
    const int4* __restrict__ ev16, const int* __restrict__ rowptr,
    const u16* __restrict__ srcmsgb, const float* __restrict__ eattr,
    const float* __restrict__ c2,
    u16* __restrict__ aggSb, u16* __restrict__ weab)
{
    const int lane = threadIdx.x & 63;
    const int d = blockIdx.x * 4 + (threadIdx.x >> 6);
    const int el = lane >> 4, c = lane & 15;
    const int start = rowptr[d], end = rowptr[d + 1];

    if (start == end) {
        if (el == 0) {
            u16 z[8];
#pragma unroll
            for (int j = 0; j < 8; ++j) z[j] = f2b(-c2[c*8 + j]);
            *(short8*)(aggSb + (size_t)d*HD + c*8) = *(short8*)z;
            if (c < 8) {
                u16 zz[4] = {0,0,0,0};
                *(ushort4*)(weab + (size_t)d*EDIM + c*4) = *(ushort4*)zz;
            }
        }
        return;
    }

    float sacc = 0.f;
    float acc[8]  = {0,0,0,0,0,0,0,0};
    float wacc[4] = {0,0,0,0};

    int icur = start + el;
    bool vcur = (icur < end);
    int iicur = vcur ? icur : start;
    int4 q = ev16[iicur];

    for (int i0 = start; i0 < end; i0 += 4) {
        const float wgt = vcur ? EXP2(__int_as_float(q.z)) : 0.f;
        const int   srow = q.x;
        const int   ecur = q.y;
        // prefetch next record (clamped; harmless re-read of ev16[start])
        const int inx = i0 + 4 + el;
        vcur = (inx < end);
        iicur = vcur ? inx : start;
        q = ev16[iicur];

        sacc += wgt;
        short8 sm = ld8(srcmsgb + (size_t)srow*HD + c*8);
#pragma unroll
        for (int j = 0; j < 8; ++j)
            acc[j] = fmaf(wgt, b2f(((u16*)&sm)[j]), acc[j]);
        if (c < 8) {
            float4 f = *(const float4*)(eattr + (size_t)ecur*EDIM + c*4);
            wacc[0] = fmaf(wgt, f.x, wacc[0]);
            wacc[1] = fmaf(wgt, f.y, wacc[1]);
            wacc[2] = fmaf(wgt, f.z, wacc[2]);
            wacc[3] = fmaf(wgt, f.w, wacc[3]);
        }
    }
#pragma unroll
    for (int off = 16; off <= 32; off <<= 1) {
        sacc += __shfl_xor(sacc, off);
#pragma unroll
        for (int j = 0; j < 8; ++j) acc[j] += __shfl_xor(acc[j], off);
#pragma unroll
        for (int j = 0; j < 4; ++j) wacc[j] += __shfl_xor(wacc[j], off);
    }
    const float inv = RCP(sacc);
    if (el == 0) {
        u16 o[8];
#pragma unroll
        for (int j = 0; j < 8; ++j) o[j] = f2b(acc[j] * inv);
        *(short8*)(aggSb + (size_t)d*HD + c*8) = *(short8*)o;
        if (c < 8) {
            u16 o2[4];
#pragma unroll
            for (int j = 0; j < 4; ++j) o2[j] = f2b(wacc[j] * inv);
            *(ushort4*)(weab + (size_t)d*EDIM + c*4) = *(ushort4*)o2;
        }
    }
}

// ---------------------------------------------------------------------------
// final: out = LN(dst_x@W1p + aggSb@Wout2 + weab@W3 + bias2) * gamma + beta
// per 16 dst rows / wave; dst_x read f32 + converted in-reg.
// ---------------------------------------------------------------------------
__global__ __launch_bounds__(256) void final_kernel(
    const float* __restrict__ dst_x, const u16* __restrict__ aggSb,
    const u16* __restrict__ weab,
    const u16* __restrict__ W1_pk, const u16* __restrict__ W2_pk,
    const u16* __restrict__ W3_pk, const float* __restrict__ bias2,
    const float* __restrict__ gamma, const float* __restrict__ beta,
    float* __restrict__ out)
{
    const int t = threadIdx.x;
    const int w = t >> 6, lane = t & 63;
    const int ln = lane & 15, quad = lane >> 4;
    int row0 = (blockIdx.x * 4 + w) * 16;
    if (row0 > NDST - 16) row0 = NDST - 16;

    const float* rp = dst_x + (size_t)(row0 + ln)*HD;
    short8 a1[4], a2[4], a3;
#pragma unroll
    for (int kc = 0; kc < 4; ++kc) {
        float4 f0 = *(const float4*)(rp + kc*32 + quad*8);
        float4 f1 = *(const float4*)(rp + kc*32 + quad*8 + 4);
        u16 tb[8] = { f2b(f0.x), f2b(f0.y), f2b(f0.z), f2b(f0.w),
                      f2b(f1.x), f2b(f1.y), f2b(f1.z), f2b(f1.w) };
        a1[kc] = *(short8*)tb;
        a2[kc] = ld8(aggSb + (size_t)(row0 + ln)*HD + kc*32 + quad*8);
    }
    a3 = ld8(weab + (size_t)(row0 + ln)*EDIM + quad*8);

    f32x4 accs[8];
#pragma unroll
    for (int tt = 0; tt < 8; ++tt) {
        const float bb = bias2[tt*16 + ln];
        f32x4 acc = {bb, bb, bb, bb};
#pragma unroll
        for (int kc = 0; kc < 4; ++kc) {
            short8 b = ld8(W1_pk + (size_t)((kc*8 + tt)*64 + lane)*8);
            acc = __builtin_amdgcn_mfma_f32_16x16x32_bf16(a1[kc], b, acc, 0, 0, 0);
        }
#pragma unroll
        for (int kc = 0; kc < 4; ++kc) {
            short8 b = ld8(W2_pk + (size_t)((kc*8 + tt)*64 + lane)*8);
            acc = __builtin_amdgcn_mfma_f32_16x16x32_bf16(a2[kc], b, acc, 0, 0, 0);
        }
        {
            short8 b = ld8(W3_pk + (size_t)(tt*64 + lane)*8);
            acc = __builtin_amdgcn_mfma_f32_16x16x32_bf16(a3, b, acc, 0, 0, 0);
        }
        accs[tt] = acc;
    }

    const float gl[8] = { gamma[ln], gamma[16+ln], gamma[32+ln], gamma[48+ln],
                          gamma[64+ln], gamma[80+ln], gamma[96+ln], gamma[112+ln] };
    const float bl[8] = { beta[ln], beta[16+ln], beta[32+ln], beta[48+ln],
                          beta[64+ln], beta[80+ln], beta[96+ln], beta[112+ln] };
#pragma unroll
    for (int r = 0; r < 4; ++r) {
        float s = 0.f, qq = 0.f;
#pragma unroll
        for (int tt = 0; tt < 8; ++tt) {
            float u = accs[tt][r];
            s += u; qq += u*u;
        }
#pragma unroll
        for (int off = 8; off >= 1; off >>= 1) {
            s  += __shfl_xor(s, off);
            qq += __shfl_xor(qq, off);
        }
        const float mean = s * (1.f / HD);
        const float var  = qq * (1.f / HD) - mean * mean;
        const float rstd = rsqrtf(var + LN_EPS);
        const int row = row0 + quad*4 + r;
#pragma unroll
        for (int tt = 0; tt < 8; ++tt)
            out[(size_t)row*HD + tt*16 + ln] =
                (accs[tt][r] - mean) * rstd * gl[tt] + bl[tt];
    }
}

// ---------------------------------------------------------------------------
extern "C" void kernel_launch(void* const* d_in, const int* in_sizes, int n_in,
                              void* d_out, int out_size, void* d_ws, size_t ws_size,
                              hipStream_t stream)
{
    const float* src_x = (const float*)d_in[0];
    const float* dst_x = (const float*)d_in[1];
    const int*   ei    = (const int*)d_in[2];
    const float* eattr = (const float*)d_in[3];
    const float* Wsrc  = (const float*)d_in[4];
    const float* bsrc  = (const float*)d_in[5];
    const float* Wdst  = (const float*)d_in[6];
    const float* bdst  = (const float*)d_in[7];
    const float* We    = (const float*)d_in[8];
    const float* be    = (const float*)d_in[9];
    const float* Wattn = (const float*)d_in[10];
    const float* battn = (const float*)d_in[11];
    const float* Wmsg  = (const float*)d_in[12];
    const float* bmsg  = (const float*)d_in[13];
    const float* Wout  = (const float*)d_in[14];
    const float* bout  = (const float*)d_in[15];
    const float* gamma = (const float*)d_in[16];
    const float* beta  = (const float*)d_in[17];
    float* out = (float*)d_out;

    float* ws = (float*)d_ws;
    u16* srcmsgb = (u16*)(ws + 0);            // 6.4M u16
    u16* aggSb   = (u16*)(ws + 3200000);      // 6.4M u16
    u16* weab    = (u16*)(ws + 6400000);      // 1.6M u16
    float* s1    = ws + 7200000;              // 50048
    float* s2    = ws + 7250048;              // 50048
    float* bsm   = ws + 7300096;              // 128
    float* c2    = ws + 7300224;              // 128
    float* bias2 = ws + 7300352;              // 128
    u16* Wsrc_pk = (u16*)(ws + 7300480);      // 16384 u16
    u16* Wdst_pk = (u16*)(ws + 7308672);
    u16* Wsm_pk  = (u16*)(ws + 7316864);
    u16* W1_pk   = (u16*)(ws + 7325056);
    u16* W2_pk   = (u16*)(ws + 7333248);
    u16* We_pk   = (u16*)(ws + 7341440);      // 4096 u16
    u16* W3_pk   = (u16*)(ws + 7343488);      // 4096 u16
    int* rowptr  = (int*)(ws + 7345536);      // 50016
    int* cnt     = (int*)(ws + 7395552);      // 50016
    int* bsum    = (int*)(ws + 7445568);      // 64
    int* rank    = (int*)(ws + 7445632);      // 500000
    int4* ev16   = (int4*)(ws + 7945632);     // 500000 int4 (16B-aligned)

    prep_kernel<<<374, 64, 0, stream>>>(Wsrc, bsrc, Wdst, We, be, Wmsg, bmsg,
                                        Wout, bout,
                                        Wsrc_pk, Wdst_pk, W1_pk, W2_pk, We_pk,
                                        Wsm_pk, W3_pk, bsm, c2, bias2, cnt);

    mega_kernel<<<2*NBLK + HB4, 256, 0, stream>>>(
        src_x, dst_x, ei, Wsrc_pk, Wsm_pk, Wdst_pk,
        bsrc, bsm, bdst, Wattn, s1, s2, srcmsgb, cnt, rank);

    scan1_kernel<<<(NDST + 1023) / 1024, 1024, 0, stream>>>(cnt, rowptr, bsum);
    scan23_kernel<<<(NDST + 255) / 256, 256, 0, stream>>>(bsum, rowptr);

    edge_score_kernel<<<(NE/16 + 3) / 4, 256, 0, stream>>>(
        ei, eattr, We_pk, be, Wattn, battn, s1, s2, rowptr, rank, ev16);

    dst_agg_kernel<<<NDST / 4, 256, 0, stream>>>(ev16, rowptr, srcmsgb,
                                                 eattr, c2, aggSb, weab);

    final_kernel<<<(NDST/16 + 3) / 4, 256, 0, stream>>>(
        dst_x, aggSb, weab, W1_pk, W2_pk, W3_pk, bias2, gamma, beta, out);
}

// Round 5
// 303.153 us; speedup vs baseline: 1.6259x; 1.6259x over previous
//
#include <hip/hip_runtime.h>
#include <math.h>

#define NSRC 50000
#define NDST 50000
#define NE   500000
#define HD   128
#define EDIM 32
#define LN_EPS 1e-5f

typedef __attribute__((ext_vector_type(8))) short short8;   // 8 bf16 = 4 VGPR
typedef __attribute__((ext_vector_type(4))) float f32x4;
typedef unsigned short u16;

#define TL2E 2.8853900817779268f   /* 2*log2(e) */
#define L2E  1.4426950408889634f   /* log2(e)   */

__device__ __forceinline__ float EXP2(float x) {
#if __has_builtin(__builtin_amdgcn_exp2f)
    return __builtin_amdgcn_exp2f(x);
#else
    return exp2f(x);
#endif
}
__device__ __forceinline__ float RCP(float x) {
#if __has_builtin(__builtin_amdgcn_rcpf)
    return __builtin_amdgcn_rcpf(x);
#else
    return 1.f / x;
#endif
}
__device__ __forceinline__ u16 f2b(float x) {           // f32 -> bf16 RNE
    unsigned u = __float_as_uint(x);
    return (u16)((u + 0x7FFFu + ((u >> 16) & 1u)) >> 16);
}
__device__ __forceinline__ float b2f(u16 h) {
    return __uint_as_float(((unsigned)h) << 16);
}
__device__ __forceinline__ short8 ld8(const u16* p) { return *(const short8*)p; }

// ---------------------------------------------------------------------------
// fold1: Wsm = Wsrc@Wmsg, bsm = bsrc@Wmsg + bmsg, WeMsg = We@Wmsg, c2 = be@Wmsg
// (128 threads span output column j -> coalesced Wmsg reads, 1 dot/thread).
// Blocks r >= 162 zero the histogram counters (replaces memset launch).
// ---------------------------------------------------------------------------
__global__ __launch_bounds__(128) void fold1_kernel(
    const float* __restrict__ Wsrc, const float* __restrict__ bsrc,
    const float* __restrict__ We,   const float* __restrict__ be,
    const float* __restrict__ Wmsg, const float* __restrict__ bmsg,
    float* __restrict__ Wsm, float* __restrict__ bsm,
    float* __restrict__ WeMsg, float* __restrict__ c2,
    int* __restrict__ cnt)
{
    const int j = threadIdx.x;
    const int r = blockIdx.x;
    if (r >= 162) {
        int i = (r - 162) * 128 + j;
        if (i < NDST + 16) cnt[i] = 0;
        return;
    }
    float s = 0.f;
    if (r < 128) {
        for (int k = 0; k < 128; ++k) s += Wsrc[r*HD + k] * Wmsg[k*HD + j];
        Wsm[r*HD + j] = s;
    } else if (r < 160) {
        const int rr = r - 128;
        for (int k = 0; k < 128; ++k) s += We[rr*HD + k] * Wmsg[k*HD + j];
        WeMsg[rr*HD + j] = s;
    } else if (r == 160) {
        for (int k = 0; k < 128; ++k) s += bsrc[k] * Wmsg[k*HD + j];
        bsm[j] = s + bmsg[j];
    } else {
        for (int k = 0; k < 128; ++k) s += be[k] * Wmsg[k*HD + j];
        c2[j] = s;
    }
}

// ---------------------------------------------------------------------------
// pack_all: pack f32 [K x 128] weights into bf16 MFMA B-fragment layout.
// Wsrc/Wdst/We pre-scaled by 2*log2(e) (tanh-dot exp2/rcp refactor).
// W1 = Wout1 + I inline. W3 = WeMsg@Wout2 and bias2 = bout + c2@Wout2 inline.
// blocks: Wsrc 0-31, Wdst 32-63, Wsm 64-95, W1 96-127, W2 128-159,
//         We 160-167 (K=32), W3 168-175 (K=32, computed), bias2 176.
// ---------------------------------------------------------------------------
__global__ __launch_bounds__(64) void pack_all_kernel(
    const float* __restrict__ Wsrc, const float* __restrict__ Wdst,
    const float* __restrict__ Wsm,  const float* __restrict__ Wout,
    const float* __restrict__ We,   const float* __restrict__ WeMsg,
    const float* __restrict__ c2,   const float* __restrict__ bout,
    u16* __restrict__ Wsrc_pk, u16* __restrict__ Wdst_pk,
    u16* __restrict__ Wsm_pk,  u16* __restrict__ W1_pk,
    u16* __restrict__ W2_pk,   u16* __restrict__ We_pk,
    u16* __restrict__ W3_pk,   float* __restrict__ bias2)
{
    const int b = blockIdx.x;
    const int lane = threadIdx.x;
    const int ln = lane & 15, quad = lane >> 4;
    const float* Wout2 = Wout + HD*HD;

    if (b == 176) {                        // bias2 = bout + c2@Wout2
#pragma unroll
        for (int h = 0; h < 2; ++h) {
            const int col = lane + h*64;
            float s = 0.f;
            for (int k = 0; k < 128; ++k) s += c2[k] * Wout2[k*HD + col];
            bias2[col] = bout[col] + s;
        }
        return;
    }
    if (b >= 168) {                        // W3 = WeMsg@Wout2 (32x128), packed
        const int t = b - 168;
        const int jj = t*16 + ln;
        float sacc[8] = {0,0,0,0,0,0,0,0};
        for (int k = 0; k < 128; ++k) {
            const float w2 = Wout2[k*HD + jj];
#pragma unroll
            for (int j = 0; j < 8; ++j)
                sacc[j] = fmaf(WeMsg[(quad*8 + j)*HD + k], w2, sacc[j]);
        }
        u16 tmp[8];
#pragma unroll
        for (int j = 0; j < 8; ++j) tmp[j] = f2b(sacc[j]);
        *(short8*)(W3_pk + (size_t)(t*64 + lane)*8) = *(short8*)tmp;
        return;
    }

    const float* src; u16* dst; int lb; float scl = 1.f; bool addI = false;
    if      (b < 32)  { src = Wsrc; dst = Wsrc_pk; lb = b;       scl = TL2E; }
    else if (b < 64)  { src = Wdst; dst = Wdst_pk; lb = b - 32;  scl = TL2E; }
    else if (b < 96)  { src = Wsm;  dst = Wsm_pk;  lb = b - 64; }
    else if (b < 128) { src = Wout; dst = W1_pk;   lb = b - 96;  addI = true; }
    else if (b < 160) { src = Wout2;dst = W2_pk;   lb = b - 128; }
    else              { src = We;   dst = We_pk;   lb = b - 160; scl = TL2E; }
    const int kc = lb >> 3, t = lb & 7;
    u16 tmp[8];
#pragma unroll
    for (int j = 0; j < 8; ++j) {
        const int i = kc*32 + quad*8 + j, jj = t*16 + ln;
        float v = src[(size_t)i*HD + jj] * scl;
        if (addI && i == jj) v += 1.f;
        tmp[j] = f2b(v);
    }
    *(short8*)(dst + (size_t)(lb*64 + lane)*8) = *(short8*)tmp;
}

// ---------------------------------------------------------------------------
// mega: block-range fusion:
//   [0, NBLK)      node: s1 tanh-dot + srcmsgb, 32 rows/wave, LDS-staged W
//   [NBLK, 2NBLK)  dst:  s2 tanh-dot, 32 rows/wave, LDS-staged W
//   [2NBLK, +HB4)  hist: cnt[dst]++ / rank, 4 edges per thread
// Weights staged to LDS once per block (32KB, restaged for phase 2) ->
// B-frags come from conflict-free ds_read_b128 instead of L1-thrashing L2.
// Each B-frag feeds TWO MFMAs (2 row-tiles) -> halved weight traffic.
// Transpose slab is per-wave (no barrier; DS ops in-order within a wave),
// XOR-swizzled (tt ^= row>>2) to spread the 32B column blocks across banks.
// ---------------------------------------------------------------------------
#define NBLK 391
#define HB4 ((NE/4 + 255) / 256)

__global__ __launch_bounds__(256) void mega_kernel(
    const float* __restrict__ src_x, const float* __restrict__ dst_x,
    const int* __restrict__ ei,
    const u16* __restrict__ Wsrc_pk, const u16* __restrict__ Wsm_pk,
    const u16* __restrict__ Wdst_pk,
    const float* __restrict__ bsrc, const float* __restrict__ bsm,
    const float* __restrict__ bdst, const float* __restrict__ wattn,
    float* __restrict__ s1, float* __restrict__ s2,
    u16* __restrict__ srcmsgb, int* __restrict__ cnt, int* __restrict__ rank)
{
    __shared__ __align__(16) u16 wlds[16384];      // 32 KB staged weights
    __shared__ __align__(16) u16 tlds[4][2048];    // 16 KB per-wave transpose
    const int t = threadIdx.x;
    const int blk = blockIdx.x;

    if (blk >= 2*NBLK) {                 // ---- hist path (4 edges/thread)
        const int idx = (blk - 2*NBLK) * 256 + t;
        if (idx < NE/4) {
            int4 d4 = ((const int4*)(ei + NE))[idx];
            int4 r4;
            r4.x = atomicAdd(&cnt[d4.x], 1);
            r4.y = atomicAdd(&cnt[d4.y], 1);
            r4.z = atomicAdd(&cnt[d4.z], 1);
            r4.w = atomicAdd(&cnt[d4.w], 1);
            ((int4*)rank)[idx] = r4;
        }
        return;
    }

    const int w = t >> 6, lane = t & 63;
    const int ln = lane & 15, quad = lane >> 4;
    const bool is_src = (blk < NBLK);
    const int b = is_src ? blk : blk - NBLK;
    int row0 = b * 128 + w * 32;
    if (row0 > NSRC - 32) row0 = NSRC - 32;       // dup writes benign

    // x loads (2 row-tiles), converted to bf16 A-frags in-register
    const float* X = is_src ? src_x : dst_x;
    const float* rp0 = X + (size_t)(row0 + ln)*HD;
    const float* rp1 = rp0 + (size_t)16*HD;
    short8 a0[4], a1[4];
#pragma unroll
    for (int kc = 0; kc < 4; ++kc) {
        float4 f0 = *(const float4*)(rp0 + kc*32 + quad*8);
        float4 f1 = *(const float4*)(rp0 + kc*32 + quad*8 + 4);
        float4 g0 = *(const float4*)(rp1 + kc*32 + quad*8);
        float4 g1 = *(const float4*)(rp1 + kc*32 + quad*8 + 4);
        u16 tb[8] = { f2b(f0.x), f2b(f0.y), f2b(f0.z), f2b(f0.w),
                      f2b(f1.x), f2b(f1.y), f2b(f1.z), f2b(f1.w) };
        a0[kc] = *(short8*)tb;
        u16 tc[8] = { f2b(g0.x), f2b(g0.y), f2b(g0.z), f2b(g0.w),
                      f2b(g1.x), f2b(g1.y), f2b(g1.z), f2b(g1.w) };
        a1[kc] = *(short8*)tc;
    }

    // stage phase-1 weights (32 KB, cooperative, coalesced 16B)
    const u16* Wpk = is_src ? Wsrc_pk : Wdst_pk;
#pragma unroll
    for (int it = 0; it < 8; ++it) {
        short8 v = ld8(Wpk + (size_t)(it*256 + t)*8);
        *(short8*)(&wlds[(it*256 + t)*8]) = v;
    }
    __syncthreads();

    const float* bb_ = is_src ? bsrc : bdst;
    const float* wa  = is_src ? wattn : wattn + HD;
    float* sout      = is_src ? s1 : s2;

    // ---- tanh-dot (exp2/rcp refactor), two tiles share each B-frag
    float v0[4] = {0,0,0,0}, v1[4] = {0,0,0,0};
    float ws = 0.f;
#pragma unroll
    for (int tt = 0; tt < 8; ++tt) {
        const float bb = bb_[tt*16 + ln] * TL2E;
        const float ww = wa[tt*16 + ln];
        f32x4 acc0 = {bb, bb, bb, bb};
        f32x4 acc1 = {bb, bb, bb, bb};
#pragma unroll
        for (int kc = 0; kc < 4; ++kc) {
            short8 bf = ld8(&wlds[(size_t)((kc*8 + tt)*64 + lane)*8]);
            acc0 = __builtin_amdgcn_mfma_f32_16x16x32_bf16(a0[kc], bf, acc0, 0, 0, 0);
            acc1 = __builtin_amdgcn_mfma_f32_16x16x32_bf16(a1[kc], bf, acc1, 0, 0, 0);
        }
        ws += ww;
#pragma unroll
        for (int r = 0; r < 4; ++r) {
            v0[r] = fmaf(ww, RCP(EXP2(acc0[r]) + 1.f), v0[r]);
            v1[r] = fmaf(ww, RCP(EXP2(acc1[r]) + 1.f), v1[r]);
        }
    }
#pragma unroll
    for (int off = 8; off >= 1; off >>= 1) {
        ws += __shfl_xor(ws, off);
#pragma unroll
        for (int r = 0; r < 4; ++r) {
            v0[r] += __shfl_xor(v0[r], off);
            v1[r] += __shfl_xor(v1[r], off);
        }
    }
    if (ln == 0) {
#pragma unroll
        for (int r = 0; r < 4; ++r) {
            sout[row0 + quad*4 + r]      = fmaf(-2.f, v0[r], ws);
            sout[row0 + 16 + quad*4 + r] = fmaf(-2.f, v1[r], ws);
        }
    }

    if (!is_src) return;

    // ---- restage with Wsm, then srcmsg path
    __syncthreads();
#pragma unroll
    for (int it = 0; it < 8; ++it) {
        short8 v = ld8(Wsm_pk + (size_t)(it*256 + t)*8);
        *(short8*)(&wlds[(it*256 + t)*8]) = v;
    }
    __syncthreads();

    u16* slab = &tlds[w][0];
#pragma unroll
    for (int tile = 0; tile < 2; ++tile) {
#pragma unroll
        for (int tt = 0; tt < 8; ++tt) {
            const float bs = bsm[tt*16 + ln];
            f32x4 acc = {bs, bs, bs, bs};
#pragma unroll
            for (int kc = 0; kc < 4; ++kc) {
                short8 bf = ld8(&wlds[(size_t)((kc*8 + tt)*64 + lane)*8]);
                acc = __builtin_amdgcn_mfma_f32_16x16x32_bf16(
                          tile ? a1[kc] : a0[kc], bf, acc, 0, 0, 0);
            }
            // swizzled write: row = quad*4+r (row>>2 == quad), col blk tt^quad
#pragma unroll
            for (int r = 0; r < 4; ++r)
                slab[(quad*4 + r)*128 + ((tt ^ quad) << 4) + ln] = f2b(acc[r]);
        }
        // per-wave readback (DS in-order within wave; no barrier needed)
#pragma unroll
        for (int r2 = 0; r2 < 4; ++r2) {
            const int row = r2*4 + quad;          // row>>2 == r2
            const int c = ln*8;
            const int sidx = row*128 + (((c >> 4) ^ r2) << 4) + (c & 15);
            short8 val = *(const short8*)(&slab[sidx]);
            *(short8*)(srcmsgb + (size_t)(row0 + tile*16 + row)*HD + c) = val;
        }
    }
}

// ---------------------------------------------------------------------------
// scan1: per-1024-chunk exclusive scan of cnt into rowptr, block sums to bsum
// ---------------------------------------------------------------------------
__global__ __launch_bounds__(1024) void scan1_kernel(
    const int* __restrict__ cnt, int* __restrict__ excl, int* __restrict__ bsum)
{
    __shared__ int buf[1024];
    const int t = threadIdx.x;
    const int i = blockIdx.x * 1024 + t;
    int v = (i < NDST) ? cnt[i] : 0;
    buf[t] = v;
    __syncthreads();
    for (int off = 1; off < 1024; off <<= 1) {
        int tv = (t >= off) ? buf[t - off] : 0;
        __syncthreads();
        buf[t] += tv;
        __syncthreads();
    }
    if (i < NDST) excl[i] = buf[t] - v;
    if (t == 1023) bsum[blockIdx.x] = buf[1023];
}

// ---------------------------------------------------------------------------
// scan23: every block redundantly wave-scans the 49 chunk sums, then applies
// the offset to its rowptr slice.
// ---------------------------------------------------------------------------
__global__ __launch_bounds__(256) void scan23_kernel(
    const int* __restrict__ bsum, int* __restrict__ rowptr)
{
    __shared__ int pref[64];
    const int t = threadIdx.x;
    const int NB = (NDST + 1023) / 1024;     // 49
    if (t < 64) {
        int orig = (t < NB) ? bsum[t] : 0;
        int v = orig;
        for (int off = 1; off < 64; off <<= 1) {
            int u = __shfl_up(v, off);
            if (t >= off) v += u;
        }
        pref[t] = v - orig;                  // exclusive prefix
        if (blockIdx.x == 0 && t == NB - 1) rowptr[NDST] = v;  // total
    }
    __syncthreads();
    const int i = blockIdx.x * 256 + t;
    if (i < NDST) rowptr[i] += pref[i >> 10];
}

// ---------------------------------------------------------------------------
// edge_score: 16 edges / wave. Reads edge_attr f32 directly; tanh-dot in
// exp2/rcp form; score kept in log2-domain (no-max softmax safe). Atomic-free
// scatter: pos = rowptr[dst] + rank[e]. Record int4 {src, e, score, 0}.
// ---------------------------------------------------------------------------
__global__ __launch_bounds__(256) void edge_score_kernel(
    const int* __restrict__ ei, const float* __restrict__ eattr,
    const u16* __restrict__ We_pk, const float* __restrict__ be,
    const float* __restrict__ wattn, const float* __restrict__ battn,
    const float* __restrict__ s1, const float* __restrict__ s2,
    const int* __restrict__ rowptr, const int* __restrict__ rank,
    int4* __restrict__ ev16)
{
    const int t = threadIdx.x;
    const int w = t >> 6, lane = t & 63;
    const int ln = lane & 15, quad = lane >> 4;
    const int e0 = (blockIdx.x * 4 + w) * 16;
    if (e0 >= NE) return;                  // NE%16==0, no partial tiles

    const float* ap = eattr + (size_t)(e0 + ln)*EDIM + quad*8;
    float4 f0 = *(const float4*)(ap);
    float4 f1 = *(const float4*)(ap + 4);
    u16 ab[8] = { f2b(f0.x), f2b(f0.y), f2b(f0.z), f2b(f0.w),
                  f2b(f1.x), f2b(f1.y), f2b(f1.z), f2b(f1.w) };
    short8 a = *(short8*)ab;

    const float* wa3 = wattn + 2*HD;
    float v[4] = {0.f, 0.f, 0.f, 0.f};
    float ws = 0.f;
#pragma unroll
    for (int tt = 0; tt < 8; ++tt) {
        const float bb = be[tt*16 + ln] * TL2E;
        const float ww = wa3[tt*16 + ln];
        f32x4 acc = {bb, bb, bb, bb};
        short8 b = ld8(We_pk + (size_t)(tt*64 + lane)*8);
        acc = __builtin_amdgcn_mfma_f32_16x16x32_bf16(a, b, acc, 0, 0, 0);
        ws += ww;
#pragma unroll
        for (int r = 0; r < 4; ++r)
            v[r] = fmaf(ww, RCP(EXP2(acc[r]) + 1.f), v[r]);
    }
#pragma unroll
    for (int off = 8; off >= 1; off >>= 1) {
        ws += __shfl_xor(ws, off);
#pragma unroll
        for (int r = 0; r < 4; ++r) v[r] += __shfl_xor(v[r], off);
    }
    // redistribute: lane ln gets the dot for edge e0+ln
    const int srcq = (ln >> 2) << 4;
    float sv0 = __shfl(v[0], srcq);
    float sv1 = __shfl(v[1], srcq);
    float sv2 = __shfl(v[2], srcq);
    float sv3 = __shfl(v[3], srcq);
    const int rr = ln & 3;
    float vlo = (rr & 1) ? sv1 : sv0;
    float vhi = (rr & 1) ? sv3 : sv2;
    float vv  = (rr & 2) ? vhi : vlo;

    if (quad == 0) {                       // 16 lanes, one edge each
        const int e = e0 + ln;
        const int srcn = ei[e];
        const int dstn = ei[NE + e];
        float sc = (fmaf(-2.f, vv, ws) + s1[srcn] + s2[dstn] + battn[0]) * L2E;
        const int pos = rowptr[dstn] + rank[e];
        ev16[pos] = make_int4(srcn, e, __float_as_int(sc), 0);
    }
}

// ---------------------------------------------------------------------------
// dst_agg: 1 wave per dst, single pass (no-max softmax): accumulate
// unnormalized w=exp2(sc), sum(w), sum(w*msg), sum(w*ea); normalize at end.
// msg row: 16 lanes x 16B bf16; ea row: 8 lanes x 16B f32 (one cache line).
// ---------------------------------------------------------------------------
__global__ __launch_bounds__(256) void dst_agg_kernel(
    const int4* __restrict__ ev16, const int* __restrict__ rowptr,
    const u16* __restrict__ srcmsgb, const float* __restrict__ eattr,
    const float* __restrict__ c2,
    u16* __restrict__ aggSb, u16* __restrict__ weab)
{
    const int lane = threadIdx.x & 63;
    const int d = blockIdx.x * 4 + (threadIdx.x >> 6);
    const int el = lane >> 4, c = lane & 15;
    const int start = rowptr[d], end = rowptr[d + 1];

    if (start == end) {
        if (el == 0) {
            u16 z[8];
#pragma unroll
            for (int j = 0; j < 8; ++j) z[j] = f2b(-c2[c*8 + j]);
            *(short8*)(aggSb + (size_t)d*HD + c*8) = *(short8*)z;
            if (c < 8) {
                u16 zz[4] = {0,0,0,0};
                *(ushort4*)(weab + (size_t)d*EDIM + c*4) = *(ushort4*)zz;
            }
        }
        return;
    }

    float sacc = 0.f;
    float acc[8]  = {0,0,0,0,0,0,0,0};
    float wacc[4] = {0,0,0,0};

    int icur = start + el;
    bool vcur = (icur < end);
    int iicur = vcur ? icur : start;
    int4 q = ev16[iicur];

    for (int i0 = start; i0 < end; i0 += 4) {
        const float wgt = vcur ? EXP2(__int_as_float(q.z)) : 0.f;
        const int   srow = q.x;
        const int   ecur = q.y;
        // prefetch next record (clamped; harmless re-read of ev16[start])
        const int inx = i0 + 4 + el;
        vcur = (inx < end);
        iicur = vcur ? inx : start;
        q = ev16[iicur];

        sacc += wgt;
        short8 sm = ld8(srcmsgb + (size_t)srow*HD + c*8);
#pragma unroll
        for (int j = 0; j < 8; ++j)
            acc[j] = fmaf(wgt, b2f(((u16*)&sm)[j]), acc[j]);
        if (c < 8) {
            float4 f = *(const float4*)(eattr + (size_t)ecur*EDIM + c*4);
            wacc[0] = fmaf(wgt, f.x, wacc[0]);
            wacc[1] = fmaf(wgt, f.y, wacc[1]);
            wacc[2] = fmaf(wgt, f.z, wacc[2]);
            wacc[3] = fmaf(wgt, f.w, wacc[3]);
        }
    }
#pragma unroll
    for (int off = 16; off <= 32; off <<= 1) {
        sacc += __shfl_xor(sacc, off);
#pragma unroll
        for (int j = 0; j < 8; ++j) acc[j] += __shfl_xor(acc[j], off);
#pragma unroll
        for (int j = 0; j < 4; ++j) wacc[j] += __shfl_xor(wacc[j], off);
    }
    const float inv = RCP(sacc);
    if (el == 0) {
        u16 o[8];
#pragma unroll
        for (int j = 0; j < 8; ++j) o[j] = f2b(acc[j] * inv);
        *(short8*)(aggSb + (size_t)d*HD + c*8) = *(short8*)o;
        if (c < 8) {
            u16 o2[4];
#pragma unroll
            for (int j = 0; j < 4; ++j) o2[j] = f2b(wacc[j] * inv);
            *(ushort4*)(weab + (size_t)d*EDIM + c*4) = *(ushort4*)o2;
        }
    }
}

// ---------------------------------------------------------------------------
// final: out = LN(dst_x@W1p + aggSb@Wout2 + weab@W3 + bias2) * gamma + beta
// per 16 dst rows / wave; dst_x read f32 + converted in-reg.
// ---------------------------------------------------------------------------
__global__ __launch_bounds__(256) void final_kernel(
    const float* __restrict__ dst_x, const u16* __restrict__ aggSb,
    const u16* __restrict__ weab,
    const u16* __restrict__ W1_pk, const u16* __restrict__ W2_pk,
    const u16* __restrict__ W3_pk, const float* __restrict__ bias2,
    const float* __restrict__ gamma, const float* __restrict__ beta,
    float* __restrict__ out)
{
    const int t = threadIdx.x;
    const int w = t >> 6, lane = t & 63;
    const int ln = lane & 15, quad = lane >> 4;
    int row0 = (blockIdx.x * 4 + w) * 16;
    if (row0 > NDST - 16) row0 = NDST - 16;

    const float* rp = dst_x + (size_t)(row0 + ln)*HD;
    short8 a1[4], a2[4], a3;
#pragma unroll
    for (int kc = 0; kc < 4; ++kc) {
        float4 f0 = *(const float4*)(rp + kc*32 + quad*8);
        float4 f1 = *(const float4*)(rp + kc*32 + quad*8 + 4);
        u16 tb[8] = { f2b(f0.x), f2b(f0.y), f2b(f0.z), f2b(f0.w),
                      f2b(f1.x), f2b(f1.y), f2b(f1.z), f2b(f1.w) };
        a1[kc] = *(short8*)tb;
        a2[kc] = ld8(aggSb + (size_t)(row0 + ln)*HD + kc*32 + quad*8);
    }
    a3 = ld8(weab + (size_t)(row0 + ln)*EDIM + quad*8);

    f32x4 accs[8];
#pragma unroll
    for (int tt = 0; tt < 8; ++tt) {
        const float bb = bias2[tt*16 + ln];
        f32x4 acc = {bb, bb, bb, bb};
#pragma unroll
        for (int kc = 0; kc < 4; ++kc) {
            short8 b = ld8(W1_pk + (size_t)((kc*8 + tt)*64 + lane)*8);
            acc = __builtin_amdgcn_mfma_f32_16x16x32_bf16(a1[kc], b, acc, 0, 0, 0);
        }
#pragma unroll
        for (int kc = 0; kc < 4; ++kc) {
            short8 b = ld8(W2_pk + (size_t)((kc*8 + tt)*64 + lane)*8);
            acc = __builtin_amdgcn_mfma_f32_16x16x32_bf16(a2[kc], b, acc, 0, 0, 0);
        }
        {
            short8 b = ld8(W3_pk + (size_t)(tt*64 + lane)*8);
            acc = __builtin_amdgcn_mfma_f32_16x16x32_bf16(a3, b, acc, 0, 0, 0);
        }
        accs[tt] = acc;
    }

    const float gl[8] = { gamma[ln], gamma[16+ln], gamma[32+ln], gamma[48+ln],
                          gamma[64+ln], gamma[80+ln], gamma[96+ln], gamma[112+ln] };
    const float bl[8] = { beta[ln], beta[16+ln], beta[32+ln], beta[48+ln],
                          beta[64+ln], beta[80+ln], beta[96+ln], beta[112+ln] };
#pragma unroll
    for (int r = 0; r < 4; ++r) {
        float s = 0.f, qq = 0.f;
#pragma unroll
        for (int tt = 0; tt < 8; ++tt) {
            float u = accs[tt][r];
            s += u; qq += u*u;
        }
#pragma unroll
        for (int off = 8; off >= 1; off >>= 1) {
            s  += __shfl_xor(s, off);
            qq += __shfl_xor(qq, off);
        }
        const float mean = s * (1.f / HD);
        const float var  = qq * (1.f / HD) - mean * mean;
        const float rstd = rsqrtf(var + LN_EPS);
        const int row = row0 + quad*4 + r;
#pragma unroll
        for (int tt = 0; tt < 8; ++tt)
            out[(size_t)row*HD + tt*16 + ln] =
                (accs[tt][r] - mean) * rstd * gl[tt] + bl[tt];
    }
}

// ---------------------------------------------------------------------------
extern "C" void kernel_launch(void* const* d_in, const int* in_sizes, int n_in,
                              void* d_out, int out_size, void* d_ws, size_t ws_size,
                              hipStream_t stream)
{
    const float* src_x = (const float*)d_in[0];
    const float* dst_x = (const float*)d_in[1];
    const int*   ei    = (const int*)d_in[2];
    const float* eattr = (const float*)d_in[3];
    const float* Wsrc  = (const float*)d_in[4];
    const float* bsrc  = (const float*)d_in[5];
    const float* Wdst  = (const float*)d_in[6];
    const float* bdst  = (const float*)d_in[7];
    const float* We    = (const float*)d_in[8];
    const float* be    = (const float*)d_in[9];
    const float* Wattn = (const float*)d_in[10];
    const float* battn = (const float*)d_in[11];
    const float* Wmsg  = (const float*)d_in[12];
    const float* bmsg  = (const float*)d_in[13];
    const float* Wout  = (const float*)d_in[14];
    const float* bout  = (const float*)d_in[15];
    const float* gamma = (const float*)d_in[16];
    const float* beta  = (const float*)d_in[17];
    float* out = (float*)d_out;

    float* ws = (float*)d_ws;
    u16* srcmsgb = (u16*)(ws + 0);            // 6.4M u16
    u16* aggSb   = (u16*)(ws + 3200000);      // 6.4M u16
    u16* weab    = (u16*)(ws + 6400000);      // 1.6M u16
    float* s1    = ws + 7200000;              // 50048
    float* s2    = ws + 7250048;              // 50048
    float* Wsm   = ws + 7300096;              // 16384
    float* bsm   = ws + 7316480;              // 128
    float* WeMsg = ws + 7316608;              // 4096
    float* c2    = ws + 7320704;              // 128
    float* bias2 = ws + 7320832;              // 128
    u16* Wsrc_pk = (u16*)(ws + 7320960);      // 16384 u16
    u16* Wdst_pk = (u16*)(ws + 7329152);
    u16* Wsm_pk  = (u16*)(ws + 7337344);
    u16* W1_pk   = (u16*)(ws + 7345536);
    u16* W2_pk   = (u16*)(ws + 7353728);
    u16* We_pk   = (u16*)(ws + 7361920);      // 4096 u16
    u16* W3_pk   = (u16*)(ws + 7363968);      // 4096 u16
    int* rowptr  = (int*)(ws + 7366016);      // 50016
    int* cnt     = (int*)(ws + 7416032);      // 50016
    int* bsum    = (int*)(ws + 7466048);      // 64
    int* rank    = (int*)(ws + 7466112);      // 500000
    int4* ev16   = (int4*)(ws + 7966112);     // 500000 int4 (16B-aligned)

    fold1_kernel<<<553, 128, 0, stream>>>(Wsrc, bsrc, We, be, Wmsg, bmsg,
                                          Wsm, bsm, WeMsg, c2, cnt);
    pack_all_kernel<<<177, 64, 0, stream>>>(Wsrc, Wdst, Wsm, Wout, We, WeMsg,
                                            c2, bout,
                                            Wsrc_pk, Wdst_pk, Wsm_pk, W1_pk,
                                            W2_pk, We_pk, W3_pk, bias2);

    mega_kernel<<<2*NBLK + HB4, 256, 0, stream>>>(
        src_x, dst_x, ei, Wsrc_pk, Wsm_pk, Wdst_pk,
        bsrc, bsm, bdst, Wattn, s1, s2, srcmsgb, cnt, rank);

    scan1_kernel<<<(NDST + 1023) / 1024, 1024, 0, stream>>>(cnt, rowptr, bsum);
    scan23_kernel<<<(NDST + 255) / 256, 256, 0, stream>>>(bsum, rowptr);

    edge_score_kernel<<<(NE/16 + 3) / 4, 256, 0, stream>>>(
        ei, eattr, We_pk, be, Wattn, battn, s1, s2, rowptr, rank, ev16);

    dst_agg_kernel<<<NDST / 4, 256, 0, stream>>>(ev16, rowptr, srcmsgb,
                                                 eattr, c2, aggSb, weab);

    final_kernel<<<(NDST/16 + 3) / 4, 256, 0, stream>>>(
        dst_x, aggSb, weab, W1_pk, W2_pk, W3_pk, bias2, gamma, beta, out);
}

// Round 6
// 295.656 us; speedup vs baseline: 1.6671x; 1.0254x over previous
//
#include <hip/hip_runtime.h>
#include <math.h>

#define NSRC 50000
#define NDST 50000
#define NE   500000
#define HD   128
#define EDIM 32
#define LN_EPS 1e-5f

typedef __attribute__((ext_vector_type(8))) short short8;   // 8 bf16 = 4 VGPR
typedef __attribute__((ext_vector_type(4))) float f32x4;
typedef unsigned short u16;

#define TL2E 2.8853900817779268f   /* 2*log2(e) */
#define L2E  1.4426950408889634f   /* log2(e)   */

__device__ __forceinline__ float EXP2(float x) {
#if __has_builtin(__builtin_amdgcn_exp2f)
    return __builtin_amdgcn_exp2f(x);
#else
    return exp2f(x);
#endif
}
__device__ __forceinline__ float RCP(float x) {
#if __has_builtin(__builtin_amdgcn_rcpf)
    return __builtin_amdgcn_rcpf(x);
#else
    return 1.f / x;
#endif
}
__device__ __forceinline__ u16 f2b(float x) {           // f32 -> bf16 RNE
    unsigned u = __float_as_uint(x);
    return (u16)((u + 0x7FFFu + ((u >> 16) & 1u)) >> 16);
}
__device__ __forceinline__ float b2f(u16 h) {
    return __uint_as_float(((unsigned)h) << 16);
}
__device__ __forceinline__ short8 ld8(const u16* p) { return *(const short8*)p; }

// ---------------------------------------------------------------------------
// fold1: Wsm = Wsrc@Wmsg, bsm = bsrc@Wmsg + bmsg, WeMsg = We@Wmsg, c2 = be@Wmsg
// (128 threads span output column j -> coalesced Wmsg reads, 1 dot/thread).
// Blocks r >= 162 zero the histogram counters (replaces memset launch).
// ---------------------------------------------------------------------------
__global__ __launch_bounds__(128) void fold1_kernel(
    const float* __restrict__ Wsrc, const float* __restrict__ bsrc,
    const float* __restrict__ We,   const float* __restrict__ be,
    const float* __restrict__ Wmsg, const float* __restrict__ bmsg,
    float* __restrict__ Wsm, float* __restrict__ bsm,
    float* __restrict__ WeMsg, float* __restrict__ c2,
    int* __restrict__ cnt)
{
    const int j = threadIdx.x;
    const int r = blockIdx.x;
    if (r >= 162) {
        int i = (r - 162) * 128 + j;
        if (i < NDST + 16) cnt[i] = 0;
        return;
    }
    float s = 0.f;
    if (r < 128) {
        for (int k = 0; k < 128; ++k) s += Wsrc[r*HD + k] * Wmsg[k*HD + j];
        Wsm[r*HD + j] = s;
    } else if (r < 160) {
        const int rr = r - 128;
        for (int k = 0; k < 128; ++k) s += We[rr*HD + k] * Wmsg[k*HD + j];
        WeMsg[rr*HD + j] = s;
    } else if (r == 160) {
        for (int k = 0; k < 128; ++k) s += bsrc[k] * Wmsg[k*HD + j];
        bsm[j] = s + bmsg[j];
    } else {
        for (int k = 0; k < 128; ++k) s += be[k] * Wmsg[k*HD + j];
        c2[j] = s;
    }
}

// ---------------------------------------------------------------------------
// pack_all: pack f32 [K x 128] weights into bf16 MFMA B-fragment layout.
// Wsrc/Wdst/We pre-scaled by 2*log2(e) (tanh-dot exp2/rcp refactor).
// W1 = Wout1 + I inline. W3 = WeMsg@Wout2 and bias2 = bout + c2@Wout2 inline.
// Block 177: constant folding for the tanh-dot paths:
//   wa{1,2,3}s = -2*log2e * wattn slices; b{src,dst,e}s = 2*log2e * biases;
//   consts = {L2E*sum(wa1), L2E*sum(wa2), L2E*(sum(wa3)+battn)}.
// With these, s1/s2/scores are produced directly in log2-domain:
//   score_l2 = K + sum(wa_s * rcp(exp2(x_s)+1))   (no ws ladder needed).
// ---------------------------------------------------------------------------
__global__ __launch_bounds__(64) void pack_all_kernel(
    const float* __restrict__ Wsrc, const float* __restrict__ Wdst,
    const float* __restrict__ Wsm,  const float* __restrict__ Wout,
    const float* __restrict__ We,   const float* __restrict__ WeMsg,
    const float* __restrict__ c2,   const float* __restrict__ bout,
    const float* __restrict__ bsrc, const float* __restrict__ bdst,
    const float* __restrict__ be,   const float* __restrict__ battn,
    const float* __restrict__ wattn,
    u16* __restrict__ Wsrc_pk, u16* __restrict__ Wdst_pk,
    u16* __restrict__ Wsm_pk,  u16* __restrict__ W1_pk,
    u16* __restrict__ W2_pk,   u16* __restrict__ We_pk,
    u16* __restrict__ W3_pk,   float* __restrict__ bias2,
    float* __restrict__ wa1s, float* __restrict__ wa2s,
    float* __restrict__ wa3s, float* __restrict__ bsrcs,
    float* __restrict__ bdsts, float* __restrict__ bes,
    float* __restrict__ consts)
{
    const int b = blockIdx.x;
    const int lane = threadIdx.x;
    const int ln = lane & 15, quad = lane >> 4;
    const float* Wout2 = Wout + HD*HD;

    if (b == 177) {                        // const folding
        float sa1 = 0.f, sa2 = 0.f, sa3 = 0.f;
#pragma unroll
        for (int h = 0; h < 2; ++h) {
            const int col = lane + h*64;
            float a1 = wattn[col], a2 = wattn[HD + col], a3 = wattn[2*HD + col];
            wa1s[col] = a1 * (-2.f * L2E);
            wa2s[col] = a2 * (-2.f * L2E);
            wa3s[col] = a3 * (-2.f * L2E);
            bsrcs[col] = bsrc[col] * TL2E;
            bdsts[col] = bdst[col] * TL2E;
            bes[col]   = be[col]   * TL2E;
            sa1 += a1; sa2 += a2; sa3 += a3;
        }
#pragma unroll
        for (int off = 32; off >= 1; off >>= 1) {
            sa1 += __shfl_xor(sa1, off);
            sa2 += __shfl_xor(sa2, off);
            sa3 += __shfl_xor(sa3, off);
        }
        if (lane == 0) {
            consts[0] = L2E * sa1;
            consts[1] = L2E * sa2;
            consts[2] = L2E * (sa3 + battn[0]);
        }
        return;
    }
    if (b == 176) {                        // bias2 = bout + c2@Wout2
#pragma unroll
        for (int h = 0; h < 2; ++h) {
            const int col = lane + h*64;
            float s = 0.f;
            for (int k = 0; k < 128; ++k) s += c2[k] * Wout2[k*HD + col];
            bias2[col] = bout[col] + s;
        }
        return;
    }
    if (b >= 168) {                        // W3 = WeMsg@Wout2 (32x128), packed
        const int t = b - 168;
        const int jj = t*16 + ln;
        float sacc[8] = {0,0,0,0,0,0,0,0};
        for (int k = 0; k < 128; ++k) {
            const float w2 = Wout2[k*HD + jj];
#pragma unroll
            for (int j = 0; j < 8; ++j)
                sacc[j] = fmaf(WeMsg[(quad*8 + j)*HD + k], w2, sacc[j]);
        }
        u16 tmp[8];
#pragma unroll
        for (int j = 0; j < 8; ++j) tmp[j] = f2b(sacc[j]);
        *(short8*)(W3_pk + (size_t)(t*64 + lane)*8) = *(short8*)tmp;
        return;
    }

    const float* src; u16* dst; int lb; float scl = 1.f; bool addI = false;
    if      (b < 32)  { src = Wsrc; dst = Wsrc_pk; lb = b;       scl = TL2E; }
    else if (b < 64)  { src = Wdst; dst = Wdst_pk; lb = b - 32;  scl = TL2E; }
    else if (b < 96)  { src = Wsm;  dst = Wsm_pk;  lb = b - 64; }
    else if (b < 128) { src = Wout; dst = W1_pk;   lb = b - 96;  addI = true; }
    else if (b < 160) { src = Wout2;dst = W2_pk;   lb = b - 128; }
    else              { src = We;   dst = We_pk;   lb = b - 160; scl = TL2E; }
    const int kc = lb >> 3, t = lb & 7;
    u16 tmp[8];
#pragma unroll
    for (int j = 0; j < 8; ++j) {
        const int i = kc*32 + quad*8 + j, jj = t*16 + ln;
        float v = src[(size_t)i*HD + jj] * scl;
        if (addI && i == jj) v += 1.f;
        tmp[j] = f2b(v);
    }
    *(short8*)(dst + (size_t)(lb*64 + lane)*8) = *(short8*)tmp;
}

// ---------------------------------------------------------------------------
// mega: block-range fusion:
//   [0, NBLK)      node: s1 tanh-dot + srcmsgb, 32 rows/wave, LDS-staged W
//   [NBLK, 2NBLK)  dst:  s2 tanh-dot, 32 rows/wave, LDS-staged W
//   [2NBLK, +HB4)  hist: cnt[dst]++ / rank, 4 edges per thread
// s1/s2 now produced in log2-domain (wa prescaled, K const) -> no ws ladder.
// ---------------------------------------------------------------------------
#define NBLK 391
#define HB4 ((NE/4 + 255) / 256)

__global__ __launch_bounds__(256) void mega_kernel(
    const float* __restrict__ src_x, const float* __restrict__ dst_x,
    const int* __restrict__ ei,
    const u16* __restrict__ Wsrc_pk, const u16* __restrict__ Wsm_pk,
    const u16* __restrict__ Wdst_pk,
    const float* __restrict__ bsrcs, const float* __restrict__ bsm,
    const float* __restrict__ bdsts,
    const float* __restrict__ wa1s, const float* __restrict__ wa2s,
    const float* __restrict__ consts,
    float* __restrict__ s1, float* __restrict__ s2,
    u16* __restrict__ srcmsgb, int* __restrict__ cnt, int* __restrict__ rank)
{
    __shared__ __align__(16) u16 wlds[16384];      // 32 KB staged weights
    __shared__ __align__(16) u16 tlds[4][2048];    // 16 KB per-wave transpose
    const int t = threadIdx.x;
    const int blk = blockIdx.x;

    if (blk >= 2*NBLK) {                 // ---- hist path (4 edges/thread)
        const int idx = (blk - 2*NBLK) * 256 + t;
        if (idx < NE/4) {
            int4 d4 = ((const int4*)(ei + NE))[idx];
            int4 r4;
            r4.x = atomicAdd(&cnt[d4.x], 1);
            r4.y = atomicAdd(&cnt[d4.y], 1);
            r4.z = atomicAdd(&cnt[d4.z], 1);
            r4.w = atomicAdd(&cnt[d4.w], 1);
            ((int4*)rank)[idx] = r4;
        }
        return;
    }

    const int w = t >> 6, lane = t & 63;
    const int ln = lane & 15, quad = lane >> 4;
    const bool is_src = (blk < NBLK);
    const int b = is_src ? blk : blk - NBLK;
    int row0 = b * 128 + w * 32;
    if (row0 > NSRC - 32) row0 = NSRC - 32;       // dup writes benign

    // x loads (2 row-tiles), converted to bf16 A-frags in-register
    const float* X = is_src ? src_x : dst_x;
    const float* rp0 = X + (size_t)(row0 + ln)*HD;
    const float* rp1 = rp0 + (size_t)16*HD;
    short8 a0[4], a1[4];
#pragma unroll
    for (int kc = 0; kc < 4; ++kc) {
        float4 f0 = *(const float4*)(rp0 + kc*32 + quad*8);
        float4 f1 = *(const float4*)(rp0 + kc*32 + quad*8 + 4);
        float4 g0 = *(const float4*)(rp1 + kc*32 + quad*8);
        float4 g1 = *(const float4*)(rp1 + kc*32 + quad*8 + 4);
        u16 tb[8] = { f2b(f0.x), f2b(f0.y), f2b(f0.z), f2b(f0.w),
                      f2b(f1.x), f2b(f1.y), f2b(f1.z), f2b(f1.w) };
        a0[kc] = *(short8*)tb;
        u16 tc[8] = { f2b(g0.x), f2b(g0.y), f2b(g0.z), f2b(g0.w),
                      f2b(g1.x), f2b(g1.y), f2b(g1.z), f2b(g1.w) };
        a1[kc] = *(short8*)tc;
    }

    // stage phase-1 weights (32 KB, cooperative, coalesced 16B)
    const u16* Wpk = is_src ? Wsrc_pk : Wdst_pk;
#pragma unroll
    for (int it = 0; it < 8; ++it) {
        short8 v = ld8(Wpk + (size_t)(it*256 + t)*8);
        *(short8*)(&wlds[(it*256 + t)*8]) = v;
    }
    __syncthreads();

    const float* bb_ = is_src ? bsrcs : bdsts;
    const float* wa  = is_src ? wa1s : wa2s;
    const float  K   = consts[is_src ? 0 : 1];
    float* sout      = is_src ? s1 : s2;

    // ---- tanh-dot (log2-domain), two tiles share each B-frag
    float v0[4] = {0,0,0,0}, v1[4] = {0,0,0,0};
#pragma unroll
    for (int tt = 0; tt < 8; ++tt) {
        const float bb = bb_[tt*16 + ln];
        const float ww = wa[tt*16 + ln];
        f32x4 acc0 = {bb, bb, bb, bb};
        f32x4 acc1 = {bb, bb, bb, bb};
#pragma unroll
        for (int kc = 0; kc < 4; ++kc) {
            short8 bf = ld8(&wlds[(size_t)((kc*8 + tt)*64 + lane)*8]);
            acc0 = __builtin_amdgcn_mfma_f32_16x16x32_bf16(a0[kc], bf, acc0, 0, 0, 0);
            acc1 = __builtin_amdgcn_mfma_f32_16x16x32_bf16(a1[kc], bf, acc1, 0, 0, 0);
        }
#pragma unroll
        for (int r = 0; r < 4; ++r) {
            v0[r] = fmaf(ww, RCP(EXP2(acc0[r]) + 1.f), v0[r]);
            v1[r] = fmaf(ww, RCP(EXP2(acc1[r]) + 1.f), v1[r]);
        }
    }
#pragma unroll
    for (int off = 8; off >= 1; off >>= 1) {
#pragma unroll
        for (int r = 0; r < 4; ++r) {
            v0[r] += __shfl_xor(v0[r], off);
            v1[r] += __shfl_xor(v1[r], off);
        }
    }
    if (ln == 0) {
#pragma unroll
        for (int r = 0; r < 4; ++r) {
            sout[row0 + quad*4 + r]      = K + v0[r];
            sout[row0 + 16 + quad*4 + r] = K + v1[r];
        }
    }

    if (!is_src) return;

    // ---- restage with Wsm, then srcmsg path
    __syncthreads();
#pragma unroll
    for (int it = 0; it < 8; ++it) {
        short8 v = ld8(Wsm_pk + (size_t)(it*256 + t)*8);
        *(short8*)(&wlds[(it*256 + t)*8]) = v;
    }
    __syncthreads();

    u16* slab = &tlds[w][0];
#pragma unroll
    for (int tile = 0; tile < 2; ++tile) {
#pragma unroll
        for (int tt = 0; tt < 8; ++tt) {
            const float bs = bsm[tt*16 + ln];
            f32x4 acc = {bs, bs, bs, bs};
#pragma unroll
            for (int kc = 0; kc < 4; ++kc) {
                short8 bf = ld8(&wlds[(size_t)((kc*8 + tt)*64 + lane)*8]);
                acc = __builtin_amdgcn_mfma_f32_16x16x32_bf16(
                          tile ? a1[kc] : a0[kc], bf, acc, 0, 0, 0);
            }
            // swizzled write: row = quad*4+r (row>>2 == quad), col blk tt^quad
#pragma unroll
            for (int r = 0; r < 4; ++r)
                slab[(quad*4 + r)*128 + ((tt ^ quad) << 4) + ln] = f2b(acc[r]);
        }
        // per-wave readback (DS in-order within wave; no barrier needed)
#pragma unroll
        for (int r2 = 0; r2 < 4; ++r2) {
            const int row = r2*4 + quad;          // row>>2 == r2
            const int c = ln*8;
            const int sidx = row*128 + (((c >> 4) ^ r2) << 4) + (c & 15);
            short8 val = *(const short8*)(&slab[sidx]);
            *(short8*)(srcmsgb + (size_t)(row0 + tile*16 + row)*HD + c) = val;
        }
    }
}

// ---------------------------------------------------------------------------
// scan1: per-1024-chunk exclusive scan of cnt into rowptr, block sums to bsum
// ---------------------------------------------------------------------------
__global__ __launch_bounds__(1024) void scan1_kernel(
    const int* __restrict__ cnt, int* __restrict__ excl, int* __restrict__ bsum)
{
    __shared__ int buf[1024];
    const int t = threadIdx.x;
    const int i = blockIdx.x * 1024 + t;
    int v = (i < NDST) ? cnt[i] : 0;
    buf[t] = v;
    __syncthreads();
    for (int off = 1; off < 1024; off <<= 1) {
        int tv = (t >= off) ? buf[t - off] : 0;
        __syncthreads();
        buf[t] += tv;
        __syncthreads();
    }
    if (i < NDST) excl[i] = buf[t] - v;
    if (t == 1023) bsum[blockIdx.x] = buf[1023];
}

// ---------------------------------------------------------------------------
// scan23: every block redundantly wave-scans the 49 chunk sums, then applies
// the offset to its rowptr slice.
// ---------------------------------------------------------------------------
__global__ __launch_bounds__(256) void scan23_kernel(
    const int* __restrict__ bsum, int* __restrict__ rowptr)
{
    __shared__ int pref[64];
    const int t = threadIdx.x;
    const int NB = (NDST + 1023) / 1024;     // 49
    if (t < 64) {
        int orig = (t < NB) ? bsum[t] : 0;
        int v = orig;
        for (int off = 1; off < 64; off <<= 1) {
            int u = __shfl_up(v, off);
            if (t >= off) v += u;
        }
        pref[t] = v - orig;                  // exclusive prefix
        if (blockIdx.x == 0 && t == NB - 1) rowptr[NDST] = v;  // total
    }
    __syncthreads();
    const int i = blockIdx.x * 256 + t;
    if (i < NDST) rowptr[i] += pref[i >> 10];
}

// ---------------------------------------------------------------------------
// edge_score: 64 edges / wave (4 A-tiles share each We B-frag). Tanh-dot in
// log2-domain (prescaled wa3s/bes, K0 const -> no ws). After the 16-lane xor
// ladder, a 15-cndmask select tree + ONE shfl gives every lane its own edge's
// dot -> fully 64-lane-parallel epilogue (gathers s1/s2/rowptr/rank, scatter
// ev16) for max memory-level parallelism. Atomic-free slot = rowptr+rank.
// Tail: e0 clamped to NE-64; duplicate edges write identical records.
// ---------------------------------------------------------------------------
__global__ __launch_bounds__(256) void edge_score_kernel(
    const int* __restrict__ ei, const float* __restrict__ eattr,
    const u16* __restrict__ We_pk, const float* __restrict__ bes,
    const float* __restrict__ wa3s, const float* __restrict__ consts,
    const float* __restrict__ s1, const float* __restrict__ s2,
    const int* __restrict__ rowptr, const int* __restrict__ rank,
    int4* __restrict__ ev16)
{
    const int t = threadIdx.x;
    const int w = t >> 6, lane = t & 63;
    const int ln = lane & 15, quad = lane >> 4;
    int e0 = (blockIdx.x * 4 + w) * 64;
    if (e0 > NE - 64) e0 = NE - 64;        // dup processing benign

    short8 a[4];
#pragma unroll
    for (int tl = 0; tl < 4; ++tl) {
        const float* ap = eattr + (size_t)(e0 + tl*16 + ln)*EDIM + quad*8;
        float4 f0 = *(const float4*)(ap);
        float4 f1 = *(const float4*)(ap + 4);
        u16 ab[8] = { f2b(f0.x), f2b(f0.y), f2b(f0.z), f2b(f0.w),
                      f2b(f1.x), f2b(f1.y), f2b(f1.z), f2b(f1.w) };
        a[tl] = *(short8*)ab;
    }

    float v0[4] = {0,0,0,0}, v1[4] = {0,0,0,0};
    float v2[4] = {0,0,0,0}, v3[4] = {0,0,0,0};
#pragma unroll
    for (int tt = 0; tt < 8; ++tt) {
        const float bb = bes[tt*16 + ln];
        const float ww = wa3s[tt*16 + ln];
        short8 b = ld8(We_pk + (size_t)(tt*64 + lane)*8);
        f32x4 ac0 = {bb, bb, bb, bb};
        f32x4 ac1 = {bb, bb, bb, bb};
        f32x4 ac2 = {bb, bb, bb, bb};
        f32x4 ac3 = {bb, bb, bb, bb};
        ac0 = __builtin_amdgcn_mfma_f32_16x16x32_bf16(a[0], b, ac0, 0, 0, 0);
        ac1 = __builtin_amdgcn_mfma_f32_16x16x32_bf16(a[1], b, ac1, 0, 0, 0);
        ac2 = __builtin_amdgcn_mfma_f32_16x16x32_bf16(a[2], b, ac2, 0, 0, 0);
        ac3 = __builtin_amdgcn_mfma_f32_16x16x32_bf16(a[3], b, ac3, 0, 0, 0);
#pragma unroll
        for (int r = 0; r < 4; ++r) {
            v0[r] = fmaf(ww, RCP(EXP2(ac0[r]) + 1.f), v0[r]);
            v1[r] = fmaf(ww, RCP(EXP2(ac1[r]) + 1.f), v1[r]);
            v2[r] = fmaf(ww, RCP(EXP2(ac2[r]) + 1.f), v2[r]);
            v3[r] = fmaf(ww, RCP(EXP2(ac3[r]) + 1.f), v3[r]);
        }
    }
    // reduce over the 16 feature lanes (ln) within each quad group
#pragma unroll
    for (int off = 8; off >= 1; off >>= 1) {
#pragma unroll
        for (int r = 0; r < 4; ++r) {
            v0[r] += __shfl_xor(v0[r], off);
            v1[r] += __shfl_xor(v1[r], off);
            v2[r] += __shfl_xor(v2[r], off);
            v3[r] += __shfl_xor(v3[r], off);
        }
    }
    // select tree: lane (quad q, ln) picks v_{ln>>2}[ln&3]
    // (value for edge (ln>>2)*16 + q*4 + (ln&3))
    const bool s0 = ln & 1, s1b = ln & 2, s2b = ln & 4, s3b = ln & 8;
    float m00 = s0 ? v0[1] : v0[0];
    float m01 = s0 ? v0[3] : v0[2];
    float m02 = s0 ? v1[1] : v1[0];
    float m03 = s0 ? v1[3] : v1[2];
    float m04 = s0 ? v2[1] : v2[0];
    float m05 = s0 ? v2[3] : v2[2];
    float m06 = s0 ? v3[1] : v3[0];
    float m07 = s0 ? v3[3] : v3[2];
    float m10 = s1b ? m01 : m00;
    float m11 = s1b ? m03 : m02;
    float m12 = s1b ? m05 : m04;
    float m13 = s1b ? m07 : m06;
    float m20 = s2b ? m11 : m10;
    float m21 = s2b ? m13 : m12;
    float selv = s3b ? m21 : m20;
    // lane l wants edge e0+l = (T= l>>4)*16 + (Q=(l>>2)&3)*4 + (R=l&3):
    // source lane = Q*16 + T*4 + R
    const int srcl = ((lane >> 2) & 3) * 16 + ((lane >> 4) << 2) + (lane & 3);
    const float myv = __shfl(selv, srcl);

    const int e = e0 + lane;
    const int srcn = ei[e];
    const int dstn = ei[NE + e];
    const float sc = consts[2] + s1[srcn] + s2[dstn] + myv;
    const int pos = rowptr[dstn] + rank[e];
    ev16[pos] = make_int4(srcn, e, __float_as_int(sc), 0);
}

// ---------------------------------------------------------------------------
// dst_agg: 1 wave per dst, single pass (no-max softmax): accumulate
// unnormalized w=exp2(sc), sum(w), sum(w*msg), sum(w*ea); normalize at end.
// msg row: 16 lanes x 16B bf16; ea row: 8 lanes x 16B f32 (one cache line).
// ---------------------------------------------------------------------------
__global__ __launch_bounds__(256) void dst_agg_kernel(
    const int4* __restrict__ ev16, const int* __restrict__ rowptr,
    const u16* __restrict__ srcmsgb, const float* __restrict__ eattr,
    const float* __restrict__ c2,
    u16* __restrict__ aggSb, u16* __restrict__ weab)
{
    const int lane = threadIdx.x & 63;
    const int d = blockIdx.x * 4 + (threadIdx.x >> 6);
    const int el = lane >> 4, c = lane & 15;
    const int start = rowptr[d], end = rowptr[d + 1];

    if (start == end) {
        if (el == 0) {
            u16 z[8];
#pragma unroll
            for (int j = 0; j < 8; ++j) z[j] = f2b(-c2[c*8 + j]);
            *(short8*)(aggSb + (size_t)d*HD + c*8) = *(short8*)z;
            if (c < 8) {
                u16 zz[4] = {0,0,0,0};
                *(ushort4*)(weab + (size_t)d*EDIM + c*4) = *(ushort4*)zz;
            }
        }
        return;
    }

    float sacc = 0.f;
    float acc[8]  = {0,0,0,0,0,0,0,0};
    float wacc[4] = {0,0,0,0};

    int icur = start + el;
    bool vcur = (icur < end);
    int iicur = vcur ? icur : start;
    int4 q = ev16[iicur];

    for (int i0 = start; i0 < end; i0 += 4) {
        const float wgt = vcur ? EXP2(__int_as_float(q.z)) : 0.f;
        const int   srow = q.x;
        const int   ecur = q.y;
        // prefetch next record (clamped; harmless re-read of ev16[start])
        const int inx = i0 + 4 + el;
        vcur = (inx < end);
        iicur = vcur ? inx : start;
        q = ev16[iicur];

        sacc += wgt;
        short8 sm = ld8(srcmsgb + (size_t)srow*HD + c*8);
#pragma unroll
        for (int j = 0; j < 8; ++j)
            acc[j] = fmaf(wgt, b2f(((u16*)&sm)[j]), acc[j]);
        if (c < 8) {
            float4 f = *(const float4*)(eattr + (size_t)ecur*EDIM + c*4);
            wacc[0] = fmaf(wgt, f.x, wacc[0]);
            wacc[1] = fmaf(wgt, f.y, wacc[1]);
            wacc[2] = fmaf(wgt, f.z, wacc[2]);
            wacc[3] = fmaf(wgt, f.w, wacc[3]);
        }
    }
#pragma unroll
    for (int off = 16; off <= 32; off <<= 1) {
        sacc += __shfl_xor(sacc, off);
#pragma unroll
        for (int j = 0; j < 8; ++j) acc[j] += __shfl_xor(acc[j], off);
#pragma unroll
        for (int j = 0; j < 4; ++j) wacc[j] += __shfl_xor(wacc[j], off);
    }
    const float inv = RCP(sacc);
    if (el == 0) {
        u16 o[8];
#pragma unroll
        for (int j = 0; j < 8; ++j) o[j] = f2b(acc[j] * inv);
        *(short8*)(aggSb + (size_t)d*HD + c*8) = *(short8*)o;
        if (c < 8) {
            u16 o2[4];
#pragma unroll
            for (int j = 0; j < 4; ++j) o2[j] = f2b(wacc[j] * inv);
            *(ushort4*)(weab + (size_t)d*EDIM + c*4) = *(ushort4*)o2;
        }
    }
}

// ---------------------------------------------------------------------------
// final: out = LN(dst_x@W1p + aggSb@Wout2 + weab@W3 + bias2) * gamma + beta
// per 16 dst rows / wave; dst_x read f32 + converted in-reg.
// ---------------------------------------------------------------------------
__global__ __launch_bounds__(256) void final_kernel(
    const float* __restrict__ dst_x, const u16* __restrict__ aggSb,
    const u16* __restrict__ weab,
    const u16* __restrict__ W1_pk, const u16* __restrict__ W2_pk,
    const u16* __restrict__ W3_pk, const float* __restrict__ bias2,
    const float* __restrict__ gamma, const float* __restrict__ beta,
    float* __restrict__ out)
{
    const int t = threadIdx.x;
    const int w = t >> 6, lane = t & 63;
    const int ln = lane & 15, quad = lane >> 4;
    int row0 = (blockIdx.x * 4 + w) * 16;
    if (row0 > NDST - 16) row0 = NDST - 16;

    const float* rp = dst_x + (size_t)(row0 + ln)*HD;
    short8 a1[4], a2[4], a3;
#pragma unroll
    for (int kc = 0; kc < 4; ++kc) {
        float4 f0 = *(const float4*)(rp + kc*32 + quad*8);
        float4 f1 = *(const float4*)(rp + kc*32 + quad*8 + 4);
        u16 tb[8] = { f2b(f0.x), f2b(f0.y), f2b(f0.z), f2b(f0.w),
                      f2b(f1.x), f2b(f1.y), f2b(f1.z), f2b(f1.w) };
        a1[kc] = *(short8*)tb;
        a2[kc] = ld8(aggSb + (size_t)(row0 + ln)*HD + kc*32 + quad*8);
    }
    a3 = ld8(weab + (size_t)(row0 + ln)*EDIM + quad*8);

    f32x4 accs[8];
#pragma unroll
    for (int tt = 0; tt < 8; ++tt) {
        const float bb = bias2[tt*16 + ln];
        f32x4 acc = {bb, bb, bb, bb};
#pragma unroll
        for (int kc = 0; kc < 4; ++kc) {
            short8 b = ld8(W1_pk + (size_t)((kc*8 + tt)*64 + lane)*8);
            acc = __builtin_amdgcn_mfma_f32_16x16x32_bf16(a1[kc], b, acc, 0, 0, 0);
        }
#pragma unroll
        for (int kc = 0; kc < 4; ++kc) {
            short8 b = ld8(W2_pk + (size_t)((kc*8 + tt)*64 + lane)*8);
            acc = __builtin_amdgcn_mfma_f32_16x16x32_bf16(a2[kc], b, acc, 0, 0, 0);
        }
        {
            short8 b = ld8(W3_pk + (size_t)(tt*64 + lane)*8);
            acc = __builtin_amdgcn_mfma_f32_16x16x32_bf16(a3, b, acc, 0, 0, 0);
        }
        accs[tt] = acc;
    }

    const float gl[8] = { gamma[ln], gamma[16+ln], gamma[32+ln], gamma[48+ln],
                          gamma[64+ln], gamma[80+ln], gamma[96+ln], gamma[112+ln] };
    const float bl[8] = { beta[ln], beta[16+ln], beta[32+ln], beta[48+ln],
                          beta[64+ln], beta[80+ln], beta[96+ln], beta[112+ln] };
#pragma unroll
    for (int r = 0; r < 4; ++r) {
        float s = 0.f, qq = 0.f;
#pragma unroll
        for (int tt = 0; tt < 8; ++tt) {
            float u = accs[tt][r];
            s += u; qq += u*u;
        }
#pragma unroll
        for (int off = 8; off >= 1; off >>= 1) {
            s  += __shfl_xor(s, off);
            qq += __shfl_xor(qq, off);
        }
        const float mean = s * (1.f / HD);
        const float var  = qq * (1.f / HD) - mean * mean;
        const float rstd = rsqrtf(var + LN_EPS);
        const int row = row0 + quad*4 + r;
#pragma unroll
        for (int tt = 0; tt < 8; ++tt)
            out[(size_t)row*HD + tt*16 + ln] =
                (accs[tt][r] - mean) * rstd * gl[tt] + bl[tt];
    }
}

// ---------------------------------------------------------------------------
extern "C" void kernel_launch(void* const* d_in, const int* in_sizes, int n_in,
                              void* d_out, int out_size, void* d_ws, size_t ws_size,
                              hipStream_t stream)
{
    const float* src_x = (const float*)d_in[0];
    const float* dst_x = (const float*)d_in[1];
    const int*   ei    = (const int*)d_in[2];
    const float* eattr = (const float*)d_in[3];
    const float* Wsrc  = (const float*)d_in[4];
    const float* bsrc  = (const float*)d_in[5];
    const float* Wdst  = (const float*)d_in[6];
    const float* bdst  = (const float*)d_in[7];
    const float* We    = (const float*)d_in[8];
    const float* be    = (const float*)d_in[9];
    const float* Wattn = (const float*)d_in[10];
    const float* battn = (const float*)d_in[11];
    const float* Wmsg  = (const float*)d_in[12];
    const float* bmsg  = (const float*)d_in[13];
    const float* Wout  = (const float*)d_in[14];
    const float* bout  = (const float*)d_in[15];
    const float* gamma = (const float*)d_in[16];
    const float* beta  = (const float*)d_in[17];
    float* out = (float*)d_out;

    float* ws = (float*)d_ws;
    u16* srcmsgb = (u16*)(ws + 0);            // 6.4M u16
    u16* aggSb   = (u16*)(ws + 3200000);      // 6.4M u16
    u16* weab    = (u16*)(ws + 6400000);      // 1.6M u16
    float* s1    = ws + 7200000;              // 50048
    float* s2    = ws + 7250048;              // 50048
    float* Wsm   = ws + 7300096;              // 16384
    float* bsm   = ws + 7316480;              // 128
    float* WeMsg = ws + 7316608;              // 4096
    float* c2    = ws + 7320704;              // 128
    float* bias2 = ws + 7320832;              // 128
    u16* Wsrc_pk = (u16*)(ws + 7320960);      // 16384 u16
    u16* Wdst_pk = (u16*)(ws + 7329152);
    u16* Wsm_pk  = (u16*)(ws + 7337344);
    u16* W1_pk   = (u16*)(ws + 7345536);
    u16* W2_pk   = (u16*)(ws + 7353728);
    u16* We_pk   = (u16*)(ws + 7361920);      // 4096 u16
    u16* W3_pk   = (u16*)(ws + 7363968);      // 4096 u16
    int* rowptr  = (int*)(ws + 7366016);      // 50016
    int* cnt     = (int*)(ws + 7416032);      // 50016
    int* bsum    = (int*)(ws + 7466048);      // 64
    int* rank    = (int*)(ws + 7466112);      // 500000
    int4* ev16   = (int4*)(ws + 7966112);     // 500000 int4 (16B-aligned)
    float* wa1s  = ws + 9966112;              // 128
    float* wa2s  = ws + 9966240;              // 128
    float* wa3s  = ws + 9966368;              // 128
    float* bsrcs = ws + 9966496;              // 128
    float* bdsts = ws + 9966624;              // 128
    float* bes   = ws + 9966752;              // 128
    float* consts= ws + 9966880;              // 4

    fold1_kernel<<<553, 128, 0, stream>>>(Wsrc, bsrc, We, be, Wmsg, bmsg,
                                          Wsm, bsm, WeMsg, c2, cnt);
    pack_all_kernel<<<178, 64, 0, stream>>>(Wsrc, Wdst, Wsm, Wout, We, WeMsg,
                                            c2, bout, bsrc, bdst, be, battn,
                                            Wattn,
                                            Wsrc_pk, Wdst_pk, Wsm_pk, W1_pk,
                                            W2_pk, We_pk, W3_pk, bias2,
                                            wa1s, wa2s, wa3s, bsrcs, bdsts,
                                            bes, consts);

    mega_kernel<<<2*NBLK + HB4, 256, 0, stream>>>(
        src_x, dst_x, ei, Wsrc_pk, Wsm_pk, Wdst_pk,
        bsrcs, bsm, bdsts, wa1s, wa2s, consts, s1, s2, srcmsgb, cnt, rank);

    scan1_kernel<<<(NDST + 1023) / 1024, 1024, 0, stream>>>(cnt, rowptr, bsum);
    scan23_kernel<<<(NDST + 255) / 256, 256, 0, stream>>>(bsum, rowptr);

    edge_score_kernel<<<((NE + 63)/64 + 3) / 4, 256, 0, stream>>>(
        ei, eattr, We_pk, bes, wa3s, consts, s1, s2, rowptr, rank, ev16);

    dst_agg_kernel<<<NDST / 4, 256, 0, stream>>>(ev16, rowptr, srcmsgb,
                                                 eattr, c2, aggSb, weab);

    final_kernel<<<(NDST/16 + 3) / 4, 256, 0, stream>>>(
        dst_x, aggSb, weab, W1_pk, W2_pk, W3_pk, bias2, gamma, beta, out);
}

// Round 7
// 290.088 us; speedup vs baseline: 1.6991x; 1.0192x over previous
//
#include <hip/hip_runtime.h>
#include <math.h>

#define NSRC 50000
#define NDST 50000
#define NE   500000
#define HD   128
#define EDIM 32
#define LN_EPS 1e-5f

typedef __attribute__((ext_vector_type(8))) short short8;   // 8 bf16 = 4 VGPR
typedef __attribute__((ext_vector_type(4))) float f32x4;
typedef unsigned short u16;

#define TL2E 2.8853900817779268f   /* 2*log2(e) */
#define L2E  1.4426950408889634f   /* log2(e)   */

__device__ __forceinline__ float EXP2(float x) {
#if __has_builtin(__builtin_amdgcn_exp2f)
    return __builtin_amdgcn_exp2f(x);
#else
    return exp2f(x);
#endif
}
__device__ __forceinline__ float RCP(float x) {
#if __has_builtin(__builtin_amdgcn_rcpf)
    return __builtin_amdgcn_rcpf(x);
#else
    return 1.f / x;
#endif
}
__device__ __forceinline__ u16 f2b(float x) {           // f32 -> bf16 RNE
    unsigned u = __float_as_uint(x);
    return (u16)((u + 0x7FFFu + ((u >> 16) & 1u)) >> 16);
}
__device__ __forceinline__ float b2f(u16 h) {
    return __uint_as_float(((unsigned)h) << 16);
}
__device__ __forceinline__ short8 ld8(const u16* p) { return *(const short8*)p; }

// ---------------------------------------------------------------------------
// fold1: Wsm = Wsrc@Wmsg, bsm = bsrc@Wmsg + bmsg, WeMsg = We@Wmsg, c2 = be@Wmsg
// (128 threads span output column j -> coalesced Wmsg reads, 1 dot/thread).
// Blocks r >= 162 zero the histogram counters (replaces memset launch).
// ---------------------------------------------------------------------------
__global__ __launch_bounds__(128) void fold1_kernel(
    const float* __restrict__ Wsrc, const float* __restrict__ bsrc,
    const float* __restrict__ We,   const float* __restrict__ be,
    const float* __restrict__ Wmsg, const float* __restrict__ bmsg,
    float* __restrict__ Wsm, float* __restrict__ bsm,
    float* __restrict__ WeMsg, float* __restrict__ c2,
    int* __restrict__ cnt)
{
    const int j = threadIdx.x;
    const int r = blockIdx.x;
    if (r >= 162) {
        int i = (r - 162) * 128 + j;
        if (i < NDST + 16) cnt[i] = 0;
        return;
    }
    float s = 0.f;
    if (r < 128) {
        for (int k = 0; k < 128; ++k) s += Wsrc[r*HD + k] * Wmsg[k*HD + j];
        Wsm[r*HD + j] = s;
    } else if (r < 160) {
        const int rr = r - 128;
        for (int k = 0; k < 128; ++k) s += We[rr*HD + k] * Wmsg[k*HD + j];
        WeMsg[rr*HD + j] = s;
    } else if (r == 160) {
        for (int k = 0; k < 128; ++k) s += bsrc[k] * Wmsg[k*HD + j];
        bsm[j] = s + bmsg[j];
    } else {
        for (int k = 0; k < 128; ++k) s += be[k] * Wmsg[k*HD + j];
        c2[j] = s;
    }
}

// ---------------------------------------------------------------------------
// pack_all: pack f32 [K x 128] weights into bf16 MFMA B-fragment layout.
// Wsrc/Wdst/We pre-scaled by 2*log2(e) (tanh-dot exp2/rcp refactor).
// W1 = Wout1 + I inline. W3 = WeMsg@Wout2 and bias2 = bout + c2@Wout2 inline.
// Block 177: constant folding for the tanh-dot paths (log2-domain scores).
// ---------------------------------------------------------------------------
__global__ __launch_bounds__(64) void pack_all_kernel(
    const float* __restrict__ Wsrc, const float* __restrict__ Wdst,
    const float* __restrict__ Wsm,  const float* __restrict__ Wout,
    const float* __restrict__ We,   const float* __restrict__ WeMsg,
    const float* __restrict__ c2,   const float* __restrict__ bout,
    const float* __restrict__ bsrc, const float* __restrict__ bdst,
    const float* __restrict__ be,   const float* __restrict__ battn,
    const float* __restrict__ wattn,
    u16* __restrict__ Wsrc_pk, u16* __restrict__ Wdst_pk,
    u16* __restrict__ Wsm_pk,  u16* __restrict__ W1_pk,
    u16* __restrict__ W2_pk,   u16* __restrict__ We_pk,
    u16* __restrict__ W3_pk,   float* __restrict__ bias2,
    float* __restrict__ wa1s, float* __restrict__ wa2s,
    float* __restrict__ wa3s, float* __restrict__ bsrcs,
    float* __restrict__ bdsts, float* __restrict__ bes,
    float* __restrict__ consts)
{
    const int b = blockIdx.x;
    const int lane = threadIdx.x;
    const int ln = lane & 15, quad = lane >> 4;
    const float* Wout2 = Wout + HD*HD;

    if (b == 177) {                        // const folding
        float sa1 = 0.f, sa2 = 0.f, sa3 = 0.f;
#pragma unroll
        for (int h = 0; h < 2; ++h) {
            const int col = lane + h*64;
            float a1 = wattn[col], a2 = wattn[HD + col], a3 = wattn[2*HD + col];
            wa1s[col] = a1 * (-2.f * L2E);
            wa2s[col] = a2 * (-2.f * L2E);
            wa3s[col] = a3 * (-2.f * L2E);
            bsrcs[col] = bsrc[col] * TL2E;
            bdsts[col] = bdst[col] * TL2E;
            bes[col]   = be[col]   * TL2E;
            sa1 += a1; sa2 += a2; sa3 += a3;
        }
#pragma unroll
        for (int off = 32; off >= 1; off >>= 1) {
            sa1 += __shfl_xor(sa1, off);
            sa2 += __shfl_xor(sa2, off);
            sa3 += __shfl_xor(sa3, off);
        }
        if (lane == 0) {
            consts[0] = L2E * sa1;
            consts[1] = L2E * sa2;
            consts[2] = L2E * (sa3 + battn[0]);
        }
        return;
    }
    if (b == 176) {                        // bias2 = bout + c2@Wout2
#pragma unroll
        for (int h = 0; h < 2; ++h) {
            const int col = lane + h*64;
            float s = 0.f;
            for (int k = 0; k < 128; ++k) s += c2[k] * Wout2[k*HD + col];
            bias2[col] = bout[col] + s;
        }
        return;
    }
    if (b >= 168) {                        // W3 = WeMsg@Wout2 (32x128), packed
        const int t = b - 168;
        const int jj = t*16 + ln;
        float sacc[8] = {0,0,0,0,0,0,0,0};
        for (int k = 0; k < 128; ++k) {
            const float w2 = Wout2[k*HD + jj];
#pragma unroll
            for (int j = 0; j < 8; ++j)
                sacc[j] = fmaf(WeMsg[(quad*8 + j)*HD + k], w2, sacc[j]);
        }
        u16 tmp[8];
#pragma unroll
        for (int j = 0; j < 8; ++j) tmp[j] = f2b(sacc[j]);
        *(short8*)(W3_pk + (size_t)(t*64 + lane)*8) = *(short8*)tmp;
        return;
    }

    const float* src; u16* dst; int lb; float scl = 1.f; bool addI = false;
    if      (b < 32)  { src = Wsrc; dst = Wsrc_pk; lb = b;       scl = TL2E; }
    else if (b < 64)  { src = Wdst; dst = Wdst_pk; lb = b - 32;  scl = TL2E; }
    else if (b < 96)  { src = Wsm;  dst = Wsm_pk;  lb = b - 64; }
    else if (b < 128) { src = Wout; dst = W1_pk;   lb = b - 96;  addI = true; }
    else if (b < 160) { src = Wout2;dst = W2_pk;   lb = b - 128; }
    else              { src = We;   dst = We_pk;   lb = b - 160; scl = TL2E; }
    const int kc = lb >> 3, t = lb & 7;
    u16 tmp[8];
#pragma unroll
    for (int j = 0; j < 8; ++j) {
        const int i = kc*32 + quad*8 + j, jj = t*16 + ln;
        float v = src[(size_t)i*HD + jj] * scl;
        if (addI && i == jj) v += 1.f;
        tmp[j] = f2b(v);
    }
    *(short8*)(dst + (size_t)(lb*64 + lane)*8) = *(short8*)tmp;
}

// ---------------------------------------------------------------------------
// mega: block-range fusion, 512 threads (8 waves) per compute block:
//   [0, NBLK)      node: s1 tanh-dot + srcmsgb, 32 rows/wave (256 rows/block)
//   [NBLK, 2NBLK)  dst:  s2 tanh-dot
//   [2NBLK, +HB4)  hist: cnt[dst]++ / rank, 4 edges per thread
// 512-thr blocks amortize the 32 KB weight stage over 8 waves and raise the
// LDS-bound occupancy cap from 12 to 16 waves/CU (64 KB/block, 2 blocks/CU).
// ---------------------------------------------------------------------------
#define NBLK ((NSRC + 255) / 256)
#define HB4 ((NE/4 + 511) / 512)

__global__ __launch_bounds__(512) void mega_kernel(
    const float* __restrict__ src_x, const float* __restrict__ dst_x,
    const int* __restrict__ ei,
    const u16* __restrict__ Wsrc_pk, const u16* __restrict__ Wsm_pk,
    const u16* __restrict__ Wdst_pk,
    const float* __restrict__ bsrcs, const float* __restrict__ bsm,
    const float* __restrict__ bdsts,
    const float* __restrict__ wa1s, const float* __restrict__ wa2s,
    const float* __restrict__ consts,
    float* __restrict__ s1, float* __restrict__ s2,
    u16* __restrict__ srcmsgb, int* __restrict__ cnt, int* __restrict__ rank)
{
    __shared__ __align__(16) u16 wlds[16384];      // 32 KB staged weights
    __shared__ __align__(16) u16 tlds[8][2048];    // 32 KB per-wave transpose
    const int t = threadIdx.x;
    const int blk = blockIdx.x;

    if (blk >= 2*NBLK) {                 // ---- hist path (4 edges/thread)
        const int idx = (blk - 2*NBLK) * 512 + t;
        if (idx < NE/4) {
            int4 d4 = ((const int4*)(ei + NE))[idx];
            int4 r4;
            r4.x = atomicAdd(&cnt[d4.x], 1);
            r4.y = atomicAdd(&cnt[d4.y], 1);
            r4.z = atomicAdd(&cnt[d4.z], 1);
            r4.w = atomicAdd(&cnt[d4.w], 1);
            ((int4*)rank)[idx] = r4;
        }
        return;
    }

    const int w = t >> 6, lane = t & 63;
    const int ln = lane & 15, quad = lane >> 4;
    const bool is_src = (blk < NBLK);
    const int b = is_src ? blk : blk - NBLK;
    int row0 = b * 256 + w * 32;
    if (row0 > NSRC - 32) row0 = NSRC - 32;       // dup writes benign

    // x loads (2 row-tiles), converted to bf16 A-frags in-register
    const float* X = is_src ? src_x : dst_x;
    const float* rp0 = X + (size_t)(row0 + ln)*HD;
    const float* rp1 = rp0 + (size_t)16*HD;
    short8 a0[4], a1[4];
#pragma unroll
    for (int kc = 0; kc < 4; ++kc) {
        float4 f0 = *(const float4*)(rp0 + kc*32 + quad*8);
        float4 f1 = *(const float4*)(rp0 + kc*32 + quad*8 + 4);
        float4 g0 = *(const float4*)(rp1 + kc*32 + quad*8);
        float4 g1 = *(const float4*)(rp1 + kc*32 + quad*8 + 4);
        u16 tb[8] = { f2b(f0.x), f2b(f0.y), f2b(f0.z), f2b(f0.w),
                      f2b(f1.x), f2b(f1.y), f2b(f1.z), f2b(f1.w) };
        a0[kc] = *(short8*)tb;
        u16 tc[8] = { f2b(g0.x), f2b(g0.y), f2b(g0.z), f2b(g0.w),
                      f2b(g1.x), f2b(g1.y), f2b(g1.z), f2b(g1.w) };
        a1[kc] = *(short8*)tc;
    }

    // stage phase-1 weights (32 KB, cooperative, coalesced 16B)
    const u16* Wpk = is_src ? Wsrc_pk : Wdst_pk;
#pragma unroll
    for (int it = 0; it < 4; ++it) {
        short8 v = ld8(Wpk + (size_t)(it*512 + t)*8);
        *(short8*)(&wlds[(it*512 + t)*8]) = v;
    }
    __syncthreads();

    const float* bb_ = is_src ? bsrcs : bdsts;
    const float* wa  = is_src ? wa1s : wa2s;
    const float  K   = consts[is_src ? 0 : 1];
    float* sout      = is_src ? s1 : s2;

    // ---- tanh-dot (log2-domain), two tiles share each B-frag
    float v0[4] = {0,0,0,0}, v1[4] = {0,0,0,0};
#pragma unroll
    for (int tt = 0; tt < 8; ++tt) {
        const float bb = bb_[tt*16 + ln];
        const float ww = wa[tt*16 + ln];
        f32x4 acc0 = {bb, bb, bb, bb};
        f32x4 acc1 = {bb, bb, bb, bb};
#pragma unroll
        for (int kc = 0; kc < 4; ++kc) {
            short8 bf = ld8(&wlds[(size_t)((kc*8 + tt)*64 + lane)*8]);
            acc0 = __builtin_amdgcn_mfma_f32_16x16x32_bf16(a0[kc], bf, acc0, 0, 0, 0);
            acc1 = __builtin_amdgcn_mfma_f32_16x16x32_bf16(a1[kc], bf, acc1, 0, 0, 0);
        }
#pragma unroll
        for (int r = 0; r < 4; ++r) {
            v0[r] = fmaf(ww, RCP(EXP2(acc0[r]) + 1.f), v0[r]);
            v1[r] = fmaf(ww, RCP(EXP2(acc1[r]) + 1.f), v1[r]);
        }
    }
#pragma unroll
    for (int off = 8; off >= 1; off >>= 1) {
#pragma unroll
        for (int r = 0; r < 4; ++r) {
            v0[r] += __shfl_xor(v0[r], off);
            v1[r] += __shfl_xor(v1[r], off);
        }
    }
    if (ln == 0) {
#pragma unroll
        for (int r = 0; r < 4; ++r) {
            sout[row0 + quad*4 + r]      = K + v0[r];
            sout[row0 + 16 + quad*4 + r] = K + v1[r];
        }
    }

    if (!is_src) return;

    // ---- restage with Wsm, then srcmsg path
    __syncthreads();
#pragma unroll
    for (int it = 0; it < 4; ++it) {
        short8 v = ld8(Wsm_pk + (size_t)(it*512 + t)*8);
        *(short8*)(&wlds[(it*512 + t)*8]) = v;
    }
    __syncthreads();

    u16* slab = &tlds[w][0];
#pragma unroll
    for (int tile = 0; tile < 2; ++tile) {
#pragma unroll
        for (int tt = 0; tt < 8; ++tt) {
            const float bs = bsm[tt*16 + ln];
            f32x4 acc = {bs, bs, bs, bs};
#pragma unroll
            for (int kc = 0; kc < 4; ++kc) {
                short8 bf = ld8(&wlds[(size_t)((kc*8 + tt)*64 + lane)*8]);
                acc = __builtin_amdgcn_mfma_f32_16x16x32_bf16(
                          tile ? a1[kc] : a0[kc], bf, acc, 0, 0, 0);
            }
            // swizzled write: row = quad*4+r (row>>2 == quad), col blk tt^quad
#pragma unroll
            for (int r = 0; r < 4; ++r)
                slab[(quad*4 + r)*128 + ((tt ^ quad) << 4) + ln] = f2b(acc[r]);
        }
        // per-wave readback (DS in-order within wave; no barrier needed)
#pragma unroll
        for (int r2 = 0; r2 < 4; ++r2) {
            const int row = r2*4 + quad;          // row>>2 == r2
            const int c = ln*8;
            const int sidx = row*128 + (((c >> 4) ^ r2) << 4) + (c & 15);
            short8 val = *(const short8*)(&slab[sidx]);
            *(short8*)(srcmsgb + (size_t)(row0 + tile*16 + row)*HD + c) = val;
        }
    }
}

// ---------------------------------------------------------------------------
// scan1: per-1024-chunk exclusive scan of cnt into rowptr, block sums to bsum
// ---------------------------------------------------------------------------
__global__ __launch_bounds__(1024) void scan1_kernel(
    const int* __restrict__ cnt, int* __restrict__ excl, int* __restrict__ bsum)
{
    __shared__ int buf[1024];
    const int t = threadIdx.x;
    const int i = blockIdx.x * 1024 + t;
    int v = (i < NDST) ? cnt[i] : 0;
    buf[t] = v;
    __syncthreads();
    for (int off = 1; off < 1024; off <<= 1) {
        int tv = (t >= off) ? buf[t - off] : 0;
        __syncthreads();
        buf[t] += tv;
        __syncthreads();
    }
    if (i < NDST) excl[i] = buf[t] - v;
    if (t == 1023) bsum[blockIdx.x] = buf[1023];
}

// ---------------------------------------------------------------------------
// scan23: every block redundantly wave-scans the 49 chunk sums, then applies
// the offset to its rowptr slice.
// ---------------------------------------------------------------------------
__global__ __launch_bounds__(256) void scan23_kernel(
    const int* __restrict__ bsum, int* __restrict__ rowptr)
{
    __shared__ int pref[64];
    const int t = threadIdx.x;
    const int NB = (NDST + 1023) / 1024;     // 49
    if (t < 64) {
        int orig = (t < NB) ? bsum[t] : 0;
        int v = orig;
        for (int off = 1; off < 64; off <<= 1) {
            int u = __shfl_up(v, off);
            if (t >= off) v += u;
        }
        pref[t] = v - orig;                  // exclusive prefix
        if (blockIdx.x == 0 && t == NB - 1) rowptr[NDST] = v;  // total
    }
    __syncthreads();
    const int i = blockIdx.x * 256 + t;
    if (i < NDST) rowptr[i] += pref[i >> 10];
}

// ---------------------------------------------------------------------------
// edge_score: 64 edges / wave (4 A-tiles share each We B-frag). Tanh-dot in
// log2-domain. 15-cndmask select tree + ONE shfl -> fully 64-lane-parallel
// epilogue. Atomic-free slot = rowptr + rank.
// ---------------------------------------------------------------------------
__global__ __launch_bounds__(256) void edge_score_kernel(
    const int* __restrict__ ei, const float* __restrict__ eattr,
    const u16* __restrict__ We_pk, const float* __restrict__ bes,
    const float* __restrict__ wa3s, const float* __restrict__ consts,
    const float* __restrict__ s1, const float* __restrict__ s2,
    const int* __restrict__ rowptr, const int* __restrict__ rank,
    int4* __restrict__ ev16)
{
    const int t = threadIdx.x;
    const int w = t >> 6, lane = t & 63;
    const int ln = lane & 15, quad = lane >> 4;
    int e0 = (blockIdx.x * 4 + w) * 64;
    if (e0 > NE - 64) e0 = NE - 64;        // dup processing benign

    short8 a[4];
#pragma unroll
    for (int tl = 0; tl < 4; ++tl) {
        const float* ap = eattr + (size_t)(e0 + tl*16 + ln)*EDIM + quad*8;
        float4 f0 = *(const float4*)(ap);
        float4 f1 = *(const float4*)(ap + 4);
        u16 ab[8] = { f2b(f0.x), f2b(f0.y), f2b(f0.z), f2b(f0.w),
                      f2b(f1.x), f2b(f1.y), f2b(f1.z), f2b(f1.w) };
        a[tl] = *(short8*)ab;
    }

    float v0[4] = {0,0,0,0}, v1[4] = {0,0,0,0};
    float v2[4] = {0,0,0,0}, v3[4] = {0,0,0,0};
#pragma unroll
    for (int tt = 0; tt < 8; ++tt) {
        const float bb = bes[tt*16 + ln];
        const float ww = wa3s[tt*16 + ln];
        short8 b = ld8(We_pk + (size_t)(tt*64 + lane)*8);
        f32x4 ac0 = {bb, bb, bb, bb};
        f32x4 ac1 = {bb, bb, bb, bb};
        f32x4 ac2 = {bb, bb, bb, bb};
        f32x4 ac3 = {bb, bb, bb, bb};
        ac0 = __builtin_amdgcn_mfma_f32_16x16x32_bf16(a[0], b, ac0, 0, 0, 0);
        ac1 = __builtin_amdgcn_mfma_f32_16x16x32_bf16(a[1], b, ac1, 0, 0, 0);
        ac2 = __builtin_amdgcn_mfma_f32_16x16x32_bf16(a[2], b, ac2, 0, 0, 0);
        ac3 = __builtin_amdgcn_mfma_f32_16x16x32_bf16(a[3], b, ac3, 0, 0, 0);
#pragma unroll
        for (int r = 0; r < 4; ++r) {
            v0[r] = fmaf(ww, RCP(EXP2(ac0[r]) + 1.f), v0[r]);
            v1[r] = fmaf(ww, RCP(EXP2(ac1[r]) + 1.f), v1[r]);
            v2[r] = fmaf(ww, RCP(EXP2(ac2[r]) + 1.f), v2[r]);
            v3[r] = fmaf(ww, RCP(EXP2(ac3[r]) + 1.f), v3[r]);
        }
    }
    // reduce over the 16 feature lanes (ln) within each quad group
#pragma unroll
    for (int off = 8; off >= 1; off >>= 1) {
#pragma unroll
        for (int r = 0; r < 4; ++r) {
            v0[r] += __shfl_xor(v0[r], off);
            v1[r] += __shfl_xor(v1[r], off);
            v2[r] += __shfl_xor(v2[r], off);
            v3[r] += __shfl_xor(v3[r], off);
        }
    }
    // select tree: lane (quad q, ln) picks v_{ln>>2}[ln&3]
    const bool s0 = ln & 1, s1b = ln & 2, s2b = ln & 4, s3b = ln & 8;
    float m00 = s0 ? v0[1] : v0[0];
    float m01 = s0 ? v0[3] : v0[2];
    float m02 = s0 ? v1[1] : v1[0];
    float m03 = s0 ? v1[3] : v1[2];
    float m04 = s0 ? v2[1] : v2[0];
    float m05 = s0 ? v2[3] : v2[2];
    float m06 = s0 ? v3[1] : v3[0];
    float m07 = s0 ? v3[3] : v3[2];
    float m10 = s1b ? m01 : m00;
    float m11 = s1b ? m03 : m02;
    float m12 = s1b ? m05 : m04;
    float m13 = s1b ? m07 : m06;
    float m20 = s2b ? m11 : m10;
    float m21 = s2b ? m13 : m12;
    float selv = s3b ? m21 : m20;
    // lane l wants edge e0+l = (T=l>>4)*16 + (Q=(l>>2)&3)*4 + (R=l&3):
    // source lane = Q*16 + T*4 + R
    const int srcl = ((lane >> 2) & 3) * 16 + ((lane >> 4) << 2) + (lane & 3);
    const float myv = __shfl(selv, srcl);

    const int e = e0 + lane;
    const int srcn = ei[e];
    const int dstn = ei[NE + e];
    const float sc = consts[2] + s1[srcn] + s2[dstn] + myv;
    const int pos = rowptr[dstn] + rank[e];
    ev16[pos] = make_int4(srcn, e, __float_as_int(sc), 0);
}

// ---------------------------------------------------------------------------
// dst_agg: 1 wave per dst, single pass (no-max softmax): accumulate
// unnormalized w=exp2(sc), sum(w), sum(w*msg), sum(w*ea); normalize at end.
// msg row: 16 lanes x 16B bf16; ea row: 8 lanes x 16B f32 (one cache line).
// ---------------------------------------------------------------------------
__global__ __launch_bounds__(256) void dst_agg_kernel(
    const int4* __restrict__ ev16, const int* __restrict__ rowptr,
    const u16* __restrict__ srcmsgb, const float* __restrict__ eattr,
    const float* __restrict__ c2,
    u16* __restrict__ aggSb, u16* __restrict__ weab)
{
    const int lane = threadIdx.x & 63;
    const int d = blockIdx.x * 4 + (threadIdx.x >> 6);
    const int el = lane >> 4, c = lane & 15;
    const int start = rowptr[d], end = rowptr[d + 1];

    if (start == end) {
        if (el == 0) {
            u16 z[8];
#pragma unroll
            for (int j = 0; j < 8; ++j) z[j] = f2b(-c2[c*8 + j]);
            *(short8*)(aggSb + (size_t)d*HD + c*8) = *(short8*)z;
            if (c < 8) {
                u16 zz[4] = {0,0,0,0};
                *(ushort4*)(weab + (size_t)d*EDIM + c*4) = *(ushort4*)zz;
            }
        }
        return;
    }

    float sacc = 0.f;
    float acc[8]  = {0,0,0,0,0,0,0,0};
    float wacc[4] = {0,0,0,0};

    int icur = start + el;
    bool vcur = (icur < end);
    int iicur = vcur ? icur : start;
    int4 q = ev16[iicur];

    for (int i0 = start; i0 < end; i0 += 4) {
        const float wgt = vcur ? EXP2(__int_as_float(q.z)) : 0.f;
        const int   srow = q.x;
        const int   ecur = q.y;
        // prefetch next record (clamped; harmless re-read of ev16[start])
        const int inx = i0 + 4 + el;
        vcur = (inx < end);
        iicur = vcur ? inx : start;
        q = ev16[iicur];

        sacc += wgt;
        short8 sm = ld8(srcmsgb + (size_t)srow*HD + c*8);
#pragma unroll
        for (int j = 0; j < 8; ++j)
            acc[j] = fmaf(wgt, b2f(((u16*)&sm)[j]), acc[j]);
        if (c < 8) {
            float4 f = *(const float4*)(eattr + (size_t)ecur*EDIM + c*4);
            wacc[0] = fmaf(wgt, f.x, wacc[0]);
            wacc[1] = fmaf(wgt, f.y, wacc[1]);
            wacc[2] = fmaf(wgt, f.z, wacc[2]);
            wacc[3] = fmaf(wgt, f.w, wacc[3]);
        }
    }
#pragma unroll
    for (int off = 16; off <= 32; off <<= 1) {
        sacc += __shfl_xor(sacc, off);
#pragma unroll
        for (int j = 0; j < 8; ++j) acc[j] += __shfl_xor(acc[j], off);
#pragma unroll
        for (int j = 0; j < 4; ++j) wacc[j] += __shfl_xor(wacc[j], off);
    }
    const float inv = RCP(sacc);
    if (el == 0) {
        u16 o[8];
#pragma unroll
        for (int j = 0; j < 8; ++j) o[j] = f2b(acc[j] * inv);
        *(short8*)(aggSb + (size_t)d*HD + c*8) = *(short8*)o;
        if (c < 8) {
            u16 o2[4];
#pragma unroll
            for (int j = 0; j < 4; ++j) o2[j] = f2b(wacc[j] * inv);
            *(ushort4*)(weab + (size_t)d*EDIM + c*4) = *(ushort4*)o2;
        }
    }
}

// ---------------------------------------------------------------------------
// final: out = LN(dst_x@W1p + aggSb@Wout2 + weab@W3 + bias2) * gamma + beta
// per 16 dst rows / wave; dst_x read f32 + converted in-reg.
// ---------------------------------------------------------------------------
__global__ __launch_bounds__(256) void final_kernel(
    const float* __restrict__ dst_x, const u16* __restrict__ aggSb,
    const u16* __restrict__ weab,
    const u16* __restrict__ W1_pk, const u16* __restrict__ W2_pk,
    const u16* __restrict__ W3_pk, const float* __restrict__ bias2,
    const float* __restrict__ gamma, const float* __restrict__ beta,
    float* __restrict__ out)
{
    const int t = threadIdx.x;
    const int w = t >> 6, lane = t & 63;
    const int ln = lane & 15, quad = lane >> 4;
    int row0 = (blockIdx.x * 4 + w) * 16;
    if (row0 > NDST - 16) row0 = NDST - 16;

    const float* rp = dst_x + (size_t)(row0 + ln)*HD;
    short8 a1[4], a2[4], a3;
#pragma unroll
    for (int kc = 0; kc < 4; ++kc) {
        float4 f0 = *(const float4*)(rp + kc*32 + quad*8);
        float4 f1 = *(const float4*)(rp + kc*32 + quad*8 + 4);
        u16 tb[8] = { f2b(f0.x), f2b(f0.y), f2b(f0.z), f2b(f0.w),
                      f2b(f1.x), f2b(f1.y), f2b(f1.z), f2b(f1.w) };
        a1[kc] = *(short8*)tb;
        a2[kc] = ld8(aggSb + (size_t)(row0 + ln)*HD + kc*32 + quad*8);
    }
    a3 = ld8(weab + (size_t)(row0 + ln)*EDIM + quad*8);

    f32x4 accs[8];
#pragma unroll
    for (int tt = 0; tt < 8; ++tt) {
        const float bb = bias2[tt*16 + ln];
        f32x4 acc = {bb, bb, bb, bb};
#pragma unroll
        for (int kc = 0; kc < 4; ++kc) {
            short8 b = ld8(W1_pk + (size_t)((kc*8 + tt)*64 + lane)*8);
            acc = __builtin_amdgcn_mfma_f32_16x16x32_bf16(a1[kc], b, acc, 0, 0, 0);
        }
#pragma unroll
        for (int kc = 0; kc < 4; ++kc) {
            short8 b = ld8(W2_pk + (size_t)((kc*8 + tt)*64 + lane)*8);
            acc = __builtin_amdgcn_mfma_f32_16x16x32_bf16(a2[kc], b, acc, 0, 0, 0);
        }
        {
            short8 b = ld8(W3_pk + (size_t)(tt*64 + lane)*8);
            acc = __builtin_amdgcn_mfma_f32_16x16x32_bf16(a3, b, acc, 0, 0, 0);
        }
        accs[tt] = acc;
    }

    const float gl[8] = { gamma[ln], gamma[16+ln], gamma[32+ln], gamma[48+ln],
                          gamma[64+ln], gamma[80+ln], gamma[96+ln], gamma[112+ln] };
    const float bl[8] = { beta[ln], beta[16+ln], beta[32+ln], beta[48+ln],
                          beta[64+ln], beta[80+ln], beta[96+ln], beta[112+ln] };
#pragma unroll
    for (int r = 0; r < 4; ++r) {
        float s = 0.f, qq = 0.f;
#pragma unroll
        for (int tt = 0; tt < 8; ++tt) {
            float u = accs[tt][r];
            s += u; qq += u*u;
        }
#pragma unroll
        for (int off = 8; off >= 1; off >>= 1) {
            s  += __shfl_xor(s, off);
            qq += __shfl_xor(qq, off);
        }
        const float mean = s * (1.f / HD);
        const float var  = qq * (1.f / HD) - mean * mean;
        const float rstd = rsqrtf(var + LN_EPS);
        const int row = row0 + quad*4 + r;
#pragma unroll
        for (int tt = 0; tt < 8; ++tt)
            out[(size_t)row*HD + tt*16 + ln] =
                (accs[tt][r] - mean) * rstd * gl[tt] + bl[tt];
    }
}

// ---------------------------------------------------------------------------
extern "C" void kernel_launch(void* const* d_in, const int* in_sizes, int n_in,
                              void* d_out, int out_size, void* d_ws, size_t ws_size,
                              hipStream_t stream)
{
    const float* src_x = (const float*)d_in[0];
    const float* dst_x = (const float*)d_in[1];
    const int*   ei    = (const int*)d_in[2];
    const float* eattr = (const float*)d_in[3];
    const float* Wsrc  = (const float*)d_in[4];
    const float* bsrc  = (const float*)d_in[5];
    const float* Wdst  = (const float*)d_in[6];
    const float* bdst  = (const float*)d_in[7];
    const float* We    = (const float*)d_in[8];
    const float* be    = (const float*)d_in[9];
    const float* Wattn = (const float*)d_in[10];
    const float* battn = (const float*)d_in[11];
    const float* Wmsg  = (const float*)d_in[12];
    const float* bmsg  = (const float*)d_in[13];
    const float* Wout  = (const float*)d_in[14];
    const float* bout  = (const float*)d_in[15];
    const float* gamma = (const float*)d_in[16];
    const float* beta  = (const float*)d_in[17];
    float* out = (float*)d_out;

    float* ws = (float*)d_ws;
    u16* srcmsgb = (u16*)(ws + 0);            // 6.4M u16
    u16* aggSb   = (u16*)(ws + 3200000);      // 6.4M u16
    u16* weab    = (u16*)(ws + 6400000);      // 1.6M u16
    float* s1    = ws + 7200000;              // 50048
    float* s2    = ws + 7250048;              // 50048
    float* Wsm   = ws + 7300096;              // 16384
    float* bsm   = ws + 7316480;              // 128
    float* WeMsg = ws + 7316608;              // 4096
    float* c2    = ws + 7320704;              // 128
    float* bias2 = ws + 7320832;              // 128
    u16* Wsrc_pk = (u16*)(ws + 7320960);      // 16384 u16
    u16* Wdst_pk = (u16*)(ws + 7329152);
    u16* Wsm_pk  = (u16*)(ws + 7337344);
    u16* W1_pk   = (u16*)(ws + 7345536);
    u16* W2_pk   = (u16*)(ws + 7353728);
    u16* We_pk   = (u16*)(ws + 7361920);      // 4096 u16
    u16* W3_pk   = (u16*)(ws + 7363968);      // 4096 u16
    int* rowptr  = (int*)(ws + 7366016);      // 50016
    int* cnt     = (int*)(ws + 7416032);      // 50016
    int* bsum    = (int*)(ws + 7466048);      // 64
    int* rank    = (int*)(ws + 7466112);      // 500000
    int4* ev16   = (int4*)(ws + 7966112);     // 500000 int4 (16B-aligned)
    float* wa1s  = ws + 9966112;              // 128
    float* wa2s  = ws + 9966240;              // 128
    float* wa3s  = ws + 9966368;              // 128
    float* bsrcs = ws + 9966496;              // 128
    float* bdsts = ws + 9966624;              // 128
    float* bes   = ws + 9966752;              // 128
    float* consts= ws + 9966880;              // 4

    fold1_kernel<<<553, 128, 0, stream>>>(Wsrc, bsrc, We, be, Wmsg, bmsg,
                                          Wsm, bsm, WeMsg, c2, cnt);
    pack_all_kernel<<<178, 64, 0, stream>>>(Wsrc, Wdst, Wsm, Wout, We, WeMsg,
                                            c2, bout, bsrc, bdst, be, battn,
                                            Wattn,
                                            Wsrc_pk, Wdst_pk, Wsm_pk, W1_pk,
                                            W2_pk, We_pk, W3_pk, bias2,
                                            wa1s, wa2s, wa3s, bsrcs, bdsts,
                                            bes, consts);

    mega_kernel<<<2*NBLK + HB4, 512, 0, stream>>>(
        src_x, dst_x, ei, Wsrc_pk, Wsm_pk, Wdst_pk,
        bsrcs, bsm, bdsts, wa1s, wa2s, consts, s1, s2, srcmsgb, cnt, rank);

    scan1_kernel<<<(NDST + 1023) / 1024, 1024, 0, stream>>>(cnt, rowptr, bsum);
    scan23_kernel<<<(NDST + 255) / 256, 256, 0, stream>>>(bsum, rowptr);

    edge_score_kernel<<<((NE + 63)/64 + 3) / 4, 256, 0, stream>>>(
        ei, eattr, We_pk, bes, wa3s, consts, s1, s2, rowptr, rank, ev16);

    dst_agg_kernel<<<NDST / 4, 256, 0, stream>>>(ev16, rowptr, srcmsgb,
                                                 eattr, c2, aggSb, weab);

    final_kernel<<<(NDST/16 + 3) / 4, 256, 0, stream>>>(
        dst_x, aggSb, weab, W1_pk, W2_pk, W3_pk, bias2, gamma, beta, out);
}

// Round 8
// 283.896 us; speedup vs baseline: 1.7362x; 1.0218x over previous
//
#include <hip/hip_runtime.h>
#include <math.h>

#define NSRC 50000
#define NDST 50000
#define NE   500000
#define HD   128
#define EDIM 32
#define LN_EPS 1e-5f

typedef __attribute__((ext_vector_type(8))) short short8;   // 8 bf16 = 4 VGPR
typedef __attribute__((ext_vector_type(4))) float f32x4;
typedef unsigned short u16;

#define TL2E 2.8853900817779268f   /* 2*log2(e) */
#define L2E  1.4426950408889634f   /* log2(e)   */

__device__ __forceinline__ float EXP2(float x) {
#if __has_builtin(__builtin_amdgcn_exp2f)
    return __builtin_amdgcn_exp2f(x);
#else
    return exp2f(x);
#endif
}
__device__ __forceinline__ float RCP(float x) {
#if __has_builtin(__builtin_amdgcn_rcpf)
    return __builtin_amdgcn_rcpf(x);
#else
    return 1.f / x;
#endif
}
__device__ __forceinline__ u16 f2b(float x) {           // f32 -> bf16 RNE
    unsigned u = __float_as_uint(x);
    return (u16)((u + 0x7FFFu + ((u >> 16) & 1u)) >> 16);
}
__device__ __forceinline__ float b2f(u16 h) {
    return __uint_as_float(((unsigned)h) << 16);
}
__device__ __forceinline__ short8 ld8(const u16* p) { return *(const short8*)p; }

// ---------------------------------------------------------------------------
// fold1: Wsm = Wsrc@Wmsg, bsm = bsrc@Wmsg + bmsg, WeMsg = We@Wmsg, c2 = be@Wmsg
// (128 threads span output column j -> coalesced Wmsg reads, 1 dot/thread).
// Blocks r >= 162 zero the histogram counters (replaces memset launch).
// ---------------------------------------------------------------------------
__global__ __launch_bounds__(128) void fold1_kernel(
    const float* __restrict__ Wsrc, const float* __restrict__ bsrc,
    const float* __restrict__ We,   const float* __restrict__ be,
    const float* __restrict__ Wmsg, const float* __restrict__ bmsg,
    float* __restrict__ Wsm, float* __restrict__ bsm,
    float* __restrict__ WeMsg, float* __restrict__ c2,
    int* __restrict__ cnt)
{
    const int j = threadIdx.x;
    const int r = blockIdx.x;
    if (r >= 162) {
        int i = (r - 162) * 128 + j;
        if (i < NDST + 16) cnt[i] = 0;
        return;
    }
    float s = 0.f;
    if (r < 128) {
        for (int k = 0; k < 128; ++k) s += Wsrc[r*HD + k] * Wmsg[k*HD + j];
        Wsm[r*HD + j] = s;
    } else if (r < 160) {
        const int rr = r - 128;
        for (int k = 0; k < 128; ++k) s += We[rr*HD + k] * Wmsg[k*HD + j];
        WeMsg[rr*HD + j] = s;
    } else if (r == 160) {
        for (int k = 0; k < 128; ++k) s += bsrc[k] * Wmsg[k*HD + j];
        bsm[j] = s + bmsg[j];
    } else {
        for (int k = 0; k < 128; ++k) s += be[k] * Wmsg[k*HD + j];
        c2[j] = s;
    }
}

// ---------------------------------------------------------------------------
// pack_all: pack f32 [K x 128] weights into bf16 MFMA B-fragment layout.
// Wsrc/We pre-scaled by 2*log2(e) (tanh-dot exp2/rcp refactor). Wdst path
// DELETED: softmax shift-invariance means s2[dst] (and all segment-constant
// score terms) cancel in alpha -> dst tanh-dot is dead code.
// blocks: Wsrc 0-31, Wsm 32-63, W1(+I) 64-95, W2 96-127, We 128-135 (K=32),
//         W3 136-143 (computed), bias2 144, scale-folds 145.
// ---------------------------------------------------------------------------
__global__ __launch_bounds__(64) void pack_all_kernel(
    const float* __restrict__ Wsrc, const float* __restrict__ Wsm,
    const float* __restrict__ Wout, const float* __restrict__ We,
    const float* __restrict__ WeMsg, const float* __restrict__ c2,
    const float* __restrict__ bout, const float* __restrict__ bsrc,
    const float* __restrict__ be,   const float* __restrict__ wattn,
    u16* __restrict__ Wsrc_pk, u16* __restrict__ Wsm_pk,
    u16* __restrict__ W1_pk,   u16* __restrict__ W2_pk,
    u16* __restrict__ We_pk,   u16* __restrict__ W3_pk,
    float* __restrict__ bias2,
    float* __restrict__ wa1s, float* __restrict__ wa3s,
    float* __restrict__ bsrcs, float* __restrict__ bes)
{
    const int b = blockIdx.x;
    const int lane = threadIdx.x;
    const int ln = lane & 15, quad = lane >> 4;
    const float* Wout2 = Wout + HD*HD;

    if (b == 145) {                        // scale folds (no sums: K cancels)
#pragma unroll
        for (int h = 0; h < 2; ++h) {
            const int col = lane + h*64;
            wa1s[col] = wattn[col]        * (-2.f * L2E);
            wa3s[col] = wattn[2*HD + col] * (-2.f * L2E);
            bsrcs[col] = bsrc[col] * TL2E;
            bes[col]   = be[col]   * TL2E;
        }
        return;
    }
    if (b == 144) {                        // bias2 = bout + c2@Wout2
#pragma unroll
        for (int h = 0; h < 2; ++h) {
            const int col = lane + h*64;
            float s = 0.f;
            for (int k = 0; k < 128; ++k) s += c2[k] * Wout2[k*HD + col];
            bias2[col] = bout[col] + s;
        }
        return;
    }
    if (b >= 136) {                        // W3 = WeMsg@Wout2 (32x128), packed
        const int t = b - 136;
        const int jj = t*16 + ln;
        float sacc[8] = {0,0,0,0,0,0,0,0};
        for (int k = 0; k < 128; ++k) {
            const float w2 = Wout2[k*HD + jj];
#pragma unroll
            for (int j = 0; j < 8; ++j)
                sacc[j] = fmaf(WeMsg[(quad*8 + j)*HD + k], w2, sacc[j]);
        }
        u16 tmp[8];
#pragma unroll
        for (int j = 0; j < 8; ++j) tmp[j] = f2b(sacc[j]);
        *(short8*)(W3_pk + (size_t)(t*64 + lane)*8) = *(short8*)tmp;
        return;
    }

    const float* src; u16* dst; int lb; float scl = 1.f; bool addI = false;
    if      (b < 32)  { src = Wsrc; dst = Wsrc_pk; lb = b;       scl = TL2E; }
    else if (b < 64)  { src = Wsm;  dst = Wsm_pk;  lb = b - 32; }
    else if (b < 96)  { src = Wout; dst = W1_pk;   lb = b - 64;  addI = true; }
    else if (b < 128) { src = Wout2;dst = W2_pk;   lb = b - 96; }
    else              { src = We;   dst = We_pk;   lb = b - 128; scl = TL2E; }
    const int kc = lb >> 3, t = lb & 7;
    u16 tmp[8];
#pragma unroll
    for (int j = 0; j < 8; ++j) {
        const int i = kc*32 + quad*8 + j, jj = t*16 + ln;
        float v = src[(size_t)i*HD + jj] * scl;
        if (addI && i == jj) v += 1.f;
        tmp[j] = f2b(v);
    }
    *(short8*)(dst + (size_t)(lb*64 + lane)*8) = *(short8*)tmp;
}

// ---------------------------------------------------------------------------
// mega: block-range fusion, 512 threads (8 waves) per compute block:
//   [0, NBLK)    node: s1 tanh-dot + srcmsgb, 32 rows/wave (256 rows/block)
//   [NBLK, +HB4) hist: cnt[dst]++ / rank, 4 edges per thread
// (dst/s2 path deleted -- segment-constant in softmax.)
// ---------------------------------------------------------------------------
#define NBLK ((NSRC + 255) / 256)
#define HB4 ((NE/4 + 511) / 512)

__global__ __launch_bounds__(512) void mega_kernel(
    const float* __restrict__ src_x, const int* __restrict__ ei,
    const u16* __restrict__ Wsrc_pk, const u16* __restrict__ Wsm_pk,
    const float* __restrict__ bsrcs, const float* __restrict__ bsm,
    const float* __restrict__ wa1s,
    float* __restrict__ s1,
    u16* __restrict__ srcmsgb, int* __restrict__ cnt, int* __restrict__ rank)
{
    __shared__ __align__(16) u16 wlds[16384];      // 32 KB staged weights
    __shared__ __align__(16) u16 tlds[8][2048];    // 32 KB per-wave transpose
    const int t = threadIdx.x;
    const int blk = blockIdx.x;

    if (blk >= NBLK) {                   // ---- hist path (4 edges/thread)
        const int idx = (blk - NBLK) * 512 + t;
        if (idx < NE/4) {
            int4 d4 = ((const int4*)(ei + NE))[idx];
            int4 r4;
            r4.x = atomicAdd(&cnt[d4.x], 1);
            r4.y = atomicAdd(&cnt[d4.y], 1);
            r4.z = atomicAdd(&cnt[d4.z], 1);
            r4.w = atomicAdd(&cnt[d4.w], 1);
            ((int4*)rank)[idx] = r4;
        }
        return;
    }

    const int w = t >> 6, lane = t & 63;
    const int ln = lane & 15, quad = lane >> 4;
    int row0 = blk * 256 + w * 32;
    if (row0 > NSRC - 32) row0 = NSRC - 32;       // dup writes benign

    // x loads (2 row-tiles), converted to bf16 A-frags in-register
    const float* rp0 = src_x + (size_t)(row0 + ln)*HD;
    const float* rp1 = rp0 + (size_t)16*HD;
    short8 a0[4], a1[4];
#pragma unroll
    for (int kc = 0; kc < 4; ++kc) {
        float4 f0 = *(const float4*)(rp0 + kc*32 + quad*8);
        float4 f1 = *(const float4*)(rp0 + kc*32 + quad*8 + 4);
        float4 g0 = *(const float4*)(rp1 + kc*32 + quad*8);
        float4 g1 = *(const float4*)(rp1 + kc*32 + quad*8 + 4);
        u16 tb[8] = { f2b(f0.x), f2b(f0.y), f2b(f0.z), f2b(f0.w),
                      f2b(f1.x), f2b(f1.y), f2b(f1.z), f2b(f1.w) };
        a0[kc] = *(short8*)tb;
        u16 tc[8] = { f2b(g0.x), f2b(g0.y), f2b(g0.z), f2b(g0.w),
                      f2b(g1.x), f2b(g1.y), f2b(g1.z), f2b(g1.w) };
        a1[kc] = *(short8*)tc;
    }

    // stage Wsrc weights (32 KB, cooperative, coalesced 16B)
#pragma unroll
    for (int it = 0; it < 4; ++it) {
        short8 v = ld8(Wsrc_pk + (size_t)(it*512 + t)*8);
        *(short8*)(&wlds[(it*512 + t)*8]) = v;
    }
    __syncthreads();

    // ---- s1 tanh-dot (log2-domain; K0 cancels in softmax)
    float v0[4] = {0,0,0,0}, v1[4] = {0,0,0,0};
#pragma unroll
    for (int tt = 0; tt < 8; ++tt) {
        const float bb = bsrcs[tt*16 + ln];
        const float ww = wa1s[tt*16 + ln];
        f32x4 acc0 = {bb, bb, bb, bb};
        f32x4 acc1 = {bb, bb, bb, bb};
#pragma unroll
        for (int kc = 0; kc < 4; ++kc) {
            short8 bf = ld8(&wlds[(size_t)((kc*8 + tt)*64 + lane)*8]);
            acc0 = __builtin_amdgcn_mfma_f32_16x16x32_bf16(a0[kc], bf, acc0, 0, 0, 0);
            acc1 = __builtin_amdgcn_mfma_f32_16x16x32_bf16(a1[kc], bf, acc1, 0, 0, 0);
        }
#pragma unroll
        for (int r = 0; r < 4; ++r) {
            v0[r] = fmaf(ww, RCP(EXP2(acc0[r]) + 1.f), v0[r]);
            v1[r] = fmaf(ww, RCP(EXP2(acc1[r]) + 1.f), v1[r]);
        }
    }
#pragma unroll
    for (int off = 8; off >= 1; off >>= 1) {
#pragma unroll
        for (int r = 0; r < 4; ++r) {
            v0[r] += __shfl_xor(v0[r], off);
            v1[r] += __shfl_xor(v1[r], off);
        }
    }
    if (ln == 0) {
#pragma unroll
        for (int r = 0; r < 4; ++r) {
            s1[row0 + quad*4 + r]      = v0[r];
            s1[row0 + 16 + quad*4 + r] = v1[r];
        }
    }

    // ---- restage with Wsm, then srcmsg path
    __syncthreads();
#pragma unroll
    for (int it = 0; it < 4; ++it) {
        short8 v = ld8(Wsm_pk + (size_t)(it*512 + t)*8);
        *(short8*)(&wlds[(it*512 + t)*8]) = v;
    }
    __syncthreads();

    u16* slab = &tlds[w][0];
#pragma unroll
    for (int tile = 0; tile < 2; ++tile) {
#pragma unroll
        for (int tt = 0; tt < 8; ++tt) {
            const float bs = bsm[tt*16 + ln];
            f32x4 acc = {bs, bs, bs, bs};
#pragma unroll
            for (int kc = 0; kc < 4; ++kc) {
                short8 bf = ld8(&wlds[(size_t)((kc*8 + tt)*64 + lane)*8]);
                acc = __builtin_amdgcn_mfma_f32_16x16x32_bf16(
                          tile ? a1[kc] : a0[kc], bf, acc, 0, 0, 0);
            }
            // swizzled write: row = quad*4+r (row>>2 == quad), col blk tt^quad
#pragma unroll
            for (int r = 0; r < 4; ++r)
                slab[(quad*4 + r)*128 + ((tt ^ quad) << 4) + ln] = f2b(acc[r]);
        }
        // per-wave readback (DS in-order within wave; no barrier needed)
#pragma unroll
        for (int r2 = 0; r2 < 4; ++r2) {
            const int row = r2*4 + quad;          // row>>2 == r2
            const int c = ln*8;
            const int sidx = row*128 + (((c >> 4) ^ r2) << 4) + (c & 15);
            short8 val = *(const short8*)(&slab[sidx]);
            *(short8*)(srcmsgb + (size_t)(row0 + tile*16 + row)*HD + c) = val;
        }
    }
}

// ---------------------------------------------------------------------------
// scan1: per-1024-chunk exclusive scan of cnt into rowptr, block sums to bsum
// ---------------------------------------------------------------------------
__global__ __launch_bounds__(1024) void scan1_kernel(
    const int* __restrict__ cnt, int* __restrict__ excl, int* __restrict__ bsum)
{
    __shared__ int buf[1024];
    const int t = threadIdx.x;
    const int i = blockIdx.x * 1024 + t;
    int v = (i < NDST) ? cnt[i] : 0;
    buf[t] = v;
    __syncthreads();
    for (int off = 1; off < 1024; off <<= 1) {
        int tv = (t >= off) ? buf[t - off] : 0;
        __syncthreads();
        buf[t] += tv;
        __syncthreads();
    }
    if (i < NDST) excl[i] = buf[t] - v;
    if (t == 1023) bsum[blockIdx.x] = buf[1023];
}

// ---------------------------------------------------------------------------
// scan23: every block redundantly wave-scans the 49 chunk sums, then applies
// the offset to its rowptr slice.
// ---------------------------------------------------------------------------
__global__ __launch_bounds__(256) void scan23_kernel(
    const int* __restrict__ bsum, int* __restrict__ rowptr)
{
    __shared__ int pref[64];
    const int t = threadIdx.x;
    const int NB = (NDST + 1023) / 1024;     // 49
    if (t < 64) {
        int orig = (t < NB) ? bsum[t] : 0;
        int v = orig;
        for (int off = 1; off < 64; off <<= 1) {
            int u = __shfl_up(v, off);
            if (t >= off) v += u;
        }
        pref[t] = v - orig;                  // exclusive prefix
        if (blockIdx.x == 0 && t == NB - 1) rowptr[NDST] = v;  // total
    }
    __syncthreads();
    const int i = blockIdx.x * 256 + t;
    if (i < NDST) rowptr[i] += pref[i >> 10];
}

// ---------------------------------------------------------------------------
// edge_score: 64 edges / wave (4 A-tiles share each We B-frag). Tanh-dot in
// log2-domain; score = s1[src] + v_e (all segment-constant terms cancel in
// softmax). 15-cndmask select tree + ONE shfl -> fully 64-lane-parallel
// epilogue. Atomic-free slot = rowptr + rank.
// ---------------------------------------------------------------------------
__global__ __launch_bounds__(256) void edge_score_kernel(
    const int* __restrict__ ei, const float* __restrict__ eattr,
    const u16* __restrict__ We_pk, const float* __restrict__ bes,
    const float* __restrict__ wa3s,
    const float* __restrict__ s1,
    const int* __restrict__ rowptr, const int* __restrict__ rank,
    int4* __restrict__ ev16)
{
    const int t = threadIdx.x;
    const int w = t >> 6, lane = t & 63;
    const int ln = lane & 15, quad = lane >> 4;
    int e0 = (blockIdx.x * 4 + w) * 64;
    if (e0 > NE - 64) e0 = NE - 64;        // dup processing benign

    short8 a[4];
#pragma unroll
    for (int tl = 0; tl < 4; ++tl) {
        const float* ap = eattr + (size_t)(e0 + tl*16 + ln)*EDIM + quad*8;
        float4 f0 = *(const float4*)(ap);
        float4 f1 = *(const float4*)(ap + 4);
        u16 ab[8] = { f2b(f0.x), f2b(f0.y), f2b(f0.z), f2b(f0.w),
                      f2b(f1.x), f2b(f1.y), f2b(f1.z), f2b(f1.w) };
        a[tl] = *(short8*)ab;
    }

    float v0[4] = {0,0,0,0}, v1[4] = {0,0,0,0};
    float v2[4] = {0,0,0,0}, v3[4] = {0,0,0,0};
#pragma unroll
    for (int tt = 0; tt < 8; ++tt) {
        const float bb = bes[tt*16 + ln];
        const float ww = wa3s[tt*16 + ln];
        short8 b = ld8(We_pk + (size_t)(tt*64 + lane)*8);
        f32x4 ac0 = {bb, bb, bb, bb};
        f32x4 ac1 = {bb, bb, bb, bb};
        f32x4 ac2 = {bb, bb, bb, bb};
        f32x4 ac3 = {bb, bb, bb, bb};
        ac0 = __builtin_amdgcn_mfma_f32_16x16x32_bf16(a[0], b, ac0, 0, 0, 0);
        ac1 = __builtin_amdgcn_mfma_f32_16x16x32_bf16(a[1], b, ac1, 0, 0, 0);
        ac2 = __builtin_amdgcn_mfma_f32_16x16x32_bf16(a[2], b, ac2, 0, 0, 0);
        ac3 = __builtin_amdgcn_mfma_f32_16x16x32_bf16(a[3], b, ac3, 0, 0, 0);
#pragma unroll
        for (int r = 0; r < 4; ++r) {
            v0[r] = fmaf(ww, RCP(EXP2(ac0[r]) + 1.f), v0[r]);
            v1[r] = fmaf(ww, RCP(EXP2(ac1[r]) + 1.f), v1[r]);
            v2[r] = fmaf(ww, RCP(EXP2(ac2[r]) + 1.f), v2[r]);
            v3[r] = fmaf(ww, RCP(EXP2(ac3[r]) + 1.f), v3[r]);
        }
    }
    // reduce over the 16 feature lanes (ln) within each quad group
#pragma unroll
    for (int off = 8; off >= 1; off >>= 1) {
#pragma unroll
        for (int r = 0; r < 4; ++r) {
            v0[r] += __shfl_xor(v0[r], off);
            v1[r] += __shfl_xor(v1[r], off);
            v2[r] += __shfl_xor(v2[r], off);
            v3[r] += __shfl_xor(v3[r], off);
        }
    }
    // select tree: lane (quad q, ln) picks v_{ln>>2}[ln&3]
    const bool s0 = ln & 1, s1b = ln & 2, s2b = ln & 4, s3b = ln & 8;
    float m00 = s0 ? v0[1] : v0[0];
    float m01 = s0 ? v0[3] : v0[2];
    float m02 = s0 ? v1[1] : v1[0];
    float m03 = s0 ? v1[3] : v1[2];
    float m04 = s0 ? v2[1] : v2[0];
    float m05 = s0 ? v2[3] : v2[2];
    float m06 = s0 ? v3[1] : v3[0];
    float m07 = s0 ? v3[3] : v3[2];
    float m10 = s1b ? m01 : m00;
    float m11 = s1b ? m03 : m02;
    float m12 = s1b ? m05 : m04;
    float m13 = s1b ? m07 : m06;
    float m20 = s2b ? m11 : m10;
    float m21 = s2b ? m13 : m12;
    float selv = s3b ? m21 : m20;
    // lane l wants edge e0+l = (T=l>>4)*16 + (Q=(l>>2)&3)*4 + (R=l&3):
    // source lane = Q*16 + T*4 + R
    const int srcl = ((lane >> 2) & 3) * 16 + ((lane >> 4) << 2) + (lane & 3);
    const float myv = __shfl(selv, srcl);

    const int e = e0 + lane;
    const int srcn = ei[e];
    const int dstn = ei[NE + e];
    const float sc = s1[srcn] + myv;
    const int pos = rowptr[dstn] + rank[e];
    ev16[pos] = make_int4(srcn, e, __float_as_int(sc), 0);
}

// ---------------------------------------------------------------------------
// dst_agg: 1 wave per dst, single pass (no-max softmax): accumulate
// unnormalized w=exp2(sc), sum(w), sum(w*msg), sum(w*ea); normalize at end.
// msg row: 16 lanes x 16B bf16; ea row: 8 lanes x 16B f32 (one cache line).
// ---------------------------------------------------------------------------
__global__ __launch_bounds__(256) void dst_agg_kernel(
    const int4* __restrict__ ev16, const int* __restrict__ rowptr,
    const u16* __restrict__ srcmsgb, const float* __restrict__ eattr,
    const float* __restrict__ c2,
    u16* __restrict__ aggSb, u16* __restrict__ weab)
{
    const int lane = threadIdx.x & 63;
    const int d = blockIdx.x * 4 + (threadIdx.x >> 6);
    const int el = lane >> 4, c = lane & 15;
    const int start = rowptr[d], end = rowptr[d + 1];

    if (start == end) {
        if (el == 0) {
            u16 z[8];
#pragma unroll
            for (int j = 0; j < 8; ++j) z[j] = f2b(-c2[c*8 + j]);
            *(short8*)(aggSb + (size_t)d*HD + c*8) = *(short8*)z;
            if (c < 8) {
                u16 zz[4] = {0,0,0,0};
                *(ushort4*)(weab + (size_t)d*EDIM + c*4) = *(ushort4*)zz;
            }
        }
        return;
    }

    float sacc = 0.f;
    float acc[8]  = {0,0,0,0,0,0,0,0};
    float wacc[4] = {0,0,0,0};

    int icur = start + el;
    bool vcur = (icur < end);
    int iicur = vcur ? icur : start;
    int4 q = ev16[iicur];

    for (int i0 = start; i0 < end; i0 += 4) {
        const float wgt = vcur ? EXP2(__int_as_float(q.z)) : 0.f;
        const int   srow = q.x;
        const int   ecur = q.y;
        // prefetch next record (clamped; harmless re-read of ev16[start])
        const int inx = i0 + 4 + el;
        vcur = (inx < end);
        iicur = vcur ? inx : start;
        q = ev16[iicur];

        sacc += wgt;
        short8 sm = ld8(srcmsgb + (size_t)srow*HD + c*8);
#pragma unroll
        for (int j = 0; j < 8; ++j)
            acc[j] = fmaf(wgt, b2f(((u16*)&sm)[j]), acc[j]);
        if (c < 8) {
            float4 f = *(const float4*)(eattr + (size_t)ecur*EDIM + c*4);
            wacc[0] = fmaf(wgt, f.x, wacc[0]);
            wacc[1] = fmaf(wgt, f.y, wacc[1]);
            wacc[2] = fmaf(wgt, f.z, wacc[2]);
            wacc[3] = fmaf(wgt, f.w, wacc[3]);
        }
    }
#pragma unroll
    for (int off = 16; off <= 32; off <<= 1) {
        sacc += __shfl_xor(sacc, off);
#pragma unroll
        for (int j = 0; j < 8; ++j) acc[j] += __shfl_xor(acc[j], off);
#pragma unroll
        for (int j = 0; j < 4; ++j) wacc[j] += __shfl_xor(wacc[j], off);
    }
    const float inv = RCP(sacc);
    if (el == 0) {
        u16 o[8];
#pragma unroll
        for (int j = 0; j < 8; ++j) o[j] = f2b(acc[j] * inv);
        *(short8*)(aggSb + (size_t)d*HD + c*8) = *(short8*)o;
        if (c < 8) {
            u16 o2[4];
#pragma unroll
            for (int j = 0; j < 4; ++j) o2[j] = f2b(wacc[j] * inv);
            *(ushort4*)(weab + (size_t)d*EDIM + c*4) = *(ushort4*)o2;
        }
    }
}

// ---------------------------------------------------------------------------
// final: out = LN(dst_x@W1p + aggSb@Wout2 + weab@W3 + bias2) * gamma + beta
// per 16 dst rows / wave; dst_x read f32 + converted in-reg.
// ---------------------------------------------------------------------------
__global__ __launch_bounds__(256) void final_kernel(
    const float* __restrict__ dst_x, const u16* __restrict__ aggSb,
    const u16* __restrict__ weab,
    const u16* __restrict__ W1_pk, const u16* __restrict__ W2_pk,
    const u16* __restrict__ W3_pk, const float* __restrict__ bias2,
    const float* __restrict__ gamma, const float* __restrict__ beta,
    float* __restrict__ out)
{
    const int t = threadIdx.x;
    const int w = t >> 6, lane = t & 63;
    const int ln = lane & 15, quad = lane >> 4;
    int row0 = (blockIdx.x * 4 + w) * 16;
    if (row0 > NDST - 16) row0 = NDST - 16;

    const float* rp = dst_x + (size_t)(row0 + ln)*HD;
    short8 a1[4], a2[4], a3;
#pragma unroll
    for (int kc = 0; kc < 4; ++kc) {
        float4 f0 = *(const float4*)(rp + kc*32 + quad*8);
        float4 f1 = *(const float4*)(rp + kc*32 + quad*8 + 4);
        u16 tb[8] = { f2b(f0.x), f2b(f0.y), f2b(f0.z), f2b(f0.w),
                      f2b(f1.x), f2b(f1.y), f2b(f1.z), f2b(f1.w) };
        a1[kc] = *(short8*)tb;
        a2[kc] = ld8(aggSb + (size_t)(row0 + ln)*HD + kc*32 + quad*8);
    }
    a3 = ld8(weab + (size_t)(row0 + ln)*EDIM + quad*8);

    f32x4 accs[8];
#pragma unroll
    for (int tt = 0; tt < 8; ++tt) {
        const float bb = bias2[tt*16 + ln];
        f32x4 acc = {bb, bb, bb, bb};
#pragma unroll
        for (int kc = 0; kc < 4; ++kc) {
            short8 b = ld8(W1_pk + (size_t)((kc*8 + tt)*64 + lane)*8);
            acc = __builtin_amdgcn_mfma_f32_16x16x32_bf16(a1[kc], b, acc, 0, 0, 0);
        }
#pragma unroll
        for (int kc = 0; kc < 4; ++kc) {
            short8 b = ld8(W2_pk + (size_t)((kc*8 + tt)*64 + lane)*8);
            acc = __builtin_amdgcn_mfma_f32_16x16x32_bf16(a2[kc], b, acc, 0, 0, 0);
        }
        {
            short8 b = ld8(W3_pk + (size_t)(tt*64 + lane)*8);
            acc = __builtin_amdgcn_mfma_f32_16x16x32_bf16(a3, b, acc, 0, 0, 0);
        }
        accs[tt] = acc;
    }

    const float gl[8] = { gamma[ln], gamma[16+ln], gamma[32+ln], gamma[48+ln],
                          gamma[64+ln], gamma[80+ln], gamma[96+ln], gamma[112+ln] };
    const float bl[8] = { beta[ln], beta[16+ln], beta[32+ln], beta[48+ln],
                          beta[64+ln], beta[80+ln], beta[96+ln], beta[112+ln] };
#pragma unroll
    for (int r = 0; r < 4; ++r) {
        float s = 0.f, qq = 0.f;
#pragma unroll
        for (int tt = 0; tt < 8; ++tt) {
            float u = accs[tt][r];
            s += u; qq += u*u;
        }
#pragma unroll
        for (int off = 8; off >= 1; off >>= 1) {
            s  += __shfl_xor(s, off);
            qq += __shfl_xor(qq, off);
        }
        const float mean = s * (1.f / HD);
        const float var  = qq * (1.f / HD) - mean * mean;
        const float rstd = rsqrtf(var + LN_EPS);
        const int row = row0 + quad*4 + r;
#pragma unroll
        for (int tt = 0; tt < 8; ++tt)
            out[(size_t)row*HD + tt*16 + ln] =
                (accs[tt][r] - mean) * rstd * gl[tt] + bl[tt];
    }
}

// ---------------------------------------------------------------------------
extern "C" void kernel_launch(void* const* d_in, const int* in_sizes, int n_in,
                              void* d_out, int out_size, void* d_ws, size_t ws_size,
                              hipStream_t stream)
{
    const float* src_x = (const float*)d_in[0];
    const float* dst_x = (const float*)d_in[1];
    const int*   ei    = (const int*)d_in[2];
    const float* eattr = (const float*)d_in[3];
    const float* Wsrc  = (const float*)d_in[4];
    const float* bsrc  = (const float*)d_in[5];
    const float* We    = (const float*)d_in[8];
    const float* be    = (const float*)d_in[9];
    const float* Wattn = (const float*)d_in[10];
    const float* Wmsg  = (const float*)d_in[12];
    const float* bmsg  = (const float*)d_in[13];
    const float* Wout  = (const float*)d_in[14];
    const float* bout  = (const float*)d_in[15];
    const float* gamma = (const float*)d_in[16];
    const float* beta  = (const float*)d_in[17];
    float* out = (float*)d_out;

    float* ws = (float*)d_ws;
    u16* srcmsgb = (u16*)(ws + 0);            // 6.4M u16
    u16* aggSb   = (u16*)(ws + 3200000);      // 6.4M u16
    u16* weab    = (u16*)(ws + 6400000);      // 1.6M u16
    float* s1    = ws + 7200000;              // 50048
    float* Wsm   = ws + 7250048;              // 16384
    float* bsm   = ws + 7266432;              // 128
    float* WeMsg = ws + 7266560;              // 4096
    float* c2    = ws + 7270656;              // 128
    float* bias2 = ws + 7270784;              // 128
    u16* Wsrc_pk = (u16*)(ws + 7270912);      // 16384 u16
    u16* Wsm_pk  = (u16*)(ws + 7279104);
    u16* W1_pk   = (u16*)(ws + 7287296);
    u16* W2_pk   = (u16*)(ws + 7295488);
    u16* We_pk   = (u16*)(ws + 7303680);      // 4096 u16
    u16* W3_pk   = (u16*)(ws + 7305728);      // 4096 u16
    int* rowptr  = (int*)(ws + 7307776);      // 50016
    int* cnt     = (int*)(ws + 7357792);      // 50016
    int* bsum    = (int*)(ws + 7407808);      // 64
    int* rank    = (int*)(ws + 7407872);      // 500000
    int4* ev16   = (int4*)(ws + 7907872);     // 500000 int4 (16B-aligned)
    float* wa1s  = ws + 9907872;              // 128
    float* wa3s  = ws + 9908000;              // 128
    float* bsrcs = ws + 9908128;              // 128
    float* bes   = ws + 9908256;              // 128

    fold1_kernel<<<553, 128, 0, stream>>>(Wsrc, bsrc, We, be, Wmsg, bmsg,
                                          Wsm, bsm, WeMsg, c2, cnt);
    pack_all_kernel<<<146, 64, 0, stream>>>(Wsrc, Wsm, Wout, We, WeMsg, c2,
                                            bout, bsrc, be, Wattn,
                                            Wsrc_pk, Wsm_pk, W1_pk, W2_pk,
                                            We_pk, W3_pk, bias2,
                                            wa1s, wa3s, bsrcs, bes);

    mega_kernel<<<NBLK + HB4, 512, 0, stream>>>(
        src_x, ei, Wsrc_pk, Wsm_pk, bsrcs, bsm, wa1s,
        s1, srcmsgb, cnt, rank);

    scan1_kernel<<<(NDST + 1023) / 1024, 1024, 0, stream>>>(cnt, rowptr, bsum);
    scan23_kernel<<<(NDST + 255) / 256, 256, 0, stream>>>(bsum, rowptr);

    edge_score_kernel<<<((NE + 63)/64 + 3) / 4, 256, 0, stream>>>(
        ei, eattr, We_pk, bes, wa3s, s1, rowptr, rank, ev16);

    dst_agg_kernel<<<NDST / 4, 256, 0, stream>>>(ev16, rowptr, srcmsgb,
                                                 eattr, c2, aggSb, weab);

    final_kernel<<<(NDST/16 + 3) / 4, 256, 0, stream>>>(
        dst_x, aggSb, weab, W1_pk, W2_pk, W3_pk, bias2, gamma, beta, out);
}

// Round 9
// 275.140 us; speedup vs baseline: 1.7914x; 1.0318x over previous
//
#include <hip/hip_runtime.h>
#include <math.h>

#define NSRC 50000
#define NDST 50000
#define NE   500000
#define HD   128
#define EDIM 32
#define LN_EPS 1e-5f

typedef __attribute__((ext_vector_type(8))) short short8;   // 8 bf16 = 4 VGPR
typedef __attribute__((ext_vector_type(4))) float f32x4;
typedef unsigned short u16;

#define TL2E 2.8853900817779268f   /* 2*log2(e) */
#define L2E  1.4426950408889634f   /* log2(e)   */

__device__ __forceinline__ float EXP2(float x) {
#if __has_builtin(__builtin_amdgcn_exp2f)
    return __builtin_amdgcn_exp2f(x);
#else
    return exp2f(x);
#endif
}
__device__ __forceinline__ float RCP(float x) {
#if __has_builtin(__builtin_amdgcn_rcpf)
    return __builtin_amdgcn_rcpf(x);
#else
    return 1.f / x;
#endif
}
__device__ __forceinline__ u16 f2b(float x) {           // f32 -> bf16 RNE
    unsigned u = __float_as_uint(x);
    return (u16)((u + 0x7FFFu + ((u >> 16) & 1u)) >> 16);
}
__device__ __forceinline__ float b2f(u16 h) {
    return __uint_as_float(((unsigned)h) << 16);
}
__device__ __forceinline__ short8 ld8(const u16* p) { return *(const short8*)p; }

// ---------------------------------------------------------------------------
// fold1: Wsm = Wsrc@Wmsg, bsm = bsrc@Wmsg + bmsg, WeMsg = We@Wmsg, c2 = be@Wmsg
// (128 threads span output column j -> coalesced Wmsg reads, 1 dot/thread).
// Blocks r >= 162 zero the histogram counters (replaces memset launch).
// ---------------------------------------------------------------------------
__global__ __launch_bounds__(128) void fold1_kernel(
    const float* __restrict__ Wsrc, const float* __restrict__ bsrc,
    const float* __restrict__ We,   const float* __restrict__ be,
    const float* __restrict__ Wmsg, const float* __restrict__ bmsg,
    float* __restrict__ Wsm, float* __restrict__ bsm,
    float* __restrict__ WeMsg, float* __restrict__ c2,
    int* __restrict__ cnt)
{
    const int j = threadIdx.x;
    const int r = blockIdx.x;
    if (r >= 162) {
        int i = (r - 162) * 128 + j;
        if (i < NDST + 16) cnt[i] = 0;
        return;
    }
    float s = 0.f;
    if (r < 128) {
        for (int k = 0; k < 128; ++k) s += Wsrc[r*HD + k] * Wmsg[k*HD + j];
        Wsm[r*HD + j] = s;
    } else if (r < 160) {
        const int rr = r - 128;
        for (int k = 0; k < 128; ++k) s += We[rr*HD + k] * Wmsg[k*HD + j];
        WeMsg[rr*HD + j] = s;
    } else if (r == 160) {
        for (int k = 0; k < 128; ++k) s += bsrc[k] * Wmsg[k*HD + j];
        bsm[j] = s + bmsg[j];
    } else {
        for (int k = 0; k < 128; ++k) s += be[k] * Wmsg[k*HD + j];
        c2[j] = s;
    }
}

// ---------------------------------------------------------------------------
// pack_all: pack f32 [K x 128] weights into bf16 MFMA B-fragment layout.
// Wsrc/We pre-scaled by 2*log2(e) (tanh-dot exp2/rcp refactor). Wdst path
// deleted (softmax shift-invariance: s2 and segment constants cancel).
// blocks: Wsrc 0-31, Wsm 32-63, W1(+I) 64-95, W2 96-127, We 128-135 (K=32),
//         W3 136-143 (computed), bias2 144, scale-folds 145.
// ---------------------------------------------------------------------------
__global__ __launch_bounds__(64) void pack_all_kernel(
    const float* __restrict__ Wsrc, const float* __restrict__ Wsm,
    const float* __restrict__ Wout, const float* __restrict__ We,
    const float* __restrict__ WeMsg, const float* __restrict__ c2,
    const float* __restrict__ bout, const float* __restrict__ bsrc,
    const float* __restrict__ be,   const float* __restrict__ wattn,
    u16* __restrict__ Wsrc_pk, u16* __restrict__ Wsm_pk,
    u16* __restrict__ W1_pk,   u16* __restrict__ W2_pk,
    u16* __restrict__ We_pk,   u16* __restrict__ W3_pk,
    float* __restrict__ bias2,
    float* __restrict__ wa1s, float* __restrict__ wa3s,
    float* __restrict__ bsrcs, float* __restrict__ bes)
{
    const int b = blockIdx.x;
    const int lane = threadIdx.x;
    const int ln = lane & 15, quad = lane >> 4;
    const float* Wout2 = Wout + HD*HD;

    if (b == 145) {                        // scale folds (no sums: K cancels)
#pragma unroll
        for (int h = 0; h < 2; ++h) {
            const int col = lane + h*64;
            wa1s[col] = wattn[col]        * (-2.f * L2E);
            wa3s[col] = wattn[2*HD + col] * (-2.f * L2E);
            bsrcs[col] = bsrc[col] * TL2E;
            bes[col]   = be[col]   * TL2E;
        }
        return;
    }
    if (b == 144) {                        // bias2 = bout + c2@Wout2
#pragma unroll
        for (int h = 0; h < 2; ++h) {
            const int col = lane + h*64;
            float s = 0.f;
            for (int k = 0; k < 128; ++k) s += c2[k] * Wout2[k*HD + col];
            bias2[col] = bout[col] + s;
        }
        return;
    }
    if (b >= 136) {                        // W3 = WeMsg@Wout2 (32x128), packed
        const int t = b - 136;
        const int jj = t*16 + ln;
        float sacc[8] = {0,0,0,0,0,0,0,0};
        for (int k = 0; k < 128; ++k) {
            const float w2 = Wout2[k*HD + jj];
#pragma unroll
            for (int j = 0; j < 8; ++j)
                sacc[j] = fmaf(WeMsg[(quad*8 + j)*HD + k], w2, sacc[j]);
        }
        u16 tmp[8];
#pragma unroll
        for (int j = 0; j < 8; ++j) tmp[j] = f2b(sacc[j]);
        *(short8*)(W3_pk + (size_t)(t*64 + lane)*8) = *(short8*)tmp;
        return;
    }

    const float* src; u16* dst; int lb; float scl = 1.f; bool addI = false;
    if      (b < 32)  { src = Wsrc; dst = Wsrc_pk; lb = b;       scl = TL2E; }
    else if (b < 64)  { src = Wsm;  dst = Wsm_pk;  lb = b - 32; }
    else if (b < 96)  { src = Wout; dst = W1_pk;   lb = b - 64;  addI = true; }
    else if (b < 128) { src = Wout2;dst = W2_pk;   lb = b - 96; }
    else              { src = We;   dst = We_pk;   lb = b - 128; scl = TL2E; }
    const int kc = lb >> 3, t = lb & 7;
    u16 tmp[8];
#pragma unroll
    for (int j = 0; j < 8; ++j) {
        const int i = kc*32 + quad*8 + j, jj = t*16 + ln;
        float v = src[(size_t)i*HD + jj] * scl;
        if (addI && i == jj) v += 1.f;
        tmp[j] = f2b(v);
    }
    *(short8*)(dst + (size_t)(lb*64 + lane)*8) = *(short8*)tmp;
}

// ---------------------------------------------------------------------------
// mega: block-range fusion, 512 threads (8 waves) per compute block:
//   [0, NBLK)    node: s1 tanh-dot + srcmsgb, 32 rows/wave (256 rows/block)
//   [NBLK, +HB4) hist: cnt[dst]++ / rank, 4 edges per thread
// ---------------------------------------------------------------------------
#define NBLK ((NSRC + 255) / 256)
#define HB4 ((NE/4 + 511) / 512)

__global__ __launch_bounds__(512) void mega_kernel(
    const float* __restrict__ src_x, const int* __restrict__ ei,
    const u16* __restrict__ Wsrc_pk, const u16* __restrict__ Wsm_pk,
    const float* __restrict__ bsrcs, const float* __restrict__ bsm,
    const float* __restrict__ wa1s,
    float* __restrict__ s1,
    u16* __restrict__ srcmsgb, int* __restrict__ cnt, int* __restrict__ rank)
{
    __shared__ __align__(16) u16 wlds[16384];      // 32 KB staged weights
    __shared__ __align__(16) u16 tlds[8][2048];    // 32 KB per-wave transpose
    const int t = threadIdx.x;
    const int blk = blockIdx.x;

    if (blk >= NBLK) {                   // ---- hist path (4 edges/thread)
        const int idx = (blk - NBLK) * 512 + t;
        if (idx < NE/4) {
            int4 d4 = ((const int4*)(ei + NE))[idx];
            int4 r4;
            r4.x = atomicAdd(&cnt[d4.x], 1);
            r4.y = atomicAdd(&cnt[d4.y], 1);
            r4.z = atomicAdd(&cnt[d4.z], 1);
            r4.w = atomicAdd(&cnt[d4.w], 1);
            ((int4*)rank)[idx] = r4;
        }
        return;
    }

    const int w = t >> 6, lane = t & 63;
    const int ln = lane & 15, quad = lane >> 4;
    int row0 = blk * 256 + w * 32;
    if (row0 > NSRC - 32) row0 = NSRC - 32;       // dup writes benign

    // x loads (2 row-tiles), converted to bf16 A-frags in-register
    const float* rp0 = src_x + (size_t)(row0 + ln)*HD;
    const float* rp1 = rp0 + (size_t)16*HD;
    short8 a0[4], a1[4];
#pragma unroll
    for (int kc = 0; kc < 4; ++kc) {
        float4 f0 = *(const float4*)(rp0 + kc*32 + quad*8);
        float4 f1 = *(const float4*)(rp0 + kc*32 + quad*8 + 4);
        float4 g0 = *(const float4*)(rp1 + kc*32 + quad*8);
        float4 g1 = *(const float4*)(rp1 + kc*32 + quad*8 + 4);
        u16 tb[8] = { f2b(f0.x), f2b(f0.y), f2b(f0.z), f2b(f0.w),
                      f2b(f1.x), f2b(f1.y), f2b(f1.z), f2b(f1.w) };
        a0[kc] = *(short8*)tb;
        u16 tc[8] = { f2b(g0.x), f2b(g0.y), f2b(g0.z), f2b(g0.w),
                      f2b(g1.x), f2b(g1.y), f2b(g1.z), f2b(g1.w) };
        a1[kc] = *(short8*)tc;
    }

    // stage Wsrc weights (32 KB, cooperative, coalesced 16B)
#pragma unroll
    for (int it = 0; it < 4; ++it) {
        short8 v = ld8(Wsrc_pk + (size_t)(it*512 + t)*8);
        *(short8*)(&wlds[(it*512 + t)*8]) = v;
    }
    __syncthreads();

    // ---- s1 tanh-dot (log2-domain; K0 cancels in softmax)
    float v0[4] = {0,0,0,0}, v1[4] = {0,0,0,0};
#pragma unroll
    for (int tt = 0; tt < 8; ++tt) {
        const float bb = bsrcs[tt*16 + ln];
        const float ww = wa1s[tt*16 + ln];
        f32x4 acc0 = {bb, bb, bb, bb};
        f32x4 acc1 = {bb, bb, bb, bb};
#pragma unroll
        for (int kc = 0; kc < 4; ++kc) {
            short8 bf = ld8(&wlds[(size_t)((kc*8 + tt)*64 + lane)*8]);
            acc0 = __builtin_amdgcn_mfma_f32_16x16x32_bf16(a0[kc], bf, acc0, 0, 0, 0);
            acc1 = __builtin_amdgcn_mfma_f32_16x16x32_bf16(a1[kc], bf, acc1, 0, 0, 0);
        }
#pragma unroll
        for (int r = 0; r < 4; ++r) {
            v0[r] = fmaf(ww, RCP(EXP2(acc0[r]) + 1.f), v0[r]);
            v1[r] = fmaf(ww, RCP(EXP2(acc1[r]) + 1.f), v1[r]);
        }
    }
#pragma unroll
    for (int off = 8; off >= 1; off >>= 1) {
#pragma unroll
        for (int r = 0; r < 4; ++r) {
            v0[r] += __shfl_xor(v0[r], off);
            v1[r] += __shfl_xor(v1[r], off);
        }
    }
    if (ln == 0) {
#pragma unroll
        for (int r = 0; r < 4; ++r) {
            s1[row0 + quad*4 + r]      = v0[r];
            s1[row0 + 16 + quad*4 + r] = v1[r];
        }
    }

    // ---- restage with Wsm, then srcmsg path
    __syncthreads();
#pragma unroll
    for (int it = 0; it < 4; ++it) {
        short8 v = ld8(Wsm_pk + (size_t)(it*512 + t)*8);
        *(short8*)(&wlds[(it*512 + t)*8]) = v;
    }
    __syncthreads();

    u16* slab = &tlds[w][0];
#pragma unroll
    for (int tile = 0; tile < 2; ++tile) {
#pragma unroll
        for (int tt = 0; tt < 8; ++tt) {
            const float bs = bsm[tt*16 + ln];
            f32x4 acc = {bs, bs, bs, bs};
#pragma unroll
            for (int kc = 0; kc < 4; ++kc) {
                short8 bf = ld8(&wlds[(size_t)((kc*8 + tt)*64 + lane)*8]);
                acc = __builtin_amdgcn_mfma_f32_16x16x32_bf16(
                          tile ? a1[kc] : a0[kc], bf, acc, 0, 0, 0);
            }
            // swizzled write: row = quad*4+r (row>>2 == quad), col blk tt^quad
#pragma unroll
            for (int r = 0; r < 4; ++r)
                slab[(quad*4 + r)*128 + ((tt ^ quad) << 4) + ln] = f2b(acc[r]);
        }
        // per-wave readback (DS in-order within wave; no barrier needed)
#pragma unroll
        for (int r2 = 0; r2 < 4; ++r2) {
            const int row = r2*4 + quad;          // row>>2 == r2
            const int c = ln*8;
            const int sidx = row*128 + (((c >> 4) ^ r2) << 4) + (c & 15);
            short8 val = *(const short8*)(&slab[sidx]);
            *(short8*)(srcmsgb + (size_t)(row0 + tile*16 + row)*HD + c) = val;
        }
    }
}

// ---------------------------------------------------------------------------
// scan1: per-1024-chunk exclusive scan of cnt into rowptr, block sums to bsum
// ---------------------------------------------------------------------------
__global__ __launch_bounds__(1024) void scan1_kernel(
    const int* __restrict__ cnt, int* __restrict__ excl, int* __restrict__ bsum)
{
    __shared__ int buf[1024];
    const int t = threadIdx.x;
    const int i = blockIdx.x * 1024 + t;
    int v = (i < NDST) ? cnt[i] : 0;
    buf[t] = v;
    __syncthreads();
    for (int off = 1; off < 1024; off <<= 1) {
        int tv = (t >= off) ? buf[t - off] : 0;
        __syncthreads();
        buf[t] += tv;
        __syncthreads();
    }
    if (i < NDST) excl[i] = buf[t] - v;
    if (t == 1023) bsum[blockIdx.x] = buf[1023];
}

// ---------------------------------------------------------------------------
// scan23: every block redundantly wave-scans the 49 chunk sums, then applies
// the offset to its rowptr slice.
// ---------------------------------------------------------------------------
__global__ __launch_bounds__(256) void scan23_kernel(
    const int* __restrict__ bsum, int* __restrict__ rowptr)
{
    __shared__ int pref[64];
    const int t = threadIdx.x;
    const int NB = (NDST + 1023) / 1024;     // 49
    if (t < 64) {
        int orig = (t < NB) ? bsum[t] : 0;
        int v = orig;
        for (int off = 1; off < 64; off <<= 1) {
            int u = __shfl_up(v, off);
            if (t >= off) v += u;
        }
        pref[t] = v - orig;                  // exclusive prefix
        if (blockIdx.x == 0 && t == NB - 1) rowptr[NDST] = v;  // total
    }
    __syncthreads();
    const int i = blockIdx.x * 256 + t;
    if (i < NDST) rowptr[i] += pref[i >> 10];
}

// ---------------------------------------------------------------------------
// edge_score: 64 edges / wave (4 A-tiles share each We B-frag). Tanh-dot in
// log2-domain; score = s1[src] + v_e. __launch_bounds__(256,4) caps the
// unified VGPR+AGPR budget at 128 regs -> >=4 waves/EU resident (was 28%
// occupancy; hidden AGPR use capped residency). 15-cndmask select tree +
// ONE shfl -> fully 64-lane-parallel epilogue. Atomic-free slot.
// ---------------------------------------------------------------------------
__global__ __launch_bounds__(256, 4) void edge_score_kernel(
    const int* __restrict__ ei, const float* __restrict__ eattr,
    const u16* __restrict__ We_pk, const float* __restrict__ bes,
    const float* __restrict__ wa3s,
    const float* __restrict__ s1,
    const int* __restrict__ rowptr, const int* __restrict__ rank,
    int4* __restrict__ ev16)
{
    const int t = threadIdx.x;
    const int w = t >> 6, lane = t & 63;
    const int ln = lane & 15, quad = lane >> 4;
    int e0 = (blockIdx.x * 4 + w) * 64;
    if (e0 > NE - 64) e0 = NE - 64;        // dup processing benign

    short8 a[4];
#pragma unroll
    for (int tl = 0; tl < 4; ++tl) {
        const float* ap = eattr + (size_t)(e0 + tl*16 + ln)*EDIM + quad*8;
        float4 f0 = *(const float4*)(ap);
        float4 f1 = *(const float4*)(ap + 4);
        u16 ab[8] = { f2b(f0.x), f2b(f0.y), f2b(f0.z), f2b(f0.w),
                      f2b(f1.x), f2b(f1.y), f2b(f1.z), f2b(f1.w) };
        a[tl] = *(short8*)ab;
    }

    float v0[4] = {0,0,0,0}, v1[4] = {0,0,0,0};
    float v2[4] = {0,0,0,0}, v3[4] = {0,0,0,0};
#pragma unroll
    for (int tt = 0; tt < 8; ++tt) {
        const float bb = bes[tt*16 + ln];
        const float ww = wa3s[tt*16 + ln];
        short8 b = ld8(We_pk + (size_t)(tt*64 + lane)*8);
        f32x4 ac0 = {bb, bb, bb, bb};
        f32x4 ac1 = {bb, bb, bb, bb};
        f32x4 ac2 = {bb, bb, bb, bb};
        f32x4 ac3 = {bb, bb, bb, bb};
        ac0 = __builtin_amdgcn_mfma_f32_16x16x32_bf16(a[0], b, ac0, 0, 0, 0);
        ac1 = __builtin_amdgcn_mfma_f32_16x16x32_bf16(a[1], b, ac1, 0, 0, 0);
        ac2 = __builtin_amdgcn_mfma_f32_16x16x32_bf16(a[2], b, ac2, 0, 0, 0);
        ac3 = __builtin_amdgcn_mfma_f32_16x16x32_bf16(a[3], b, ac3, 0, 0, 0);
#pragma unroll
        for (int r = 0; r < 4; ++r) {
            v0[r] = fmaf(ww, RCP(EXP2(ac0[r]) + 1.f), v0[r]);
            v1[r] = fmaf(ww, RCP(EXP2(ac1[r]) + 1.f), v1[r]);
            v2[r] = fmaf(ww, RCP(EXP2(ac2[r]) + 1.f), v2[r]);
            v3[r] = fmaf(ww, RCP(EXP2(ac3[r]) + 1.f), v3[r]);
        }
    }
    // reduce over the 16 feature lanes (ln) within each quad group
#pragma unroll
    for (int off = 8; off >= 1; off >>= 1) {
#pragma unroll
        for (int r = 0; r < 4; ++r) {
            v0[r] += __shfl_xor(v0[r], off);
            v1[r] += __shfl_xor(v1[r], off);
            v2[r] += __shfl_xor(v2[r], off);
            v3[r] += __shfl_xor(v3[r], off);
        }
    }
    // select tree: lane (quad q, ln) picks v_{ln>>2}[ln&3]
    const bool s0 = ln & 1, s1b = ln & 2, s2b = ln & 4, s3b = ln & 8;
    float m00 = s0 ? v0[1] : v0[0];
    float m01 = s0 ? v0[3] : v0[2];
    float m02 = s0 ? v1[1] : v1[0];
    float m03 = s0 ? v1[3] : v1[2];
    float m04 = s0 ? v2[1] : v2[0];
    float m05 = s0 ? v2[3] : v2[2];
    float m06 = s0 ? v3[1] : v3[0];
    float m07 = s0 ? v3[3] : v3[2];
    float m10 = s1b ? m01 : m00;
    float m11 = s1b ? m03 : m02;
    float m12 = s1b ? m05 : m04;
    float m13 = s1b ? m07 : m06;
    float m20 = s2b ? m11 : m10;
    float m21 = s2b ? m13 : m12;
    float selv = s3b ? m21 : m20;
    // lane l wants edge e0+l = (T=l>>4)*16 + (Q=(l>>2)&3)*4 + (R=l&3):
    // source lane = Q*16 + T*4 + R
    const int srcl = ((lane >> 2) & 3) * 16 + ((lane >> 4) << 2) + (lane & 3);
    const float myv = __shfl(selv, srcl);

    const int e = e0 + lane;
    const int srcn = ei[e];
    const int dstn = ei[NE + e];
    const float sc = s1[srcn] + myv;
    const int pos = rowptr[dstn] + rank[e];
    ev16[pos] = make_int4(srcn, e, __float_as_int(sc), 0);
}

// ---------------------------------------------------------------------------
// dst_agg: 1 wave per dst, single pass (no-max softmax): accumulate
// unnormalized w=exp2(sc), sum(w), sum(w*msg), sum(w*ea); normalize at end.
// msg row: 16 lanes x 16B bf16; ea row: 8 lanes x 16B f32 (one cache line).
// ---------------------------------------------------------------------------
__global__ __launch_bounds__(256) void dst_agg_kernel(
    const int4* __restrict__ ev16, const int* __restrict__ rowptr,
    const u16* __restrict__ srcmsgb, const float* __restrict__ eattr,
    const float* __restrict__ c2,
    u16* __restrict__ aggSb, u16* __restrict__ weab)
{
    const int lane = threadIdx.x & 63;
    const int d = blockIdx.x * 4 + (threadIdx.x >> 6);
    const int el = lane >> 4, c = lane & 15;
    const int start = rowptr[d], end = rowptr[d + 1];

    if (start == end) {
        if (el == 0) {
            u16 z[8];
#pragma unroll
            for (int j = 0; j < 8; ++j) z[j] = f2b(-c2[c*8 + j]);
            *(short8*)(aggSb + (size_t)d*HD + c*8) = *(short8*)z;
            if (c < 8) {
                u16 zz[4] = {0,0,0,0};
                *(ushort4*)(weab + (size_t)d*EDIM + c*4) = *(ushort4*)zz;
            }
        }
        return;
    }

    float sacc = 0.f;
    float acc[8]  = {0,0,0,0,0,0,0,0};
    float wacc[4] = {0,0,0,0};

    int icur = start + el;
    bool vcur = (icur < end);
    int iicur = vcur ? icur : start;
    int4 q = ev16[iicur];

    for (int i0 = start; i0 < end; i0 += 4) {
        const float wgt = vcur ? EXP2(__int_as_float(q.z)) : 0.f;
        const int   srow = q.x;
        const int   ecur = q.y;
        // prefetch next record (clamped; harmless re-read of ev16[start])
        const int inx = i0 + 4 + el;
        vcur = (inx < end);
        iicur = vcur ? inx : start;
        q = ev16[iicur];

        sacc += wgt;
        short8 sm = ld8(srcmsgb + (size_t)srow*HD + c*8);
#pragma unroll
        for (int j = 0; j < 8; ++j)
            acc[j] = fmaf(wgt, b2f(((u16*)&sm)[j]), acc[j]);
        if (c < 8) {
            float4 f = *(const float4*)(eattr + (size_t)ecur*EDIM + c*4);
            wacc[0] = fmaf(wgt, f.x, wacc[0]);
            wacc[1] = fmaf(wgt, f.y, wacc[1]);
            wacc[2] = fmaf(wgt, f.z, wacc[2]);
            wacc[3] = fmaf(wgt, f.w, wacc[3]);
        }
    }
#pragma unroll
    for (int off = 16; off <= 32; off <<= 1) {
        sacc += __shfl_xor(sacc, off);
#pragma unroll
        for (int j = 0; j < 8; ++j) acc[j] += __shfl_xor(acc[j], off);
#pragma unroll
        for (int j = 0; j < 4; ++j) wacc[j] += __shfl_xor(wacc[j], off);
    }
    const float inv = RCP(sacc);
    if (el == 0) {
        u16 o[8];
#pragma unroll
        for (int j = 0; j < 8; ++j) o[j] = f2b(acc[j] * inv);
        *(short8*)(aggSb + (size_t)d*HD + c*8) = *(short8*)o;
        if (c < 8) {
            u16 o2[4];
#pragma unroll
            for (int j = 0; j < 4; ++j) o2[j] = f2b(wacc[j] * inv);
            *(ushort4*)(weab + (size_t)d*EDIM + c*4) = *(ushort4*)o2;
        }
    }
}

// ---------------------------------------------------------------------------
// final: out = LN(dst_x@W1p + aggSb@Wout2 + weab@W3 + bias2) * gamma + beta
// per 16 dst rows / wave. W1/W2 LDS-staged per block (mega-style, reused
// buffer) -> B-frags from conflict-free ds_read_b128 instead of L1-thrashing
// 72KB-per-wave global streams. W3 (8KB) stays global/L1. accs persist in
// registers across the restage.
// ---------------------------------------------------------------------------
__global__ __launch_bounds__(256) void final_kernel(
    const float* __restrict__ dst_x, const u16* __restrict__ aggSb,
    const u16* __restrict__ weab,
    const u16* __restrict__ W1_pk, const u16* __restrict__ W2_pk,
    const u16* __restrict__ W3_pk, const float* __restrict__ bias2,
    const float* __restrict__ gamma, const float* __restrict__ beta,
    float* __restrict__ out)
{
    __shared__ __align__(16) u16 wlds[16384];      // 32 KB staged weights
    const int t = threadIdx.x;
    const int w = t >> 6, lane = t & 63;
    const int ln = lane & 15, quad = lane >> 4;
    int row0 = (blockIdx.x * 4 + w) * 16;
    if (row0 > NDST - 16) row0 = NDST - 16;

    const float* rp = dst_x + (size_t)(row0 + ln)*HD;
    short8 a1[4], a2[4], a3;
#pragma unroll
    for (int kc = 0; kc < 4; ++kc) {
        float4 f0 = *(const float4*)(rp + kc*32 + quad*8);
        float4 f1 = *(const float4*)(rp + kc*32 + quad*8 + 4);
        u16 tb[8] = { f2b(f0.x), f2b(f0.y), f2b(f0.z), f2b(f0.w),
                      f2b(f1.x), f2b(f1.y), f2b(f1.z), f2b(f1.w) };
        a1[kc] = *(short8*)tb;
        a2[kc] = ld8(aggSb + (size_t)(row0 + ln)*HD + kc*32 + quad*8);
    }
    a3 = ld8(weab + (size_t)(row0 + ln)*EDIM + quad*8);

    // stage W1 (32 KB, cooperative)
#pragma unroll
    for (int it = 0; it < 8; ++it) {
        short8 v = ld8(W1_pk + (size_t)(it*256 + t)*8);
        *(short8*)(&wlds[(it*256 + t)*8]) = v;
    }
    __syncthreads();

    f32x4 accs[8];
#pragma unroll
    for (int tt = 0; tt < 8; ++tt) {
        const float bb = bias2[tt*16 + ln];
        f32x4 acc = {bb, bb, bb, bb};
#pragma unroll
        for (int kc = 0; kc < 4; ++kc) {
            short8 b = ld8(&wlds[(size_t)((kc*8 + tt)*64 + lane)*8]);
            acc = __builtin_amdgcn_mfma_f32_16x16x32_bf16(a1[kc], b, acc, 0, 0, 0);
        }
        accs[tt] = acc;
    }

    // restage with W2
    __syncthreads();
#pragma unroll
    for (int it = 0; it < 8; ++it) {
        short8 v = ld8(W2_pk + (size_t)(it*256 + t)*8);
        *(short8*)(&wlds[(it*256 + t)*8]) = v;
    }
    __syncthreads();

#pragma unroll
    for (int tt = 0; tt < 8; ++tt) {
        f32x4 acc = accs[tt];
#pragma unroll
        for (int kc = 0; kc < 4; ++kc) {
            short8 b = ld8(&wlds[(size_t)((kc*8 + tt)*64 + lane)*8]);
            acc = __builtin_amdgcn_mfma_f32_16x16x32_bf16(a2[kc], b, acc, 0, 0, 0);
        }
        {
            short8 b = ld8(W3_pk + (size_t)(tt*64 + lane)*8);
            acc = __builtin_amdgcn_mfma_f32_16x16x32_bf16(a3, b, acc, 0, 0, 0);
        }
        accs[tt] = acc;
    }

    const float gl[8] = { gamma[ln], gamma[16+ln], gamma[32+ln], gamma[48+ln],
                          gamma[64+ln], gamma[80+ln], gamma[96+ln], gamma[112+ln] };
    const float bl[8] = { beta[ln], beta[16+ln], beta[32+ln], beta[48+ln],
                          beta[64+ln], beta[80+ln], beta[96+ln], beta[112+ln] };
#pragma unroll
    for (int r = 0; r < 4; ++r) {
        float s = 0.f, qq = 0.f;
#pragma unroll
        for (int tt = 0; tt < 8; ++tt) {
            float u = accs[tt][r];
            s += u; qq += u*u;
        }
#pragma unroll
        for (int off = 8; off >= 1; off >>= 1) {
            s  += __shfl_xor(s, off);
            qq += __shfl_xor(qq, off);
        }
        const float mean = s * (1.f / HD);
        const float var  = qq * (1.f / HD) - mean * mean;
        const float rstd = rsqrtf(var + LN_EPS);
        const int row = row0 + quad*4 + r;
#pragma unroll
        for (int tt = 0; tt < 8; ++tt)
            out[(size_t)row*HD + tt*16 + ln] =
                (accs[tt][r] - mean) * rstd * gl[tt] + bl[tt];
    }
}

// ---------------------------------------------------------------------------
extern "C" void kernel_launch(void* const* d_in, const int* in_sizes, int n_in,
                              void* d_out, int out_size, void* d_ws, size_t ws_size,
                              hipStream_t stream)
{
    const float* src_x = (const float*)d_in[0];
    const float* dst_x = (const float*)d_in[1];
    const int*   ei    = (const int*)d_in[2];
    const float* eattr = (const float*)d_in[3];
    const float* Wsrc  = (const float*)d_in[4];
    const float* bsrc  = (const float*)d_in[5];
    const float* We    = (const float*)d_in[8];
    const float* be    = (const float*)d_in[9];
    const float* Wattn = (const float*)d_in[10];
    const float* Wmsg  = (const float*)d_in[12];
    const float* bmsg  = (const float*)d_in[13];
    const float* Wout  = (const float*)d_in[14];
    const float* bout  = (const float*)d_in[15];
    const float* gamma = (const float*)d_in[16];
    const float* beta  = (const float*)d_in[17];
    float* out = (float*)d_out;

    float* ws = (float*)d_ws;
    u16* srcmsgb = (u16*)(ws + 0);            // 6.4M u16
    u16* aggSb   = (u16*)(ws + 3200000);      // 6.4M u16
    u16* weab    = (u16*)(ws + 6400000);      // 1.6M u16
    float* s1    = ws + 7200000;              // 50048
    float* Wsm   = ws + 7250048;              // 16384
    float* bsm   = ws + 7266432;              // 128
    float* WeMsg = ws + 7266560;              // 4096
    float* c2    = ws + 7270656;              // 128
    float* bias2 = ws + 7270784;              // 128
    u16* Wsrc_pk = (u16*)(ws + 7270912);      // 16384 u16
    u16* Wsm_pk  = (u16*)(ws + 7279104);
    u16* W1_pk   = (u16*)(ws + 7287296);
    u16* W2_pk   = (u16*)(ws + 7295488);
    u16* We_pk   = (u16*)(ws + 7303680);      // 4096 u16
    u16* W3_pk   = (u16*)(ws + 7305728);      // 4096 u16
    int* rowptr  = (int*)(ws + 7307776);      // 50016
    int* cnt     = (int*)(ws + 7357792);      // 50016
    int* bsum    = (int*)(ws + 7407808);      // 64
    int* rank    = (int*)(ws + 7407872);      // 500000
    int4* ev16   = (int4*)(ws + 7907872);     // 500000 int4 (16B-aligned)
    float* wa1s  = ws + 9907872;              // 128
    float* wa3s  = ws + 9908000;              // 128
    float* bsrcs = ws + 9908128;              // 128
    float* bes   = ws + 9908256;              // 128

    fold1_kernel<<<553, 128, 0, stream>>>(Wsrc, bsrc, We, be, Wmsg, bmsg,
                                          Wsm, bsm, WeMsg, c2, cnt);
    pack_all_kernel<<<146, 64, 0, stream>>>(Wsrc, Wsm, Wout, We, WeMsg, c2,
                                            bout, bsrc, be, Wattn,
                                            Wsrc_pk, Wsm_pk, W1_pk, W2_pk,
                                            We_pk, W3_pk, bias2,
                                            wa1s, wa3s, bsrcs, bes);

    mega_kernel<<<NBLK + HB4, 512, 0, stream>>>(
        src_x, ei, Wsrc_pk, Wsm_pk, bsrcs, bsm, wa1s,
        s1, srcmsgb, cnt, rank);

    scan1_kernel<<<(NDST + 1023) / 1024, 1024, 0, stream>>>(cnt, rowptr, bsum);
    scan23_kernel<<<(NDST + 255) / 256, 256, 0, stream>>>(bsum, rowptr);

    edge_score_kernel<<<((NE + 63)/64 + 3) / 4, 256, 0, stream>>>(
        ei, eattr, We_pk, bes, wa3s, s1, rowptr, rank, ev16);

    dst_agg_kernel<<<NDST / 4, 256, 0, stream>>>(ev16, rowptr, srcmsgb,
                                                 eattr, c2, aggSb, weab);

    final_kernel<<<(NDST/16 + 3) / 4, 256, 0, stream>>>(
        dst_x, aggSb, weab, W1_pk, W2_pk, W3_pk, bias2, gamma, beta, out);
}

// Round 10
// 272.315 us; speedup vs baseline: 1.8100x; 1.0104x over previous
//
#include <hip/hip_runtime.h>
#include <math.h>

#define NSRC 50000
#define NDST 50000
#define NE   500000
#define HD   128
#define EDIM 32
#define LN_EPS 1e-5f

typedef __attribute__((ext_vector_type(8))) short short8;   // 8 bf16 = 4 VGPR
typedef __attribute__((ext_vector_type(4))) float f32x4;
typedef unsigned short u16;

#define TL2E 2.8853900817779268f   /* 2*log2(e) */
#define L2E  1.4426950408889634f   /* log2(e)   */

__device__ __forceinline__ float EXP2(float x) {
#if __has_builtin(__builtin_amdgcn_exp2f)
    return __builtin_amdgcn_exp2f(x);
#else
    return exp2f(x);
#endif
}
__device__ __forceinline__ float RCP(float x) {
#if __has_builtin(__builtin_amdgcn_rcpf)
    return __builtin_amdgcn_rcpf(x);
#else
    return 1.f / x;
#endif
}
__device__ __forceinline__ u16 f2b(float x) {           // f32 -> bf16 RNE
    unsigned u = __float_as_uint(x);
    return (u16)((u + 0x7FFFu + ((u >> 16) & 1u)) >> 16);
}
__device__ __forceinline__ float b2f(u16 h) {
    return __uint_as_float(((unsigned)h) << 16);
}
__device__ __forceinline__ short8 ld8(const u16* p) { return *(const short8*)p; }

// ---------------------------------------------------------------------------
// fold1: Wsm = Wsrc@Wmsg, bsm = bsrc@Wmsg + bmsg, WeMsg = We@Wmsg, c2 = be@Wmsg
// (128 threads span output column j -> coalesced Wmsg reads, 1 dot/thread).
// Blocks r >= 162 zero the histogram counters (replaces memset launch).
// ---------------------------------------------------------------------------
__global__ __launch_bounds__(128) void fold1_kernel(
    const float* __restrict__ Wsrc, const float* __restrict__ bsrc,
    const float* __restrict__ We,   const float* __restrict__ be,
    const float* __restrict__ Wmsg, const float* __restrict__ bmsg,
    float* __restrict__ Wsm, float* __restrict__ bsm,
    float* __restrict__ WeMsg, float* __restrict__ c2,
    int* __restrict__ cnt)
{
    const int j = threadIdx.x;
    const int r = blockIdx.x;
    if (r >= 162) {
        int i = (r - 162) * 128 + j;
        if (i < NDST + 16) cnt[i] = 0;
        return;
    }
    float s = 0.f;
    if (r < 128) {
        for (int k = 0; k < 128; ++k) s += Wsrc[r*HD + k] * Wmsg[k*HD + j];
        Wsm[r*HD + j] = s;
    } else if (r < 160) {
        const int rr = r - 128;
        for (int k = 0; k < 128; ++k) s += We[rr*HD + k] * Wmsg[k*HD + j];
        WeMsg[rr*HD + j] = s;
    } else if (r == 160) {
        for (int k = 0; k < 128; ++k) s += bsrc[k] * Wmsg[k*HD + j];
        bsm[j] = s + bmsg[j];
    } else {
        for (int k = 0; k < 128; ++k) s += be[k] * Wmsg[k*HD + j];
        c2[j] = s;
    }
}

// ---------------------------------------------------------------------------
// pack_all: pack f32 [K x 128] weights into bf16 MFMA B-fragment layout.
// Wsrc/We pre-scaled by 2*log2(e) (tanh-dot exp2/rcp refactor). Wdst path
// deleted (softmax shift-invariance: s2 and segment constants cancel).
// blocks: Wsrc 0-31, Wsm 32-63, W1(+I) 64-95, W2 96-127, We 128-135 (K=32),
//         W3 136-143 (computed), bias2 144, scale-folds 145.
// ---------------------------------------------------------------------------
__global__ __launch_bounds__(64) void pack_all_kernel(
    const float* __restrict__ Wsrc, const float* __restrict__ Wsm,
    const float* __restrict__ Wout, const float* __restrict__ We,
    const float* __restrict__ WeMsg, const float* __restrict__ c2,
    const float* __restrict__ bout, const float* __restrict__ bsrc,
    const float* __restrict__ be,   const float* __restrict__ wattn,
    u16* __restrict__ Wsrc_pk, u16* __restrict__ Wsm_pk,
    u16* __restrict__ W1_pk,   u16* __restrict__ W2_pk,
    u16* __restrict__ We_pk,   u16* __restrict__ W3_pk,
    float* __restrict__ bias2,
    float* __restrict__ wa1s, float* __restrict__ wa3s,
    float* __restrict__ bsrcs, float* __restrict__ bes)
{
    const int b = blockIdx.x;
    const int lane = threadIdx.x;
    const int ln = lane & 15, quad = lane >> 4;
    const float* Wout2 = Wout + HD*HD;

    if (b == 145) {                        // scale folds (no sums: K cancels)
#pragma unroll
        for (int h = 0; h < 2; ++h) {
            const int col = lane + h*64;
            wa1s[col] = wattn[col]        * (-2.f * L2E);
            wa3s[col] = wattn[2*HD + col] * (-2.f * L2E);
            bsrcs[col] = bsrc[col] * TL2E;
            bes[col]   = be[col]   * TL2E;
        }
        return;
    }
    if (b == 144) {                        // bias2 = bout + c2@Wout2
#pragma unroll
        for (int h = 0; h < 2; ++h) {
            const int col = lane + h*64;
            float s = 0.f;
            for (int k = 0; k < 128; ++k) s += c2[k] * Wout2[k*HD + col];
            bias2[col] = bout[col] + s;
        }
        return;
    }
    if (b >= 136) {                        // W3 = WeMsg@Wout2 (32x128), packed
        const int t = b - 136;
        const int jj = t*16 + ln;
        float sacc[8] = {0,0,0,0,0,0,0,0};
        for (int k = 0; k < 128; ++k) {
            const float w2 = Wout2[k*HD + jj];
#pragma unroll
            for (int j = 0; j < 8; ++j)
                sacc[j] = fmaf(WeMsg[(quad*8 + j)*HD + k], w2, sacc[j]);
        }
        u16 tmp[8];
#pragma unroll
        for (int j = 0; j < 8; ++j) tmp[j] = f2b(sacc[j]);
        *(short8*)(W3_pk + (size_t)(t*64 + lane)*8) = *(short8*)tmp;
        return;
    }

    const float* src; u16* dst; int lb; float scl = 1.f; bool addI = false;
    if      (b < 32)  { src = Wsrc; dst = Wsrc_pk; lb = b;       scl = TL2E; }
    else if (b < 64)  { src = Wsm;  dst = Wsm_pk;  lb = b - 32; }
    else if (b < 96)  { src = Wout; dst = W1_pk;   lb = b - 64;  addI = true; }
    else if (b < 128) { src = Wout2;dst = W2_pk;   lb = b - 96; }
    else              { src = We;   dst = We_pk;   lb = b - 128; scl = TL2E; }
    const int kc = lb >> 3, t = lb & 7;
    u16 tmp[8];
#pragma unroll
    for (int j = 0; j < 8; ++j) {
        const int i = kc*32 + quad*8 + j, jj = t*16 + ln;
        float v = src[(size_t)i*HD + jj] * scl;
        if (addI && i == jj) v += 1.f;
        tmp[j] = f2b(v);
    }
    *(short8*)(dst + (size_t)(lb*64 + lane)*8) = *(short8*)tmp;
}

// ---------------------------------------------------------------------------
// mega: block-range fusion, 512 threads (8 waves) per compute block:
//   [0, NBLK)    node: s1 tanh-dot + srcmsgb, 32 rows/wave (256 rows/block)
//   [NBLK, +HB4) hist: cnt[dst]++ / rank, 4 edges per thread
// ---------------------------------------------------------------------------
#define NBLK ((NSRC + 255) / 256)
#define HB4 ((NE/4 + 511) / 512)

__global__ __launch_bounds__(512) void mega_kernel(
    const float* __restrict__ src_x, const int* __restrict__ ei,
    const u16* __restrict__ Wsrc_pk, const u16* __restrict__ Wsm_pk,
    const float* __restrict__ bsrcs, const float* __restrict__ bsm,
    const float* __restrict__ wa1s,
    float* __restrict__ s1,
    u16* __restrict__ srcmsgb, int* __restrict__ cnt, int* __restrict__ rank)
{
    __shared__ __align__(16) u16 wlds[16384];      // 32 KB staged weights
    __shared__ __align__(16) u16 tlds[8][2048];    // 32 KB per-wave transpose
    const int t = threadIdx.x;
    const int blk = blockIdx.x;

    if (blk >= NBLK) {                   // ---- hist path (4 edges/thread)
        const int idx = (blk - NBLK) * 512 + t;
        if (idx < NE/4) {
            int4 d4 = ((const int4*)(ei + NE))[idx];
            int4 r4;
            r4.x = atomicAdd(&cnt[d4.x], 1);
            r4.y = atomicAdd(&cnt[d4.y], 1);
            r4.z = atomicAdd(&cnt[d4.z], 1);
            r4.w = atomicAdd(&cnt[d4.w], 1);
            ((int4*)rank)[idx] = r4;
        }
        return;
    }

    const int w = t >> 6, lane = t & 63;
    const int ln = lane & 15, quad = lane >> 4;
    int row0 = blk * 256 + w * 32;
    if (row0 > NSRC - 32) row0 = NSRC - 32;       // dup writes benign

    // x loads (2 row-tiles), converted to bf16 A-frags in-register
    const float* rp0 = src_x + (size_t)(row0 + ln)*HD;
    const float* rp1 = rp0 + (size_t)16*HD;
    short8 a0[4], a1[4];
#pragma unroll
    for (int kc = 0; kc < 4; ++kc) {
        float4 f0 = *(const float4*)(rp0 + kc*32 + quad*8);
        float4 f1 = *(const float4*)(rp0 + kc*32 + quad*8 + 4);
        float4 g0 = *(const float4*)(rp1 + kc*32 + quad*8);
        float4 g1 = *(const float4*)(rp1 + kc*32 + quad*8 + 4);
        u16 tb[8] = { f2b(f0.x), f2b(f0.y), f2b(f0.z), f2b(f0.w),
                      f2b(f1.x), f2b(f1.y), f2b(f1.z), f2b(f1.w) };
        a0[kc] = *(short8*)tb;
        u16 tc[8] = { f2b(g0.x), f2b(g0.y), f2b(g0.z), f2b(g0.w),
                      f2b(g1.x), f2b(g1.y), f2b(g1.z), f2b(g1.w) };
        a1[kc] = *(short8*)tc;
    }

    // stage Wsrc weights (32 KB, cooperative, coalesced 16B)
#pragma unroll
    for (int it = 0; it < 4; ++it) {
        short8 v = ld8(Wsrc_pk + (size_t)(it*512 + t)*8);
        *(short8*)(&wlds[(it*512 + t)*8]) = v;
    }
    __syncthreads();

    // ---- s1 tanh-dot (log2-domain; K0 cancels in softmax)
    float v0[4] = {0,0,0,0}, v1[4] = {0,0,0,0};
#pragma unroll
    for (int tt = 0; tt < 8; ++tt) {
        const float bb = bsrcs[tt*16 + ln];
        const float ww = wa1s[tt*16 + ln];
        f32x4 acc0 = {bb, bb, bb, bb};
        f32x4 acc1 = {bb, bb, bb, bb};
#pragma unroll
        for (int kc = 0; kc < 4; ++kc) {
            short8 bf = ld8(&wlds[(size_t)((kc*8 + tt)*64 + lane)*8]);
            acc0 = __builtin_amdgcn_mfma_f32_16x16x32_bf16(a0[kc], bf, acc0, 0, 0, 0);
            acc1 = __builtin_amdgcn_mfma_f32_16x16x32_bf16(a1[kc], bf, acc1, 0, 0, 0);
        }
#pragma unroll
        for (int r = 0; r < 4; ++r) {
            v0[r] = fmaf(ww, RCP(EXP2(acc0[r]) + 1.f), v0[r]);
            v1[r] = fmaf(ww, RCP(EXP2(acc1[r]) + 1.f), v1[r]);
        }
    }
#pragma unroll
    for (int off = 8; off >= 1; off >>= 1) {
#pragma unroll
        for (int r = 0; r < 4; ++r) {
            v0[r] += __shfl_xor(v0[r], off);
            v1[r] += __shfl_xor(v1[r], off);
        }
    }
    if (ln == 0) {
#pragma unroll
        for (int r = 0; r < 4; ++r) {
            s1[row0 + quad*4 + r]      = v0[r];
            s1[row0 + 16 + quad*4 + r] = v1[r];
        }
    }

    // ---- restage with Wsm, then srcmsg path
    __syncthreads();
#pragma unroll
    for (int it = 0; it < 4; ++it) {
        short8 v = ld8(Wsm_pk + (size_t)(it*512 + t)*8);
        *(short8*)(&wlds[(it*512 + t)*8]) = v;
    }
    __syncthreads();

    u16* slab = &tlds[w][0];
#pragma unroll
    for (int tile = 0; tile < 2; ++tile) {
#pragma unroll
        for (int tt = 0; tt < 8; ++tt) {
            const float bs = bsm[tt*16 + ln];
            f32x4 acc = {bs, bs, bs, bs};
#pragma unroll
            for (int kc = 0; kc < 4; ++kc) {
                short8 bf = ld8(&wlds[(size_t)((kc*8 + tt)*64 + lane)*8]);
                acc = __builtin_amdgcn_mfma_f32_16x16x32_bf16(
                          tile ? a1[kc] : a0[kc], bf, acc, 0, 0, 0);
            }
            // swizzled write: row = quad*4+r (row>>2 == quad), col blk tt^quad
#pragma unroll
            for (int r = 0; r < 4; ++r)
                slab[(quad*4 + r)*128 + ((tt ^ quad) << 4) + ln] = f2b(acc[r]);
        }
        // per-wave readback (DS in-order within wave; no barrier needed)
#pragma unroll
        for (int r2 = 0; r2 < 4; ++r2) {
            const int row = r2*4 + quad;          // row>>2 == r2
            const int c = ln*8;
            const int sidx = row*128 + (((c >> 4) ^ r2) << 4) + (c & 15);
            short8 val = *(const short8*)(&slab[sidx]);
            *(short8*)(srcmsgb + (size_t)(row0 + tile*16 + row)*HD + c) = val;
        }
    }
}

// ---------------------------------------------------------------------------
// scan1: per-1024-chunk exclusive scan of cnt into rowptr, block sums to bsum
// ---------------------------------------------------------------------------
__global__ __launch_bounds__(1024) void scan1_kernel(
    const int* __restrict__ cnt, int* __restrict__ excl, int* __restrict__ bsum)
{
    __shared__ int buf[1024];
    const int t = threadIdx.x;
    const int i = blockIdx.x * 1024 + t;
    int v = (i < NDST) ? cnt[i] : 0;
    buf[t] = v;
    __syncthreads();
    for (int off = 1; off < 1024; off <<= 1) {
        int tv = (t >= off) ? buf[t - off] : 0;
        __syncthreads();
        buf[t] += tv;
        __syncthreads();
    }
    if (i < NDST) excl[i] = buf[t] - v;
    if (t == 1023) bsum[blockIdx.x] = buf[1023];
}

// ---------------------------------------------------------------------------
// scan23: every block redundantly wave-scans the 49 chunk sums, then applies
// the offset to its rowptr slice.
// ---------------------------------------------------------------------------
__global__ __launch_bounds__(256) void scan23_kernel(
    const int* __restrict__ bsum, int* __restrict__ rowptr)
{
    __shared__ int pref[64];
    const int t = threadIdx.x;
    const int NB = (NDST + 1023) / 1024;     // 49
    if (t < 64) {
        int orig = (t < NB) ? bsum[t] : 0;
        int v = orig;
        for (int off = 1; off < 64; off <<= 1) {
            int u = __shfl_up(v, off);
            if (t >= off) v += u;
        }
        pref[t] = v - orig;                  // exclusive prefix
        if (blockIdx.x == 0 && t == NB - 1) rowptr[NDST] = v;  // total
    }
    __syncthreads();
    const int i = blockIdx.x * 256 + t;
    if (i < NDST) rowptr[i] += pref[i >> 10];
}

// ---------------------------------------------------------------------------
// edge_score: 64 edges / wave (4 A-tiles share each We B-frag). Tanh-dot in
// log2-domain; score = s1[src] + v_e. EPILOGUE GATHERS HOISTED to kernel
// entry (ei/s1/rowptr/rank don't depend on the dots -> their ~500-cycle
// chain hides under the whole MFMA/transcendental loop instead of sitting
// exposed at the wave tail). 15-cndmask select tree + ONE shfl.
// ---------------------------------------------------------------------------
__global__ __launch_bounds__(256) void edge_score_kernel(
    const int* __restrict__ ei, const float* __restrict__ eattr,
    const u16* __restrict__ We_pk, const float* __restrict__ bes,
    const float* __restrict__ wa3s,
    const float* __restrict__ s1,
    const int* __restrict__ rowptr, const int* __restrict__ rank,
    int4* __restrict__ ev16)
{
    const int t = threadIdx.x;
    const int w = t >> 6, lane = t & 63;
    const int ln = lane & 15, quad = lane >> 4;
    int e0 = (blockIdx.x * 4 + w) * 64;
    if (e0 > NE - 64) e0 = NE - 64;        // dup processing benign

    // ---- hoisted epilogue gathers (independent of the dot computation)
    const int e = e0 + lane;
    const int srcn = ei[e];
    const int dstn = ei[NE + e];
    const float s1v = s1[srcn];
    const int pos = rowptr[dstn] + rank[e];

    short8 a[4];
#pragma unroll
    for (int tl = 0; tl < 4; ++tl) {
        const float* ap = eattr + (size_t)(e0 + tl*16 + ln)*EDIM + quad*8;
        float4 f0 = *(const float4*)(ap);
        float4 f1 = *(const float4*)(ap + 4);
        u16 ab[8] = { f2b(f0.x), f2b(f0.y), f2b(f0.z), f2b(f0.w),
                      f2b(f1.x), f2b(f1.y), f2b(f1.z), f2b(f1.w) };
        a[tl] = *(short8*)ab;
    }

    float v0[4] = {0,0,0,0}, v1[4] = {0,0,0,0};
    float v2[4] = {0,0,0,0}, v3[4] = {0,0,0,0};
#pragma unroll
    for (int tt = 0; tt < 8; ++tt) {
        const float bb = bes[tt*16 + ln];
        const float ww = wa3s[tt*16 + ln];
        short8 b = ld8(We_pk + (size_t)(tt*64 + lane)*8);
        f32x4 ac0 = {bb, bb, bb, bb};
        f32x4 ac1 = {bb, bb, bb, bb};
        f32x4 ac2 = {bb, bb, bb, bb};
        f32x4 ac3 = {bb, bb, bb, bb};
        ac0 = __builtin_amdgcn_mfma_f32_16x16x32_bf16(a[0], b, ac0, 0, 0, 0);
        ac1 = __builtin_amdgcn_mfma_f32_16x16x32_bf16(a[1], b, ac1, 0, 0, 0);
        ac2 = __builtin_amdgcn_mfma_f32_16x16x32_bf16(a[2], b, ac2, 0, 0, 0);
        ac3 = __builtin_amdgcn_mfma_f32_16x16x32_bf16(a[3], b, ac3, 0, 0, 0);
#pragma unroll
        for (int r = 0; r < 4; ++r) {
            v0[r] = fmaf(ww, RCP(EXP2(ac0[r]) + 1.f), v0[r]);
            v1[r] = fmaf(ww, RCP(EXP2(ac1[r]) + 1.f), v1[r]);
            v2[r] = fmaf(ww, RCP(EXP2(ac2[r]) + 1.f), v2[r]);
            v3[r] = fmaf(ww, RCP(EXP2(ac3[r]) + 1.f), v3[r]);
        }
    }
    // reduce over the 16 feature lanes (ln) within each quad group
#pragma unroll
    for (int off = 8; off >= 1; off >>= 1) {
#pragma unroll
        for (int r = 0; r < 4; ++r) {
            v0[r] += __shfl_xor(v0[r], off);
            v1[r] += __shfl_xor(v1[r], off);
            v2[r] += __shfl_xor(v2[r], off);
            v3[r] += __shfl_xor(v3[r], off);
        }
    }
    // select tree: lane (quad q, ln) picks v_{ln>>2}[ln&3]
    const bool s0 = ln & 1, s1b = ln & 2, s2b = ln & 4, s3b = ln & 8;
    float m00 = s0 ? v0[1] : v0[0];
    float m01 = s0 ? v0[3] : v0[2];
    float m02 = s0 ? v1[1] : v1[0];
    float m03 = s0 ? v1[3] : v1[2];
    float m04 = s0 ? v2[1] : v2[0];
    float m05 = s0 ? v2[3] : v2[2];
    float m06 = s0 ? v3[1] : v3[0];
    float m07 = s0 ? v3[3] : v3[2];
    float m10 = s1b ? m01 : m00;
    float m11 = s1b ? m03 : m02;
    float m12 = s1b ? m05 : m04;
    float m13 = s1b ? m07 : m06;
    float m20 = s2b ? m11 : m10;
    float m21 = s2b ? m13 : m12;
    float selv = s3b ? m21 : m20;
    // lane l wants edge e0+l = (T=l>>4)*16 + (Q=(l>>2)&3)*4 + (R=l&3):
    // source lane = Q*16 + T*4 + R
    const int srcl = ((lane >> 2) & 3) * 16 + ((lane >> 4) << 2) + (lane & 3);
    const float myv = __shfl(selv, srcl);

    const float sc = s1v + myv;
    ev16[pos] = make_int4(srcn, e, __float_as_int(sc), 0);
}

// ---------------------------------------------------------------------------
// dst_agg: 1 wave per dst, single pass (no-max softmax), 2-DEEP SOFTWARE
// PIPELINE: per iteration issue record Q(k+2) and the srcmsg/eattr gathers
// for Q(k+1) (whose record already arrived), then compute iteration k ->
// the record->gather dependent chain overlaps one full iteration of compute.
// msg row: 16 lanes x 16B bf16; ea row: 8 lanes x 16B f32 (one cache line).
// ---------------------------------------------------------------------------
__global__ __launch_bounds__(256) void dst_agg_kernel(
    const int4* __restrict__ ev16, const int* __restrict__ rowptr,
    const u16* __restrict__ srcmsgb, const float* __restrict__ eattr,
    const float* __restrict__ c2,
    u16* __restrict__ aggSb, u16* __restrict__ weab)
{
    const int lane = threadIdx.x & 63;
    const int d = blockIdx.x * 4 + (threadIdx.x >> 6);
    const int el = lane >> 4, c = lane & 15;
    const int start = rowptr[d], end = rowptr[d + 1];

    if (start == end) {
        if (el == 0) {
            u16 z[8];
#pragma unroll
            for (int j = 0; j < 8; ++j) z[j] = f2b(-c2[c*8 + j]);
            *(short8*)(aggSb + (size_t)d*HD + c*8) = *(short8*)z;
            if (c < 8) {
                u16 zz[4] = {0,0,0,0};
                *(ushort4*)(weab + (size_t)d*EDIM + c*4) = *(ushort4*)zz;
            }
        }
        return;
    }

    float sacc = 0.f;
    float acc[8]  = {0,0,0,0,0,0,0,0};
    float wacc[4] = {0,0,0,0};

    // pipeline prologue: Q(0), Q(1), SM(0), EA(0)
    const int iA = start + el;
    bool vA = (iA < end);
    int4 qA = ev16[vA ? iA : start];
    const int iB = iA + 4;
    bool vB = (iB < end);
    int4 qB = ev16[vB ? iB : start];
    short8 smA = ld8(srcmsgb + (size_t)qA.x*HD + c*8);
    float4 eaA = {0.f, 0.f, 0.f, 0.f};
    if (c < 8) eaA = *(const float4*)(eattr + (size_t)qA.y*EDIM + c*4);

    for (int i0 = start; i0 < end; i0 += 4) {
        // issue Q(k+2)
        const int iC = i0 + 8 + el;
        const bool vC = (iC < end);
        int4 qC = ev16[vC ? iC : start];
        // issue SM(k+1), EA(k+1) from already-arrived Q(k+1)
        short8 smB = ld8(srcmsgb + (size_t)qB.x*HD + c*8);
        float4 eaB = {0.f, 0.f, 0.f, 0.f};
        if (c < 8) eaB = *(const float4*)(eattr + (size_t)qB.y*EDIM + c*4);

        // compute iteration k
        const float wgt = vA ? EXP2(__int_as_float(qA.z)) : 0.f;
        sacc += wgt;
#pragma unroll
        for (int j = 0; j < 8; ++j)
            acc[j] = fmaf(wgt, b2f(((u16*)&smA)[j]), acc[j]);
        if (c < 8) {
            wacc[0] = fmaf(wgt, eaA.x, wacc[0]);
            wacc[1] = fmaf(wgt, eaA.y, wacc[1]);
            wacc[2] = fmaf(wgt, eaA.z, wacc[2]);
            wacc[3] = fmaf(wgt, eaA.w, wacc[3]);
        }
        // rotate
        qA = qB; vA = vB; smA = smB; eaA = eaB;
        qB = qC; vB = vC;
    }
#pragma unroll
    for (int off = 16; off <= 32; off <<= 1) {
        sacc += __shfl_xor(sacc, off);
#pragma unroll
        for (int j = 0; j < 8; ++j) acc[j] += __shfl_xor(acc[j], off);
#pragma unroll
        for (int j = 0; j < 4; ++j) wacc[j] += __shfl_xor(wacc[j], off);
    }
    const float inv = RCP(sacc);
    if (el == 0) {
        u16 o[8];
#pragma unroll
        for (int j = 0; j < 8; ++j) o[j] = f2b(acc[j] * inv);
        *(short8*)(aggSb + (size_t)d*HD + c*8) = *(short8*)o;
        if (c < 8) {
            u16 o2[4];
#pragma unroll
            for (int j = 0; j < 4; ++j) o2[j] = f2b(wacc[j] * inv);
            *(ushort4*)(weab + (size_t)d*EDIM + c*4) = *(ushort4*)o2;
        }
    }
}

// ---------------------------------------------------------------------------
// final: out = LN(dst_x@W1p + aggSb@Wout2 + weab@W3 + bias2) * gamma + beta
// per 16 dst rows / wave. W1/W2 LDS-staged per block; W3 (8KB) global/L1;
// accs persist in registers across the restage.
// ---------------------------------------------------------------------------
__global__ __launch_bounds__(256) void final_kernel(
    const float* __restrict__ dst_x, const u16* __restrict__ aggSb,
    const u16* __restrict__ weab,
    const u16* __restrict__ W1_pk, const u16* __restrict__ W2_pk,
    const u16* __restrict__ W3_pk, const float* __restrict__ bias2,
    const float* __restrict__ gamma, const float* __restrict__ beta,
    float* __restrict__ out)
{
    __shared__ __align__(16) u16 wlds[16384];      // 32 KB staged weights
    const int t = threadIdx.x;
    const int w = t >> 6, lane = t & 63;
    const int ln = lane & 15, quad = lane >> 4;
    int row0 = (blockIdx.x * 4 + w) * 16;
    if (row0 > NDST - 16) row0 = NDST - 16;

    const float* rp = dst_x + (size_t)(row0 + ln)*HD;
    short8 a1[4], a2[4], a3;
#pragma unroll
    for (int kc = 0; kc < 4; ++kc) {
        float4 f0 = *(const float4*)(rp + kc*32 + quad*8);
        float4 f1 = *(const float4*)(rp + kc*32 + quad*8 + 4);
        u16 tb[8] = { f2b(f0.x), f2b(f0.y), f2b(f0.z), f2b(f0.w),
                      f2b(f1.x), f2b(f1.y), f2b(f1.z), f2b(f1.w) };
        a1[kc] = *(short8*)tb;
        a2[kc] = ld8(aggSb + (size_t)(row0 + ln)*HD + kc*32 + quad*8);
    }
    a3 = ld8(weab + (size_t)(row0 + ln)*EDIM + quad*8);

    // stage W1 (32 KB, cooperative)
#pragma unroll
    for (int it = 0; it < 8; ++it) {
        short8 v = ld8(W1_pk + (size_t)(it*256 + t)*8);
        *(short8*)(&wlds[(it*256 + t)*8]) = v;
    }
    __syncthreads();

    f32x4 accs[8];
#pragma unroll
    for (int tt = 0; tt < 8; ++tt) {
        const float bb = bias2[tt*16 + ln];
        f32x4 acc = {bb, bb, bb, bb};
#pragma unroll
        for (int kc = 0; kc < 4; ++kc) {
            short8 b = ld8(&wlds[(size_t)((kc*8 + tt)*64 + lane)*8]);
            acc = __builtin_amdgcn_mfma_f32_16x16x32_bf16(a1[kc], b, acc, 0, 0, 0);
        }
        accs[tt] = acc;
    }

    // restage with W2
    __syncthreads();
#pragma unroll
    for (int it = 0; it < 8; ++it) {
        short8 v = ld8(W2_pk + (size_t)(it*256 + t)*8);
        *(short8*)(&wlds[(it*256 + t)*8]) = v;
    }
    __syncthreads();

#pragma unroll
    for (int tt = 0; tt < 8; ++tt) {
        f32x4 acc = accs[tt];
#pragma unroll
        for (int kc = 0; kc < 4; ++kc) {
            short8 b = ld8(&wlds[(size_t)((kc*8 + tt)*64 + lane)*8]);
            acc = __builtin_amdgcn_mfma_f32_16x16x32_bf16(a2[kc], b, acc, 0, 0, 0);
        }
        {
            short8 b = ld8(W3_pk + (size_t)(tt*64 + lane)*8);
            acc = __builtin_amdgcn_mfma_f32_16x16x32_bf16(a3, b, acc, 0, 0, 0);
        }
        accs[tt] = acc;
    }

    const float gl[8] = { gamma[ln], gamma[16+ln], gamma[32+ln], gamma[48+ln],
                          gamma[64+ln], gamma[80+ln], gamma[96+ln], gamma[112+ln] };
    const float bl[8] = { beta[ln], beta[16+ln], beta[32+ln], beta[48+ln],
                          beta[64+ln], beta[80+ln], beta[96+ln], beta[112+ln] };
#pragma unroll
    for (int r = 0; r < 4; ++r) {
        float s = 0.f, qq = 0.f;
#pragma unroll
        for (int tt = 0; tt < 8; ++tt) {
            float u = accs[tt][r];
            s += u; qq += u*u;
        }
#pragma unroll
        for (int off = 8; off >= 1; off >>= 1) {
            s  += __shfl_xor(s, off);
            qq += __shfl_xor(qq, off);
        }
        const float mean = s * (1.f / HD);
        const float var  = qq * (1.f / HD) - mean * mean;
        const float rstd = rsqrtf(var + LN_EPS);
        const int row = row0 + quad*4 + r;
#pragma unroll
        for (int tt = 0; tt < 8; ++tt)
            out[(size_t)row*HD + tt*16 + ln] =
                (accs[tt][r] - mean) * rstd * gl[tt] + bl[tt];
    }
}

// ---------------------------------------------------------------------------
extern "C" void kernel_launch(void* const* d_in, const int* in_sizes, int n_in,
                              void* d_out, int out_size, void* d_ws, size_t ws_size,
                              hipStream_t stream)
{
    const float* src_x = (const float*)d_in[0];
    const float* dst_x = (const float*)d_in[1];
    const int*   ei    = (const int*)d_in[2];
    const float* eattr = (const float*)d_in[3];
    const float* Wsrc  = (const float*)d_in[4];
    const float* bsrc  = (const float*)d_in[5];
    const float* We    = (const float*)d_in[8];
    const float* be    = (const float*)d_in[9];
    const float* Wattn = (const float*)d_in[10];
    const float* Wmsg  = (const float*)d_in[12];
    const float* bmsg  = (const float*)d_in[13];
    const float* Wout  = (const float*)d_in[14];
    const float* bout  = (const float*)d_in[15];
    const float* gamma = (const float*)d_in[16];
    const float* beta  = (const float*)d_in[17];
    float* out = (float*)d_out;

    float* ws = (float*)d_ws;
    u16* srcmsgb = (u16*)(ws + 0);            // 6.4M u16
    u16* aggSb   = (u16*)(ws + 3200000);      // 6.4M u16
    u16* weab    = (u16*)(ws + 6400000);      // 1.6M u16
    float* s1    = ws + 7200000;              // 50048
    float* Wsm   = ws + 7250048;              // 16384
    float* bsm   = ws + 7266432;              // 128
    float* WeMsg = ws + 7266560;              // 4096
    float* c2    = ws + 7270656;              // 128
    float* bias2 = ws + 7270784;              // 128
    u16* Wsrc_pk = (u16*)(ws + 7270912);      // 16384 u16
    u16* Wsm_pk  = (u16*)(ws + 7279104);
    u16* W1_pk   = (u16*)(ws + 7287296);
    u16* W2_pk   = (u16*)(ws + 7295488);
    u16* We_pk   = (u16*)(ws + 7303680);      // 4096 u16
    u16* W3_pk   = (u16*)(ws + 7305728);      // 4096 u16
    int* rowptr  = (int*)(ws + 7307776);      // 50016
    int* cnt     = (int*)(ws + 7357792);      // 50016
    int* bsum    = (int*)(ws + 7407808);      // 64
    int* rank    = (int*)(ws + 7407872);      // 500000
    int4* ev16   = (int4*)(ws + 7907872);     // 500000 int4 (16B-aligned)
    float* wa1s  = ws + 9907872;              // 128
    float* wa3s  = ws + 9908000;              // 128
    float* bsrcs = ws + 9908128;              // 128
    float* bes   = ws + 9908256;              // 128

    fold1_kernel<<<553, 128, 0, stream>>>(Wsrc, bsrc, We, be, Wmsg, bmsg,
                                          Wsm, bsm, WeMsg, c2, cnt);
    pack_all_kernel<<<146, 64, 0, stream>>>(Wsrc, Wsm, Wout, We, WeMsg, c2,
                                            bout, bsrc, be, Wattn,
                                            Wsrc_pk, Wsm_pk, W1_pk, W2_pk,
                                            We_pk, W3_pk, bias2,
                                            wa1s, wa3s, bsrcs, bes);

    mega_kernel<<<NBLK + HB4, 512, 0, stream>>>(
        src_x, ei, Wsrc_pk, Wsm_pk, bsrcs, bsm, wa1s,
        s1, srcmsgb, cnt, rank);

    scan1_kernel<<<(NDST + 1023) / 1024, 1024, 0, stream>>>(cnt, rowptr, bsum);
    scan23_kernel<<<(NDST + 255) / 256, 256, 0, stream>>>(bsum, rowptr);

    edge_score_kernel<<<((NE + 63)/64 + 3) / 4, 256, 0, stream>>>(
        ei, eattr, We_pk, bes, wa3s, s1, rowptr, rank, ev16);

    dst_agg_kernel<<<NDST / 4, 256, 0, stream>>>(ev16, rowptr, srcmsgb,
                                                 eattr, c2, aggSb, weab);

    final_kernel<<<(NDST/16 + 3) / 4, 256, 0, stream>>>(
        dst_x, aggSb, weab, W1_pk, W2_pk, W3_pk, bias2, gamma, beta, out);
}

// Round 11
// 271.543 us; speedup vs baseline: 1.8151x; 1.0028x over previous
//
#include <hip/hip_runtime.h>
#include <math.h>

#define NSRC 50000
#define NDST 50000
#define NE   500000
#define HD   128
#define EDIM 32
#define LN_EPS 1e-5f

typedef __attribute__((ext_vector_type(8))) short short8;   // 8 bf16 = 4 VGPR
typedef __attribute__((ext_vector_type(4))) float f32x4;
typedef unsigned short u16;

#define TL2E 2.8853900817779268f   /* 2*log2(e) */
#define L2E  1.4426950408889634f   /* log2(e)   */

__device__ __forceinline__ float EXP2(float x) {
#if __has_builtin(__builtin_amdgcn_exp2f)
    return __builtin_amdgcn_exp2f(x);
#else
    return exp2f(x);
#endif
}
__device__ __forceinline__ float RCP(float x) {
#if __has_builtin(__builtin_amdgcn_rcpf)
    return __builtin_amdgcn_rcpf(x);
#else
    return 1.f / x;
#endif
}
__device__ __forceinline__ u16 f2b(float x) {           // f32 -> bf16 RNE
    unsigned u = __float_as_uint(x);
    return (u16)((u + 0x7FFFu + ((u >> 16) & 1u)) >> 16);
}
__device__ __forceinline__ float b2f(u16 h) {
    return __uint_as_float(((unsigned)h) << 16);
}
__device__ __forceinline__ short8 ld8(const u16* p) { return *(const short8*)p; }

// ---------------------------------------------------------------------------
// fold1: Wsm = Wsrc@Wmsg, bsm = bsrc@Wmsg + bmsg, WeMsg = We@Wmsg, c2 = be@Wmsg
// (128 threads span output column j -> coalesced Wmsg reads, 1 dot/thread).
// Blocks r >= 162 zero the histogram counters (replaces memset launch).
// ---------------------------------------------------------------------------
__global__ __launch_bounds__(128) void fold1_kernel(
    const float* __restrict__ Wsrc, const float* __restrict__ bsrc,
    const float* __restrict__ We,   const float* __restrict__ be,
    const float* __restrict__ Wmsg, const float* __restrict__ bmsg,
    float* __restrict__ Wsm, float* __restrict__ bsm,
    float* __restrict__ WeMsg, float* __restrict__ c2,
    int* __restrict__ cnt)
{
    const int j = threadIdx.x;
    const int r = blockIdx.x;
    if (r >= 162) {
        int i = (r - 162) * 128 + j;
        if (i < NDST + 16) cnt[i] = 0;
        return;
    }
    float s = 0.f;
    if (r < 128) {
        for (int k = 0; k < 128; ++k) s += Wsrc[r*HD + k] * Wmsg[k*HD + j];
        Wsm[r*HD + j] = s;
    } else if (r < 160) {
        const int rr = r - 128;
        for (int k = 0; k < 128; ++k) s += We[rr*HD + k] * Wmsg[k*HD + j];
        WeMsg[rr*HD + j] = s;
    } else if (r == 160) {
        for (int k = 0; k < 128; ++k) s += bsrc[k] * Wmsg[k*HD + j];
        bsm[j] = s + bmsg[j];
    } else {
        for (int k = 0; k < 128; ++k) s += be[k] * Wmsg[k*HD + j];
        c2[j] = s;
    }
}

// ---------------------------------------------------------------------------
// pack_all: pack f32 [K x 128] weights into bf16 MFMA B-fragment layout.
// Wsrc/We pre-scaled by 2*log2(e) (tanh-dot exp2/rcp refactor). Wdst path
// deleted (softmax shift-invariance: s2 and segment constants cancel).
// blocks: Wsrc 0-31, Wsm 32-63, W1(+I) 64-95, W2 96-127, We 128-135 (K=32),
//         W3 136-143 (computed), bias2 144, scale-folds 145.
// ---------------------------------------------------------------------------
__global__ __launch_bounds__(64) void pack_all_kernel(
    const float* __restrict__ Wsrc, const float* __restrict__ Wsm,
    const float* __restrict__ Wout, const float* __restrict__ We,
    const float* __restrict__ WeMsg, const float* __restrict__ c2,
    const float* __restrict__ bout, const float* __restrict__ bsrc,
    const float* __restrict__ be,   const float* __restrict__ wattn,
    u16* __restrict__ Wsrc_pk, u16* __restrict__ Wsm_pk,
    u16* __restrict__ W1_pk,   u16* __restrict__ W2_pk,
    u16* __restrict__ We_pk,   u16* __restrict__ W3_pk,
    float* __restrict__ bias2,
    float* __restrict__ wa1s, float* __restrict__ wa3s,
    float* __restrict__ bsrcs, float* __restrict__ bes)
{
    const int b = blockIdx.x;
    const int lane = threadIdx.x;
    const int ln = lane & 15, quad = lane >> 4;
    const float* Wout2 = Wout + HD*HD;

    if (b == 145) {                        // scale folds (no sums: K cancels)
#pragma unroll
        for (int h = 0; h < 2; ++h) {
            const int col = lane + h*64;
            wa1s[col] = wattn[col]        * (-2.f * L2E);
            wa3s[col] = wattn[2*HD + col] * (-2.f * L2E);
            bsrcs[col] = bsrc[col] * TL2E;
            bes[col]   = be[col]   * TL2E;
        }
        return;
    }
    if (b == 144) {                        // bias2 = bout + c2@Wout2
#pragma unroll
        for (int h = 0; h < 2; ++h) {
            const int col = lane + h*64;
            float s = 0.f;
            for (int k = 0; k < 128; ++k) s += c2[k] * Wout2[k*HD + col];
            bias2[col] = bout[col] + s;
        }
        return;
    }
    if (b >= 136) {                        // W3 = WeMsg@Wout2 (32x128), packed
        const int t = b - 136;
        const int jj = t*16 + ln;
        float sacc[8] = {0,0,0,0,0,0,0,0};
        for (int k = 0; k < 128; ++k) {
            const float w2 = Wout2[k*HD + jj];
#pragma unroll
            for (int j = 0; j < 8; ++j)
                sacc[j] = fmaf(WeMsg[(quad*8 + j)*HD + k], w2, sacc[j]);
        }
        u16 tmp[8];
#pragma unroll
        for (int j = 0; j < 8; ++j) tmp[j] = f2b(sacc[j]);
        *(short8*)(W3_pk + (size_t)(t*64 + lane)*8) = *(short8*)tmp;
        return;
    }

    const float* src; u16* dst; int lb; float scl = 1.f; bool addI = false;
    if      (b < 32)  { src = Wsrc; dst = Wsrc_pk; lb = b;       scl = TL2E; }
    else if (b < 64)  { src = Wsm;  dst = Wsm_pk;  lb = b - 32; }
    else if (b < 96)  { src = Wout; dst = W1_pk;   lb = b - 64;  addI = true; }
    else if (b < 128) { src = Wout2;dst = W2_pk;   lb = b - 96; }
    else              { src = We;   dst = We_pk;   lb = b - 128; scl = TL2E; }
    const int kc = lb >> 3, t = lb & 7;
    u16 tmp[8];
#pragma unroll
    for (int j = 0; j < 8; ++j) {
        const int i = kc*32 + quad*8 + j, jj = t*16 + ln;
        float v = src[(size_t)i*HD + jj] * scl;
        if (addI && i == jj) v += 1.f;
        tmp[j] = f2b(v);
    }
    *(short8*)(dst + (size_t)(lb*64 + lane)*8) = *(short8*)tmp;
}

// ---------------------------------------------------------------------------
// mega: block-range fusion, 512 threads (8 waves) per compute block:
//   [0, NBLK)    node: s1 tanh-dot + srcmsgb, 32 rows/wave (256 rows/block)
//   [NBLK, +HB4) hist: cnt[dst]++ / rank, 4 edges per thread
// BOTH weight sets staged upfront (Wsrc->wlds, Wsm->mlds) so the stage
// overlaps the x-load latency; phase-2's transpose slab REUSES wlds (dead
// after phase 1). Barriers 4 -> 2; no mid-kernel global->LDS round trip.
// LDS still 64 KB -> 2 blocks/CU.
// ---------------------------------------------------------------------------
#define NBLK ((NSRC + 255) / 256)
#define HB4 ((NE/4 + 511) / 512)

__global__ __launch_bounds__(512) void mega_kernel(
    const float* __restrict__ src_x, const int* __restrict__ ei,
    const u16* __restrict__ Wsrc_pk, const u16* __restrict__ Wsm_pk,
    const float* __restrict__ bsrcs, const float* __restrict__ bsm,
    const float* __restrict__ wa1s,
    float* __restrict__ s1,
    u16* __restrict__ srcmsgb, int* __restrict__ cnt, int* __restrict__ rank)
{
    __shared__ __align__(16) u16 wlds[16384];  // Wsrc (phase 1), slabs (phase 2)
    __shared__ __align__(16) u16 mlds[16384];  // Wsm (whole kernel)
    const int t = threadIdx.x;
    const int blk = blockIdx.x;

    if (blk >= NBLK) {                   // ---- hist path (4 edges/thread)
        const int idx = (blk - NBLK) * 512 + t;
        if (idx < NE/4) {
            int4 d4 = ((const int4*)(ei + NE))[idx];
            int4 r4;
            r4.x = atomicAdd(&cnt[d4.x], 1);
            r4.y = atomicAdd(&cnt[d4.y], 1);
            r4.z = atomicAdd(&cnt[d4.z], 1);
            r4.w = atomicAdd(&cnt[d4.w], 1);
            ((int4*)rank)[idx] = r4;
        }
        return;
    }

    const int w = t >> 6, lane = t & 63;
    const int ln = lane & 15, quad = lane >> 4;
    int row0 = blk * 256 + w * 32;
    if (row0 > NSRC - 32) row0 = NSRC - 32;       // dup writes benign

    // x loads (2 row-tiles), converted to bf16 A-frags in-register
    const float* rp0 = src_x + (size_t)(row0 + ln)*HD;
    const float* rp1 = rp0 + (size_t)16*HD;
    short8 a0[4], a1[4];
#pragma unroll
    for (int kc = 0; kc < 4; ++kc) {
        float4 f0 = *(const float4*)(rp0 + kc*32 + quad*8);
        float4 f1 = *(const float4*)(rp0 + kc*32 + quad*8 + 4);
        float4 g0 = *(const float4*)(rp1 + kc*32 + quad*8);
        float4 g1 = *(const float4*)(rp1 + kc*32 + quad*8 + 4);
        u16 tb[8] = { f2b(f0.x), f2b(f0.y), f2b(f0.z), f2b(f0.w),
                      f2b(f1.x), f2b(f1.y), f2b(f1.z), f2b(f1.w) };
        a0[kc] = *(short8*)tb;
        u16 tc[8] = { f2b(g0.x), f2b(g0.y), f2b(g0.z), f2b(g0.w),
                      f2b(g1.x), f2b(g1.y), f2b(g1.z), f2b(g1.w) };
        a1[kc] = *(short8*)tc;
    }

    // stage BOTH weight sets upfront (overlaps the x-load latency)
#pragma unroll
    for (int it = 0; it < 4; ++it) {
        short8 v = ld8(Wsrc_pk + (size_t)(it*512 + t)*8);
        *(short8*)(&wlds[(it*512 + t)*8]) = v;
    }
#pragma unroll
    for (int it = 0; it < 4; ++it) {
        short8 v = ld8(Wsm_pk + (size_t)(it*512 + t)*8);
        *(short8*)(&mlds[(it*512 + t)*8]) = v;
    }
    __syncthreads();

    // ---- phase 1: s1 tanh-dot from wlds (log2-domain; K0 cancels)
    float v0[4] = {0,0,0,0}, v1[4] = {0,0,0,0};
#pragma unroll
    for (int tt = 0; tt < 8; ++tt) {
        const float bb = bsrcs[tt*16 + ln];
        const float ww = wa1s[tt*16 + ln];
        f32x4 acc0 = {bb, bb, bb, bb};
        f32x4 acc1 = {bb, bb, bb, bb};
#pragma unroll
        for (int kc = 0; kc < 4; ++kc) {
            short8 bf = ld8(&wlds[(size_t)((kc*8 + tt)*64 + lane)*8]);
            acc0 = __builtin_amdgcn_mfma_f32_16x16x32_bf16(a0[kc], bf, acc0, 0, 0, 0);
            acc1 = __builtin_amdgcn_mfma_f32_16x16x32_bf16(a1[kc], bf, acc1, 0, 0, 0);
        }
#pragma unroll
        for (int r = 0; r < 4; ++r) {
            v0[r] = fmaf(ww, RCP(EXP2(acc0[r]) + 1.f), v0[r]);
            v1[r] = fmaf(ww, RCP(EXP2(acc1[r]) + 1.f), v1[r]);
        }
    }
#pragma unroll
    for (int off = 8; off >= 1; off >>= 1) {
#pragma unroll
        for (int r = 0; r < 4; ++r) {
            v0[r] += __shfl_xor(v0[r], off);
            v1[r] += __shfl_xor(v1[r], off);
        }
    }
    if (ln == 0) {
#pragma unroll
        for (int r = 0; r < 4; ++r) {
            s1[row0 + quad*4 + r]      = v0[r];
            s1[row0 + 16 + quad*4 + r] = v1[r];
        }
    }

    // all waves done READING wlds -> safe to reuse as slab space
    __syncthreads();

    // ---- phase 2: srcmsg from mlds; per-wave slab in wlds
    u16* slab = &wlds[w*2048];
#pragma unroll
    for (int tile = 0; tile < 2; ++tile) {
#pragma unroll
        for (int tt = 0; tt < 8; ++tt) {
            const float bs = bsm[tt*16 + ln];
            f32x4 acc = {bs, bs, bs, bs};
#pragma unroll
            for (int kc = 0; kc < 4; ++kc) {
                short8 bf = ld8(&mlds[(size_t)((kc*8 + tt)*64 + lane)*8]);
                acc = __builtin_amdgcn_mfma_f32_16x16x32_bf16(
                          tile ? a1[kc] : a0[kc], bf, acc, 0, 0, 0);
            }
            // swizzled write: row = quad*4+r (row>>2 == quad), col blk tt^quad
#pragma unroll
            for (int r = 0; r < 4; ++r)
                slab[(quad*4 + r)*128 + ((tt ^ quad) << 4) + ln] = f2b(acc[r]);
        }
        // per-wave readback (DS in-order within wave; no barrier needed)
#pragma unroll
        for (int r2 = 0; r2 < 4; ++r2) {
            const int row = r2*4 + quad;          // row>>2 == r2
            const int c = ln*8;
            const int sidx = row*128 + (((c >> 4) ^ r2) << 4) + (c & 15);
            short8 val = *(const short8*)(&slab[sidx]);
            *(short8*)(srcmsgb + (size_t)(row0 + tile*16 + row)*HD + c) = val;
        }
    }
}

// ---------------------------------------------------------------------------
// scan1: per-1024-chunk exclusive scan of cnt into rowptr, block sums to bsum
// ---------------------------------------------------------------------------
__global__ __launch_bounds__(1024) void scan1_kernel(
    const int* __restrict__ cnt, int* __restrict__ excl, int* __restrict__ bsum)
{
    __shared__ int buf[1024];
    const int t = threadIdx.x;
    const int i = blockIdx.x * 1024 + t;
    int v = (i < NDST) ? cnt[i] : 0;
    buf[t] = v;
    __syncthreads();
    for (int off = 1; off < 1024; off <<= 1) {
        int tv = (t >= off) ? buf[t - off] : 0;
        __syncthreads();
        buf[t] += tv;
        __syncthreads();
    }
    if (i < NDST) excl[i] = buf[t] - v;
    if (t == 1023) bsum[blockIdx.x] = buf[1023];
}

// ---------------------------------------------------------------------------
// scan23: every block redundantly wave-scans the 49 chunk sums, then applies
// the offset to its rowptr slice.
// ---------------------------------------------------------------------------
__global__ __launch_bounds__(256) void scan23_kernel(
    const int* __restrict__ bsum, int* __restrict__ rowptr)
{
    __shared__ int pref[64];
    const int t = threadIdx.x;
    const int NB = (NDST + 1023) / 1024;     // 49
    if (t < 64) {
        int orig = (t < NB) ? bsum[t] : 0;
        int v = orig;
        for (int off = 1; off < 64; off <<= 1) {
            int u = __shfl_up(v, off);
            if (t >= off) v += u;
        }
        pref[t] = v - orig;                  // exclusive prefix
        if (blockIdx.x == 0 && t == NB - 1) rowptr[NDST] = v;  // total
    }
    __syncthreads();
    const int i = blockIdx.x * 256 + t;
    if (i < NDST) rowptr[i] += pref[i >> 10];
}

// ---------------------------------------------------------------------------
// edge_score: 64 edges / wave (4 A-tiles share each We B-frag). Tanh-dot in
// log2-domain; score = s1[src] + v_e. Epilogue gathers hoisted to kernel
// entry (their ~500-cycle chain hides under the MFMA/transcendental loop).
// 15-cndmask select tree + ONE shfl. Atomic-free slot = rowptr + rank.
// ---------------------------------------------------------------------------
__global__ __launch_bounds__(256) void edge_score_kernel(
    const int* __restrict__ ei, const float* __restrict__ eattr,
    const u16* __restrict__ We_pk, const float* __restrict__ bes,
    const float* __restrict__ wa3s,
    const float* __restrict__ s1,
    const int* __restrict__ rowptr, const int* __restrict__ rank,
    int4* __restrict__ ev16)
{
    const int t = threadIdx.x;
    const int w = t >> 6, lane = t & 63;
    const int ln = lane & 15, quad = lane >> 4;
    int e0 = (blockIdx.x * 4 + w) * 64;
    if (e0 > NE - 64) e0 = NE - 64;        // dup processing benign

    // ---- hoisted epilogue gathers (independent of the dot computation)
    const int e = e0 + lane;
    const int srcn = ei[e];
    const int dstn = ei[NE + e];
    const float s1v = s1[srcn];
    const int pos = rowptr[dstn] + rank[e];

    short8 a[4];
#pragma unroll
    for (int tl = 0; tl < 4; ++tl) {
        const float* ap = eattr + (size_t)(e0 + tl*16 + ln)*EDIM + quad*8;
        float4 f0 = *(const float4*)(ap);
        float4 f1 = *(const float4*)(ap + 4);
        u16 ab[8] = { f2b(f0.x), f2b(f0.y), f2b(f0.z), f2b(f0.w),
                      f2b(f1.x), f2b(f1.y), f2b(f1.z), f2b(f1.w) };
        a[tl] = *(short8*)ab;
    }

    float v0[4] = {0,0,0,0}, v1[4] = {0,0,0,0};
    float v2[4] = {0,0,0,0}, v3[4] = {0,0,0,0};
#pragma unroll
    for (int tt = 0; tt < 8; ++tt) {
        const float bb = bes[tt*16 + ln];
        const float ww = wa3s[tt*16 + ln];
        short8 b = ld8(We_pk + (size_t)(tt*64 + lane)*8);
        f32x4 ac0 = {bb, bb, bb, bb};
        f32x4 ac1 = {bb, bb, bb, bb};
        f32x4 ac2 = {bb, bb, bb, bb};
        f32x4 ac3 = {bb, bb, bb, bb};
        ac0 = __builtin_amdgcn_mfma_f32_16x16x32_bf16(a[0], b, ac0, 0, 0, 0);
        ac1 = __builtin_amdgcn_mfma_f32_16x16x32_bf16(a[1], b, ac1, 0, 0, 0);
        ac2 = __builtin_amdgcn_mfma_f32_16x16x32_bf16(a[2], b, ac2, 0, 0, 0);
        ac3 = __builtin_amdgcn_mfma_f32_16x16x32_bf16(a[3], b, ac3, 0, 0, 0);
#pragma unroll
        for (int r = 0; r < 4; ++r) {
            v0[r] = fmaf(ww, RCP(EXP2(ac0[r]) + 1.f), v0[r]);
            v1[r] = fmaf(ww, RCP(EXP2(ac1[r]) + 1.f), v1[r]);
            v2[r] = fmaf(ww, RCP(EXP2(ac2[r]) + 1.f), v2[r]);
            v3[r] = fmaf(ww, RCP(EXP2(ac3[r]) + 1.f), v3[r]);
        }
    }
    // reduce over the 16 feature lanes (ln) within each quad group
#pragma unroll
    for (int off = 8; off >= 1; off >>= 1) {
#pragma unroll
        for (int r = 0; r < 4; ++r) {
            v0[r] += __shfl_xor(v0[r], off);
            v1[r] += __shfl_xor(v1[r], off);
            v2[r] += __shfl_xor(v2[r], off);
            v3[r] += __shfl_xor(v3[r], off);
        }
    }
    // select tree: lane (quad q, ln) picks v_{ln>>2}[ln&3]
    const bool s0 = ln & 1, s1b = ln & 2, s2b = ln & 4, s3b = ln & 8;
    float m00 = s0 ? v0[1] : v0[0];
    float m01 = s0 ? v0[3] : v0[2];
    float m02 = s0 ? v1[1] : v1[0];
    float m03 = s0 ? v1[3] : v1[2];
    float m04 = s0 ? v2[1] : v2[0];
    float m05 = s0 ? v2[3] : v2[2];
    float m06 = s0 ? v3[1] : v3[0];
    float m07 = s0 ? v3[3] : v3[2];
    float m10 = s1b ? m01 : m00;
    float m11 = s1b ? m03 : m02;
    float m12 = s1b ? m05 : m04;
    float m13 = s1b ? m07 : m06;
    float m20 = s2b ? m11 : m10;
    float m21 = s2b ? m13 : m12;
    float selv = s3b ? m21 : m20;
    // lane l wants edge e0+l = (T=l>>4)*16 + (Q=(l>>2)&3)*4 + (R=l&3):
    // source lane = Q*16 + T*4 + R
    const int srcl = ((lane >> 2) & 3) * 16 + ((lane >> 4) << 2) + (lane & 3);
    const float myv = __shfl(selv, srcl);

    const float sc = s1v + myv;
    ev16[pos] = make_int4(srcn, e, __float_as_int(sc), 0);
}

// ---------------------------------------------------------------------------
// dst_agg: 1 wave per dst, single pass (no-max softmax), 2-deep software
// pipeline: per iteration issue record Q(k+2) and the srcmsg/eattr gathers
// for Q(k+1), then compute iteration k.
// msg row: 16 lanes x 16B bf16; ea row: 8 lanes x 16B f32 (one cache line).
// ---------------------------------------------------------------------------
__global__ __launch_bounds__(256) void dst_agg_kernel(
    const int4* __restrict__ ev16, const int* __restrict__ rowptr,
    const u16* __restrict__ srcmsgb, const float* __restrict__ eattr,
    const float* __restrict__ c2,
    u16* __restrict__ aggSb, u16* __restrict__ weab)
{
    const int lane = threadIdx.x & 63;
    const int d = blockIdx.x * 4 + (threadIdx.x >> 6);
    const int el = lane >> 4, c = lane & 15;
    const int start = rowptr[d], end = rowptr[d + 1];

    if (start == end) {
        if (el == 0) {
            u16 z[8];
#pragma unroll
            for (int j = 0; j < 8; ++j) z[j] = f2b(-c2[c*8 + j]);
            *(short8*)(aggSb + (size_t)d*HD + c*8) = *(short8*)z;
            if (c < 8) {
                u16 zz[4] = {0,0,0,0};
                *(ushort4*)(weab + (size_t)d*EDIM + c*4) = *(ushort4*)zz;
            }
        }
        return;
    }

    float sacc = 0.f;
    float acc[8]  = {0,0,0,0,0,0,0,0};
    float wacc[4] = {0,0,0,0};

    // pipeline prologue: Q(0), Q(1), SM(0), EA(0)
    const int iA = start + el;
    bool vA = (iA < end);
    int4 qA = ev16[vA ? iA : start];
    const int iB = iA + 4;
    bool vB = (iB < end);
    int4 qB = ev16[vB ? iB : start];
    short8 smA = ld8(srcmsgb + (size_t)qA.x*HD + c*8);
    float4 eaA = {0.f, 0.f, 0.f, 0.f};
    if (c < 8) eaA = *(const float4*)(eattr + (size_t)qA.y*EDIM + c*4);

    for (int i0 = start; i0 < end; i0 += 4) {
        // issue Q(k+2)
        const int iC = i0 + 8 + el;
        const bool vC = (iC < end);
        int4 qC = ev16[vC ? iC : start];
        // issue SM(k+1), EA(k+1) from already-arrived Q(k+1)
        short8 smB = ld8(srcmsgb + (size_t)qB.x*HD + c*8);
        float4 eaB = {0.f, 0.f, 0.f, 0.f};
        if (c < 8) eaB = *(const float4*)(eattr + (size_t)qB.y*EDIM + c*4);

        // compute iteration k
        const float wgt = vA ? EXP2(__int_as_float(qA.z)) : 0.f;
        sacc += wgt;
#pragma unroll
        for (int j = 0; j < 8; ++j)
            acc[j] = fmaf(wgt, b2f(((u16*)&smA)[j]), acc[j]);
        if (c < 8) {
            wacc[0] = fmaf(wgt, eaA.x, wacc[0]);
            wacc[1] = fmaf(wgt, eaA.y, wacc[1]);
            wacc[2] = fmaf(wgt, eaA.z, wacc[2]);
            wacc[3] = fmaf(wgt, eaA.w, wacc[3]);
        }
        // rotate
        qA = qB; vA = vB; smA = smB; eaA = eaB;
        qB = qC; vB = vC;
    }
#pragma unroll
    for (int off = 16; off <= 32; off <<= 1) {
        sacc += __shfl_xor(sacc, off);
#pragma unroll
        for (int j = 0; j < 8; ++j) acc[j] += __shfl_xor(acc[j], off);
#pragma unroll
        for (int j = 0; j < 4; ++j) wacc[j] += __shfl_xor(wacc[j], off);
    }
    const float inv = RCP(sacc);
    if (el == 0) {
        u16 o[8];
#pragma unroll
        for (int j = 0; j < 8; ++j) o[j] = f2b(acc[j] * inv);
        *(short8*)(aggSb + (size_t)d*HD + c*8) = *(short8*)o;
        if (c < 8) {
            u16 o2[4];
#pragma unroll
            for (int j = 0; j < 4; ++j) o2[j] = f2b(wacc[j] * inv);
            *(ushort4*)(weab + (size_t)d*EDIM + c*4) = *(ushort4*)o2;
        }
    }
}

// ---------------------------------------------------------------------------
// final: out = LN(dst_x@W1p + aggSb@Wout2 + weab@W3 + bias2) * gamma + beta
// per 16 dst rows / wave. W1/W2 LDS-staged per block; W3 (8KB) global/L1;
// accs persist in registers across the restage.
// ---------------------------------------------------------------------------
__global__ __launch_bounds__(256) void final_kernel(
    const float* __restrict__ dst_x, const u16* __restrict__ aggSb,
    const u16* __restrict__ weab,
    const u16* __restrict__ W1_pk, const u16* __restrict__ W2_pk,
    const u16* __restrict__ W3_pk, const float* __restrict__ bias2,
    const float* __restrict__ gamma, const float* __restrict__ beta,
    float* __restrict__ out)
{
    __shared__ __align__(16) u16 wlds[16384];      // 32 KB staged weights
    const int t = threadIdx.x;
    const int w = t >> 6, lane = t & 63;
    const int ln = lane & 15, quad = lane >> 4;
    int row0 = (blockIdx.x * 4 + w) * 16;
    if (row0 > NDST - 16) row0 = NDST - 16;

    const float* rp = dst_x + (size_t)(row0 + ln)*HD;
    short8 a1[4], a2[4], a3;
#pragma unroll
    for (int kc = 0; kc < 4; ++kc) {
        float4 f0 = *(const float4*)(rp + kc*32 + quad*8);
        float4 f1 = *(const float4*)(rp + kc*32 + quad*8 + 4);
        u16 tb[8] = { f2b(f0.x), f2b(f0.y), f2b(f0.z), f2b(f0.w),
                      f2b(f1.x), f2b(f1.y), f2b(f1.z), f2b(f1.w) };
        a1[kc] = *(short8*)tb;
        a2[kc] = ld8(aggSb + (size_t)(row0 + ln)*HD + kc*32 + quad*8);
    }
    a3 = ld8(weab + (size_t)(row0 + ln)*EDIM + quad*8);

    // stage W1 (32 KB, cooperative)
#pragma unroll
    for (int it = 0; it < 8; ++it) {
        short8 v = ld8(W1_pk + (size_t)(it*256 + t)*8);
        *(short8*)(&wlds[(it*256 + t)*8]) = v;
    }
    __syncthreads();

    f32x4 accs[8];
#pragma unroll
    for (int tt = 0; tt < 8; ++tt) {
        const float bb = bias2[tt*16 + ln];
        f32x4 acc = {bb, bb, bb, bb};
#pragma unroll
        for (int kc = 0; kc < 4; ++kc) {
            short8 b = ld8(&wlds[(size_t)((kc*8 + tt)*64 + lane)*8]);
            acc = __builtin_amdgcn_mfma_f32_16x16x32_bf16(a1[kc], b, acc, 0, 0, 0);
        }
        accs[tt] = acc;
    }

    // restage with W2
    __syncthreads();
#pragma unroll
    for (int it = 0; it < 8; ++it) {
        short8 v = ld8(W2_pk + (size_t)(it*256 + t)*8);
        *(short8*)(&wlds[(it*256 + t)*8]) = v;
    }
    __syncthreads();

#pragma unroll
    for (int tt = 0; tt < 8; ++tt) {
        f32x4 acc = accs[tt];
#pragma unroll
        for (int kc = 0; kc < 4; ++kc) {
            short8 b = ld8(&wlds[(size_t)((kc*8 + tt)*64 + lane)*8]);
            acc = __builtin_amdgcn_mfma_f32_16x16x32_bf16(a2[kc], b, acc, 0, 0, 0);
        }
        {
            short8 b = ld8(W3_pk + (size_t)(tt*64 + lane)*8);
            acc = __builtin_amdgcn_mfma_f32_16x16x32_bf16(a3, b, acc, 0, 0, 0);
        }
        accs[tt] = acc;
    }

    const float gl[8] = { gamma[ln], gamma[16+ln], gamma[32+ln], gamma[48+ln],
                          gamma[64+ln], gamma[80+ln], gamma[96+ln], gamma[112+ln] };
    const float bl[8] = { beta[ln], beta[16+ln], beta[32+ln], beta[48+ln],
                          beta[64+ln], beta[80+ln], beta[96+ln], beta[112+ln] };
#pragma unroll
    for (int r = 0; r < 4; ++r) {
        float s = 0.f, qq = 0.f;
#pragma unroll
        for (int tt = 0; tt < 8; ++tt) {
            float u = accs[tt][r];
            s += u; qq += u*u;
        }
#pragma unroll
        for (int off = 8; off >= 1; off >>= 1) {
            s  += __shfl_xor(s, off);
            qq += __shfl_xor(qq, off);
        }
        const float mean = s * (1.f / HD);
        const float var  = qq * (1.f / HD) - mean * mean;
        const float rstd = rsqrtf(var + LN_EPS);
        const int row = row0 + quad*4 + r;
#pragma unroll
        for (int tt = 0; tt < 8; ++tt)
            out[(size_t)row*HD + tt*16 + ln] =
                (accs[tt][r] - mean) * rstd * gl[tt] + bl[tt];
    }
}

// ---------------------------------------------------------------------------
extern "C" void kernel_launch(void* const* d_in, const int* in_sizes, int n_in,
                              void* d_out, int out_size, void* d_ws, size_t ws_size,
                              hipStream_t stream)
{
    const float* src_x = (const float*)d_in[0];
    const float* dst_x = (const float*)d_in[1];
    const int*   ei    = (const int*)d_in[2];
    const float* eattr = (const float*)d_in[3];
    const float* Wsrc  = (const float*)d_in[4];
    const float* bsrc  = (const float*)d_in[5];
    const float* We    = (const float*)d_in[8];
    const float* be    = (const float*)d_in[9];
    const float* Wattn = (const float*)d_in[10];
    const float* Wmsg  = (const float*)d_in[12];
    const float* bmsg  = (const float*)d_in[13];
    const float* Wout  = (const float*)d_in[14];
    const float* bout  = (const float*)d_in[15];
    const float* gamma = (const float*)d_in[16];
    const float* beta  = (const float*)d_in[17];
    float* out = (float*)d_out;

    float* ws = (float*)d_ws;
    u16* srcmsgb = (u16*)(ws + 0);            // 6.4M u16
    u16* aggSb   = (u16*)(ws + 3200000);      // 6.4M u16
    u16* weab    = (u16*)(ws + 6400000);      // 1.6M u16
    float* s1    = ws + 7200000;              // 50048
    float* Wsm   = ws + 7250048;              // 16384
    float* bsm   = ws + 7266432;              // 128
    float* WeMsg = ws + 7266560;              // 4096
    float* c2    = ws + 7270656;              // 128
    float* bias2 = ws + 7270784;              // 128
    u16* Wsrc_pk = (u16*)(ws + 7270912);      // 16384 u16
    u16* Wsm_pk  = (u16*)(ws + 7279104);
    u16* W1_pk   = (u16*)(ws + 7287296);
    u16* W2_pk   = (u16*)(ws + 7295488);
    u16* We_pk   = (u16*)(ws + 7303680);      // 4096 u16
    u16* W3_pk   = (u16*)(ws + 7305728);      // 4096 u16
    int* rowptr  = (int*)(ws + 7307776);      // 50016
    int* cnt     = (int*)(ws + 7357792);      // 50016
    int* bsum    = (int*)(ws + 7407808);      // 64
    int* rank    = (int*)(ws + 7407872);      // 500000
    int4* ev16   = (int4*)(ws + 7907872);     // 500000 int4 (16B-aligned)
    float* wa1s  = ws + 9907872;              // 128
    float* wa3s  = ws + 9908000;              // 128
    float* bsrcs = ws + 9908128;              // 128
    float* bes   = ws + 9908256;              // 128

    fold1_kernel<<<553, 128, 0, stream>>>(Wsrc, bsrc, We, be, Wmsg, bmsg,
                                          Wsm, bsm, WeMsg, c2, cnt);
    pack_all_kernel<<<146, 64, 0, stream>>>(Wsrc, Wsm, Wout, We, WeMsg, c2,
                                            bout, bsrc, be, Wattn,
                                            Wsrc_pk, Wsm_pk, W1_pk, W2_pk,
                                            We_pk, W3_pk, bias2,
                                            wa1s, wa3s, bsrcs, bes);

    mega_kernel<<<NBLK + HB4, 512, 0, stream>>>(
        src_x, ei, Wsrc_pk, Wsm_pk, bsrcs, bsm, wa1s,
        s1, srcmsgb, cnt, rank);

    scan1_kernel<<<(NDST + 1023) / 1024, 1024, 0, stream>>>(cnt, rowptr, bsum);
    scan23_kernel<<<(NDST + 255) / 256, 256, 0, stream>>>(bsum, rowptr);

    edge_score_kernel<<<((NE + 63)/64 + 3) / 4, 256, 0, stream>>>(
        ei, eattr, We_pk, bes, wa3s, s1, rowptr, rank, ev16);

    dst_agg_kernel<<<NDST / 4, 256, 0, stream>>>(ev16, rowptr, srcmsgb,
                                                 eattr, c2, aggSb, weab);

    final_kernel<<<(NDST/16 + 3) / 4, 256, 0, stream>>>(
        dst_x, aggSb, weab, W1_pk, W2_pk, W3_pk, bias2, gamma, beta, out);
}